// Round 12
// baseline (414.020 us; speedup 1.0000x reference)
//
#include <hip/hip_runtime.h>
#include <hip/hip_fp16.h>

#define N_NODES 50000
#define N_EDGES 800000
#define N_GRAPHS 256
#define F_IN 112
#define DIM 32
#define BN_EPS 1e-5
#define PAD 32     // ints per atomic slot: one 128-B line per cursor
#define HROW 128   // fp16 gather-row stride (256 B = exactly 2 lines, zero waste)
#define CAP 64     // edge slots per node (P(deg>63) ~ 1e-19 for Poisson(16))
#define NB 1563    // buckets = ceil(50000/32)
#define NREP 8     // one bucket replica per XCD
#define RCAP 128   // entries per replica-bucket (Poisson(64), 8 sigma headroom)

typedef __attribute__((ext_vector_type(8))) short short8;
typedef __attribute__((ext_vector_type(4))) float float4v;

// ---- bf16 helpers (RNE) ----
__device__ inline unsigned short f2bf(float f) {
    union { float f; unsigned int u; } v; v.f = f;
    unsigned int u = v.u;
    u += 0x7FFFu + ((u >> 16) & 1u);
    return (unsigned short)(u >> 16);
}
__device__ inline float bf2f(unsigned short h) {
    union { unsigned int u; float f; } v; v.u = ((unsigned int)h) << 16;
    return v.f;
}

__device__ inline void w_split_body(const float* __restrict__ W, int K, int N, int Kpad,
                                    unsigned short* __restrict__ hi_t,
                                    unsigned short* __restrict__ lo_t, int idx) {
    if (idx >= N * Kpad) return;
    int n = idx / Kpad, k = idx - n * Kpad;
    float v = (k < K) ? W[(size_t)k * N + n] : 0.f;
    unsigned short h = f2bf(v);
    hi_t[idx] = h;
    lo_t[idx] = f2bf(v - bf2f(h));
}

// ---- merged prep: bucket_append FIRST (long pole), then x->fp16, weight
//      splits, graph bounds. Bucket src/dst reads are non-temporal so the
//      streaming sweep doesn't evict dirty bucket-replica lines from L2.
#define PB_BA 3125                   // 800000/256 bucket-append blocks
#define PB_XH (PB_BA + 12500)        // 50000*64 half2 / 256
#define PB_W1 (PB_XH + 56)
#define PB_W2 (PB_W1 + 56)
#define PB_W4 (PB_W2 + 4)
#define PB_GB (PB_W4 + 196)          // total blocks
__global__ __launch_bounds__(256) void prep_kernel(const int* __restrict__ src, const int* __restrict__ dst,
                                                   int* __restrict__ bcur_pad, int* __restrict__ bucket,
                                                   const float* __restrict__ X, __half* __restrict__ Xh,
                                                   const float* __restrict__ g1_w1, unsigned short* w1h, unsigned short* w1l,
                                                   const float* __restrict__ g1_w2, unsigned short* w2h, unsigned short* w2l,
                                                   const float* __restrict__ g2_w2, unsigned short* w4h, unsigned short* w4l,
                                                   const int* __restrict__ batch, int* __restrict__ goff) {
    int b = blockIdx.x, t = threadIdx.x;
    if (b < PB_BA) {
        unsigned xcc = 0;
        asm volatile("s_getreg_b32 %0, hwreg(HW_REG_XCC_ID)" : "=s"(xcc));
        int r = (int)(xcc & (NREP - 1));
        int i = b * 256 + t;
        if (i < N_EDGES) {
            int d = __builtin_nontemporal_load(dst + i);
            int s = __builtin_nontemporal_load(src + i);
            int bk = d >> 5;
            size_t slot = (size_t)bk * NREP + r;
            int c = atomicAdd(&bcur_pad[slot * PAD], 1);
            if (c < RCAP) bucket[slot * RCAP + c] = ((d & 31) << 16) | s;
        }
    } else if (b < PB_XH) {
        int idx = (b - PB_BA) * 256 + t;             // one half2 per thread
        if (idx >= N_NODES * (HROW / 2)) return;
        int row = idx / (HROW / 2), c2 = idx - row * (HROW / 2);
        int col = c2 * 2;
        float2 v = make_float2(0.f, 0.f);
        if (col < F_IN) v = *(const float2*)(X + (size_t)row * F_IN + col);
        ((__half2*)Xh)[idx] = __floats2half2_rn(v.x, v.y);
    } else if (b < PB_W1) {
        w_split_body(g1_w1, F_IN, F_IN, 128, w1h, w1l, (b - PB_XH) * 256 + t);
    } else if (b < PB_W2) {
        w_split_body(g1_w2, F_IN, F_IN, 128, w2h, w2l, (b - PB_W1) * 256 + t);
    } else if (b < PB_W4) {
        w_split_body(g2_w2, DIM, DIM, 32, w4h, w4l, (b - PB_W2) * 256 + t);
    } else {
        int i = (b - PB_W4) * 256 + t;
        if (i >= N_NODES) return;
        int cur = batch[i];
        int prev = (i == 0) ? -1 : batch[i - 1];
        for (int g = prev + 1; g <= cur; g++) goff[g] = i;
        if (i == N_NODES - 1) {
            for (int g = cur + 1; g <= N_GRAPHS; g++) goff[g] = N_NODES;
        }
    }
}

// ---------------- phase B: per-bucket LDS binning -> coalesced perm/deg write
__global__ __launch_bounds__(256) void bin_build(const int* __restrict__ bcur_pad,
                                                 const int* __restrict__ bucket,
                                                 int* __restrict__ perm_pad,
                                                 int* __restrict__ deg) {
    __shared__ int bins[32][CAP];
    __shared__ int lcur[32];
    int b = blockIdx.x, t = threadIdx.x;
    if (t < 32) lcur[t] = 0;
    __syncthreads();
    for (int r = 0; r < NREP; r++) {
        size_t slot = (size_t)b * NREP + r;
        int count = min(bcur_pad[slot * PAD], RCAP);
        for (int i = t; i < count; i += 256) {
            int e = bucket[slot * RCAP + i];
            int l = e >> 16, s = e & 0xFFFF;
            int c = atomicAdd(&lcur[l], 1);
            if (c < CAP) bins[l][c] = s;
        }
    }
    __syncthreads();
    if (t < 32) {
        int node = b * 32 + t;
        if (node < N_NODES) deg[node] = min(lcur[t], CAP);
    }
    for (int i = t; i < 32 * (CAP / 4); i += 256) {
        int l = i / (CAP / 4), q = i % (CAP / 4);
        int node = b * 32 + l;
        if (node < N_NODES) {
            ((int4*)&perm_pad[(size_t)node * CAP])[q] = ((const int4*)bins[l])[q];
        }
    }
}

// ------------------- layer-1 aggregation (wave per node), fp16 gather
__global__ __launch_bounds__(256) void agg_kernel(const float* __restrict__ X,
                                                  const __half* __restrict__ Xh,
                                                  const int* __restrict__ deg_arr,
                                                  const int* __restrict__ perm_pad,
                                                  float* __restrict__ out, int M) {
    constexpr int P = F_IN / 2;
    int w = (blockIdx.x * 256 + threadIdx.x) >> 6;
    int lane = threadIdx.x & 63;
    if (w >= M) return;
    int deg = deg_arr[w];
    const int* pl = perm_pad + (size_t)w * CAP;
    float ax = 0.f, ay = 0.f;
    int e = 0;
    for (; e + 16 <= deg; e += 16) {
        int s[16];
#pragma unroll
        for (int j = 0; j < 16; j++) s[j] = pl[e + j];
        float2 v[16];
#pragma unroll
        for (int j = 0; j < 16; j++)
            v[j] = __half22float2(*(const __half2*)(Xh + (size_t)s[j] * HROW + 2 * lane));
#pragma unroll
        for (int j = 0; j < 16; j++) { ax += v[j].x; ay += v[j].y; }
    }
    for (; e + 4 <= deg; e += 4) {
        int s0 = pl[e], s1 = pl[e + 1], s2 = pl[e + 2], s3 = pl[e + 3];
        float2 v0 = __half22float2(*(const __half2*)(Xh + (size_t)s0 * HROW + 2 * lane));
        float2 v1 = __half22float2(*(const __half2*)(Xh + (size_t)s1 * HROW + 2 * lane));
        float2 v2 = __half22float2(*(const __half2*)(Xh + (size_t)s2 * HROW + 2 * lane));
        float2 v3 = __half22float2(*(const __half2*)(Xh + (size_t)s3 * HROW + 2 * lane));
        ax += (v0.x + v1.x) + (v2.x + v3.x);
        ay += (v0.y + v1.y) + (v2.y + v3.y);
    }
    for (; e < deg; e++) {
        int s = pl[e];
        float2 v = __half22float2(*(const __half2*)(Xh + (size_t)s * HROW + 2 * lane));
        ax += v.x;
        ay += v.y;
    }
    if (lane < P) {
        float2 self = *(const float2*)(X + (size_t)w * F_IN + 2 * lane);
        *(float2*)(out + (size_t)w * F_IN + 2 * lane) = make_float2(self.x + ax, self.y + ay);
    }
}

// ---------- layer-2 aggregation on 32-wide fp16 y rows (quarter-wave/edge)
__global__ __launch_bounds__(256) void agg32_kernel(const __half* __restrict__ Y,
                                                    const int* __restrict__ deg_arr,
                                                    const int* __restrict__ perm_pad,
                                                    const float* __restrict__ c0,
                                                    const float* __restrict__ b1,
                                                    float* __restrict__ out, int M) {
    int w = (blockIdx.x * 256 + threadIdx.x) >> 6;
    int lane = threadIdx.x & 63;
    if (w >= M) return;
    int f = lane & 15;
    int g = lane >> 4;
    int deg = deg_arr[w];
    const int* pl = perm_pad + (size_t)w * CAP;
    float ax = 0.f, ay = 0.f;
    int e = g;
    for (; e + 4 < deg; e += 8) {
        int s0 = pl[e], s1 = pl[e + 4];
        float2 v0 = __half22float2(*(const __half2*)(Y + (size_t)s0 * DIM + 2 * f));
        float2 v1 = __half22float2(*(const __half2*)(Y + (size_t)s1 * DIM + 2 * f));
        ax += v0.x + v1.x;
        ay += v0.y + v1.y;
    }
    if (e < deg) {
        int s0 = pl[e];
        float2 v0 = __half22float2(*(const __half2*)(Y + (size_t)s0 * DIM + 2 * f));
        ax += v0.x;
        ay += v0.y;
    }
    ax += __shfl_xor(ax, 16); ax += __shfl_xor(ax, 32);
    ay += __shfl_xor(ay, 16); ay += __shfl_xor(ay, 32);
    if (g == 0) {
        float2 self = __half22float2(*(const __half2*)(Y + (size_t)w * DIM + 2 * f));
        float deg1 = (float)(deg + 1);
        float zx = self.x + ax + deg1 * c0[2 * f] + b1[2 * f];
        float zy = self.y + ay + deg1 * c0[2 * f + 1] + b1[2 * f + 1];
        *(float2*)(out + (size_t)w * DIM + 2 * f) = make_float2(fmaxf(zx, 0.f), fmaxf(zy, 0.f));
    }
}

// ------- BN1-folded W3 split: W3'[k][n] = s1[k]*W3[k][n]; c0[n] = sum t1[k]W3[k][n]
__global__ __launch_bounds__(256) void w3_fold(const float* __restrict__ W,   // [112][32]
                                               const float* __restrict__ s1,
                                               const float* __restrict__ t1,
                                               unsigned short* __restrict__ hi_t,  // [32][128]
                                               unsigned short* __restrict__ lo_t,
                                               float* __restrict__ c0) {
    int idx = blockIdx.x * 256 + threadIdx.x;
    if (idx < DIM * 128) {
        int n = idx >> 7, k = idx & 127;
        float v = (k < F_IN) ? s1[k] * W[(size_t)k * DIM + n] : 0.f;
        unsigned short h = f2bf(v);
        hi_t[idx] = h;
        lo_t[idx] = f2bf(v - bf2f(h));
    }
    if (blockIdx.x == 0 && threadIdx.x < DIM) {
        int n = threadIdx.x;
        float acc = 0.f;
        for (int k = 0; k < F_IN; k++) acc += t1[k] * W[(size_t)k * DIM + n];
        c0[n] = acc;
    }
}

// ------------------------- split-bf16 MFMA GEMM: C = act(A @ W + bias)
// STATS: fuse per-block BN partial sums (sum, sumsq per column) into epilogue.
template <int NT, int KC, int K, bool RELU, int CHS, bool STATS>
__global__ __launch_bounds__(256) void gemm_mfma(const float* __restrict__ A,
                                                 const unsigned short* __restrict__ Whi,
                                                 const unsigned short* __restrict__ Wlo,
                                                 const float* __restrict__ bias,
                                                 float* __restrict__ C,
                                                 __half* __restrict__ Ch,
                                                 float* __restrict__ pbuf, int M) {
    constexpr int N = NT * 16;
    constexpr int Kpad = KC * 32;
    __shared__ __align__(16) unsigned short Ah[64 * 32];
    __shared__ __align__(16) unsigned short Al[64 * 32];
    __shared__ __align__(16) unsigned short Wh[N * 32];
    __shared__ __align__(16) unsigned short Wl[N * 32];
    int t = threadIdx.x;
    int lane = t & 63, wid = t >> 6;
    int r0 = blockIdx.x * 64;
    int m = lane & 15, quad = lane >> 4;

    float4v acc[NT];
#pragma unroll
    for (int nt = 0; nt < NT; nt++) acc[nt] = (float4v){0.f, 0.f, 0.f, 0.f};

    for (int c = 0; c < KC; c++) {
        int kc = c * 32;
#pragma unroll
        for (int i = 0; i < 2; i++) {
            int idx = t + i * 256;
            int row = idx >> 3, c4 = idx & 7;
            int col = kc + c4 * 4;
            int grow = r0 + row;
            float4 v = make_float4(0.f, 0.f, 0.f, 0.f);
            if (grow < M) {
                if (col + 3 < K) {
                    v = *(const float4*)(A + (size_t)grow * K + col);
                } else {
                    float tmp[4] = {0.f, 0.f, 0.f, 0.f};
                    for (int j = 0; j < 4; j++) if (col + j < K) tmp[j] = A[(size_t)grow * K + col + j];
                    v = make_float4(tmp[0], tmp[1], tmp[2], tmp[3]);
                }
            }
            unsigned short h0 = f2bf(v.x), h1 = f2bf(v.y), h2 = f2bf(v.z), h3 = f2bf(v.w);
            unsigned short l0 = f2bf(v.x - bf2f(h0)), l1 = f2bf(v.y - bf2f(h1));
            unsigned short l2 = f2bf(v.z - bf2f(h2)), l3 = f2bf(v.w - bf2f(h3));
            int o = row * 32 + c4 * 4;
            *(uint2*)&Ah[o] = make_uint2((unsigned)h0 | ((unsigned)h1 << 16), (unsigned)h2 | ((unsigned)h3 << 16));
            *(uint2*)&Al[o] = make_uint2((unsigned)l0 | ((unsigned)l1 << 16), (unsigned)l2 | ((unsigned)l3 << 16));
        }
        for (int idx = t; idx < N * 8; idx += 256) {
            int n = idx >> 3, w = idx & 7;
            int gsrc = n * (Kpad / 4) + (kc >> 2) + w;
            ((uint2*)Wh)[idx] = ((const uint2*)Whi)[gsrc];
            ((uint2*)Wl)[idx] = ((const uint2*)Wlo)[gsrc];
        }
        __syncthreads();
        short8 a_h = *(const short8*)&Ah[(wid * 16 + m) * 32 + quad * 8];
        short8 a_l = *(const short8*)&Al[(wid * 16 + m) * 32 + quad * 8];
#pragma unroll
        for (int nt = 0; nt < NT; nt++) {
            short8 b_h = *(const short8*)&Wh[(nt * 16 + m) * 32 + quad * 8];
            short8 b_l = *(const short8*)&Wl[(nt * 16 + m) * 32 + quad * 8];
            acc[nt] = __builtin_amdgcn_mfma_f32_16x16x32_bf16(a_h, b_h, acc[nt], 0, 0, 0);
            acc[nt] = __builtin_amdgcn_mfma_f32_16x16x32_bf16(a_h, b_l, acc[nt], 0, 0, 0);
            acc[nt] = __builtin_amdgcn_mfma_f32_16x16x32_bf16(a_l, b_h, acc[nt], 0, 0, 0);
        }
        __syncthreads();
    }
    float st_s[NT], st_q[NT];
#pragma unroll
    for (int nt = 0; nt < NT; nt++) {
        int col = nt * 16 + m;
        float b = bias ? bias[col] : 0.f;
        float s_loc = 0.f, q_loc = 0.f;
#pragma unroll
        for (int r = 0; r < 4; r++) {
            int row = r0 + wid * 16 + quad * 4 + r;
            float v = acc[nt][r] + b;
            if (RELU) v = fmaxf(v, 0.f);
            if (row < M) {
                if (C) C[(size_t)row * N + col] = v;
                if (Ch) Ch[(size_t)row * CHS + col] = __float2half(v);
                if (STATS) { s_loc += v; q_loc += v * v; }
            }
        }
        st_s[nt] = s_loc;
        st_q[nt] = q_loc;
    }
    if constexpr (STATS) {
        __shared__ float sls[4][2 * N];
#pragma unroll
        for (int nt = 0; nt < NT; nt++) {
            float s = st_s[nt], q = st_q[nt];
            s += __shfl_xor(s, 16); s += __shfl_xor(s, 32);
            q += __shfl_xor(q, 16); q += __shfl_xor(q, 32);
            if (quad == 0) {
                sls[wid][nt * 16 + m] = s;
                sls[wid][N + nt * 16 + m] = q;
            }
        }
        __syncthreads();
        for (int j = t; j < 2 * N; j += 256) {
            pbuf[(size_t)blockIdx.x * 2 * N + j] = sls[0][j] + sls[1][j] + sls[2][j] + sls[3][j];
        }
    }
}

// ----------------------------------- BN stats (layer 2 only, 32-wide)
template <int BLOCKS>
__global__ __launch_bounds__(256) void bn_stats32(const float* __restrict__ H, int M,
                                                  float* __restrict__ pbuf) {
    __shared__ float ls[8][64];
    int t = threadIdx.x;
    int col = t & 31, rg = t >> 5;
    float s = 0.f, q = 0.f;
    for (int r = blockIdx.x * 8 + rg; r < M; r += BLOCKS * 8) {
        float v = H[(size_t)r * 32 + col];
        s += v; q += v * v;
    }
    ls[rg][col] = s;
    ls[rg][32 + col] = q;
    __syncthreads();
    if (t < 64) {
        float a = 0.f;
        for (int i = 0; i < 8; i++) a += ls[i][t];
        pbuf[(size_t)blockIdx.x * 64 + t] = a;
    }
}

template <int F, int BLOCKS>
__global__ __launch_bounds__(128) void bn_finalize(const float* __restrict__ pbuf, const float* __restrict__ g,
                                                   const float* __restrict__ b, float* __restrict__ s,
                                                   float* __restrict__ tt, int M) {
    int j = threadIdx.x;
    if (j < F) {
        double sum = 0.0, sq = 0.0;
        for (int i = 0; i < BLOCKS; i++) {
            sum += (double)pbuf[(size_t)i * 2 * F + j];
            sq  += (double)pbuf[(size_t)i * 2 * F + F + j];
        }
        double mean = sum / M;
        double var = sq / M - mean * mean;
        double sc = (double)g[j] / sqrt(var + BN_EPS);
        s[j] = (float)sc;
        tt[j] = (float)((double)b[j] - mean * sc);
    }
}

// -------------------------------------------- pool (BN2 folded) + head
__global__ __launch_bounds__(256) void pool_head(const float* __restrict__ H2, const int* __restrict__ goff,
                                                 const float* __restrict__ s2, const float* __restrict__ t2,
                                                 const float* __restrict__ fcxd_w, const float* __restrict__ fcxd_b,
                                                 const float* __restrict__ fc1_w, const float* __restrict__ fc1_b,
                                                 const float* __restrict__ fc2_w, const float* __restrict__ fc2_b,
                                                 const float* __restrict__ fc3_w, const float* __restrict__ fc3_b,
                                                 const float* __restrict__ fc4_w, const float* __restrict__ fc4_b,
                                                 const float* __restrict__ fc5_w, const float* __restrict__ fc5_b,
                                                 float* __restrict__ out) {
    __shared__ float red[256];
    __shared__ float p[64];
    __shared__ float z[64];
    int g = blockIdx.x, t = threadIdx.x;
    int r0 = goff[g], r1 = goff[g + 1];
    int cnt = r1 - r0;
    int j = t & 31, rr = t >> 5;
    float a = 0.f;
    for (int r = r0 + rr; r < r1; r += 8) a += H2[(size_t)r * DIM + j];
    red[t] = a;
    __syncthreads();
    if (t < 32) {
        float ssum = 0.f;
        for (int q = 0; q < 8; q++) ssum += red[q * 32 + j];
        p[j] = s2[j] * ssum + (float)cnt * t2[j];
    }
    __syncthreads();
    if (t < 64) {
        float acc = fcxd_b[t];
        for (int i = 0; i < 32; i++) acc += p[i] * fcxd_w[i * 64 + t];
        z[t] = fmaxf(acc, 0.f);
    }
    __syncthreads();
    if (t < 32) {
        float acc = fc1_b[t];
        for (int i = 0; i < 64; i++) acc += z[i] * fc1_w[i * 32 + t];
        p[t] = acc;
    }
    __syncthreads();
    if (t < 16) {
        float acc = fc2_b[t];
        for (int i = 0; i < 32; i++) acc += p[i] * fc2_w[i * 16 + t];
        z[t] = acc;
    }
    __syncthreads();
    if (t < 8) {
        float acc = fc3_b[t];
        for (int i = 0; i < 16; i++) acc += z[i] * fc3_w[i * 8 + t];
        p[t] = acc;
    }
    __syncthreads();
    if (t < 2) {
        float acc = fc4_b[t];
        for (int i = 0; i < 8; i++) acc += p[i] * fc4_w[i * 2 + t];
        z[t] = acc;
    }
    __syncthreads();
    if (t == 0) {
        out[g] = z[0] * fc5_w[0] + z[1] * fc5_w[1] + fc5_b[0];
    }
}

// ---------------------------------------------------------------- launch
extern "C" void kernel_launch(void* const* d_in, const int* in_sizes, int n_in,
                              void* d_out, int out_size, void* d_ws, size_t ws_size,
                              hipStream_t stream) {
    const float* x     = (const float*)d_in[0];
    const int*   src   = (const int*)d_in[1];
    const int*   dst   = (const int*)d_in[2];
    const int*   batch = (const int*)d_in[3];
    const float* g1_w1 = (const float*)d_in[4];
    const float* g1_b1 = (const float*)d_in[5];
    const float* g1_w2 = (const float*)d_in[6];
    const float* g1_b2 = (const float*)d_in[7];
    const float* bn1_g = (const float*)d_in[8];
    const float* bn1_b = (const float*)d_in[9];
    const float* g2_w1 = (const float*)d_in[10];
    const float* g2_b1 = (const float*)d_in[11];
    const float* g2_w2 = (const float*)d_in[12];
    const float* g2_b2 = (const float*)d_in[13];
    const float* bn2_g = (const float*)d_in[14];
    const float* bn2_b = (const float*)d_in[15];
    const float* fcxd_w = (const float*)d_in[16];
    const float* fcxd_b = (const float*)d_in[17];
    const float* fc1_w = (const float*)d_in[18];
    const float* fc1_b = (const float*)d_in[19];
    const float* fc2_w = (const float*)d_in[20];
    const float* fc2_b = (const float*)d_in[21];
    const float* fc3_w = (const float*)d_in[22];
    const float* fc3_b = (const float*)d_in[23];
    const float* fc4_w = (const float*)d_in[24];
    const float* fc4_b = (const float*)d_in[25];
    const float* fc5_w = (const float*)d_in[26];
    const float* fc5_b = (const float*)d_in[27];
    float* out = (float*)d_out;
    char* ws = (char*)d_ws;

    const int GEMM_MB = (N_NODES + 63) / 64;       // 782 (also BN1 partial blocks)
    constexpr int BN2_BLOCKS = 128;

    size_t off = 0;
    auto take = [&](size_t bytes) { size_t o = off; off += (bytes + 255) & ~(size_t)255; return o; };
    int* bcur_pad  = (int*)(ws + take((size_t)NB * NREP * PAD * 4));    // zeroed (1.6 MB)
    size_t zero_bytes = off;
    int* bucket    = (int*)(ws + take((size_t)NB * NREP * RCAP * 4));
    int* perm_pad  = (int*)(ws + take((size_t)N_NODES * CAP * 4));
    int* deg       = (int*)(ws + take((size_t)N_NODES * 4));
    int* goff      = (int*)(ws + take((size_t)(N_GRAPHS + 4) * 4));
    float* s1      = (float*)(ws + take(F_IN * 4));
    float* t1      = (float*)(ws + take(F_IN * 4));
    float* s2      = (float*)(ws + take(DIM * 4));
    float* t2      = (float*)(ws + take(DIM * 4));
    float* c0      = (float*)(ws + take(DIM * 4));
    float* pb1     = (float*)(ws + take((size_t)GEMM_MB * 2 * F_IN * 4));
    float* pb2     = (float*)(ws + take((size_t)BN2_BLOCKS * 2 * DIM * 4));
    unsigned short* w1h = (unsigned short*)(ws + take((size_t)F_IN * 128 * 2));
    unsigned short* w1l = (unsigned short*)(ws + take((size_t)F_IN * 128 * 2));
    unsigned short* w2h = (unsigned short*)(ws + take((size_t)F_IN * 128 * 2));
    unsigned short* w2l = (unsigned short*)(ws + take((size_t)F_IN * 128 * 2));
    unsigned short* w3h = (unsigned short*)(ws + take((size_t)DIM * 128 * 2));
    unsigned short* w3l = (unsigned short*)(ws + take((size_t)DIM * 128 * 2));
    unsigned short* w4h = (unsigned short*)(ws + take((size_t)DIM * 32 * 2));
    unsigned short* w4l = (unsigned short*)(ws + take((size_t)DIM * 32 * 2));
    __half* x_half = (__half*)(ws + take((size_t)N_NODES * HROW * 2));
    __half* y_half = (__half*)(ws + take((size_t)N_NODES * DIM * 2));
    float* bufA    = (float*)(ws + take((size_t)N_NODES * F_IN * 4));
    float* bufB    = (float*)(ws + take((size_t)N_NODES * F_IN * 4));
    float* bufS1   = (float*)(ws + take((size_t)N_NODES * DIM * 4));
    float* bufS2   = (float*)(ws + take((size_t)N_NODES * DIM * 4));
    (void)ws_size; (void)in_sizes; (void)n_in; (void)out_size;

    hipMemsetAsync(ws, 0, zero_bytes, stream);

    // merged prep: bucket append (NT loads, XCD-replicated) + x->fp16 + weight
    // splits + graph bounds — one launch, bucket blocks dispatched first.
    prep_kernel<<<PB_GB, 256, 0, stream>>>(src, dst, bcur_pad, bucket,
                                           x, x_half,
                                           g1_w1, w1h, w1l, g1_w2, w2h, w2l, g2_w2, w4h, w4l,
                                           batch, goff);
    bin_build<<<NB, 256, 0, stream>>>(bcur_pad, bucket, perm_pad, deg);

    const int AGG_BLOCKS = (N_NODES + 3) / 4;

    // GIN layer 1 (BN1 stats fused into gemm1b epilogue)
    agg_kernel<<<AGG_BLOCKS, 256, 0, stream>>>(x, x_half, deg, perm_pad, bufA, N_NODES);
    gemm_mfma<7, 4, F_IN, true, 0, false><<<GEMM_MB, 256, 0, stream>>>(bufA, w1h, w1l, g1_b1, bufB, nullptr, nullptr, N_NODES);
    gemm_mfma<7, 4, F_IN, true, 0, true><<<GEMM_MB, 256, 0, stream>>>(bufB, w2h, w2l, g1_b2, bufA, nullptr, pb1, N_NODES);
    bn_finalize<F_IN, 782><<<1, 128, 0, stream>>>(pb1, bn1_g, bn1_b, s1, t1, N_NODES);

    // GIN layer 2: linear-first (BN1 folded into W3' and c0), then 32-wide agg
    w3_fold<<<(DIM * 128 + 255) / 256, 256, 0, stream>>>(g2_w1, s1, t1, w3h, w3l, c0);
    gemm_mfma<2, 4, F_IN, false, DIM, false><<<GEMM_MB, 256, 0, stream>>>(bufA, w3h, w3l, nullptr, nullptr, y_half, nullptr, N_NODES);
    agg32_kernel<<<AGG_BLOCKS, 256, 0, stream>>>(y_half, deg, perm_pad, c0, g2_b1, bufS1, N_NODES);
    gemm_mfma<2, 1, DIM, true, 0, false><<<GEMM_MB, 256, 0, stream>>>(bufS1, w4h, w4l, g2_b2, bufS2, nullptr, nullptr, N_NODES);
    bn_stats32<BN2_BLOCKS><<<BN2_BLOCKS, 256, 0, stream>>>(bufS2, N_NODES, pb2);
    bn_finalize<DIM, BN2_BLOCKS><<<1, 64, 0, stream>>>(pb2, bn2_g, bn2_b, s2, t2, N_NODES);

    // pool (BN2 folded) + dense head
    pool_head<<<N_GRAPHS, 256, 0, stream>>>(bufS2, goff, s2, t2,
                                            fcxd_w, fcxd_b, fc1_w, fc1_b, fc2_w, fc2_b,
                                            fc3_w, fc3_b, fc4_w, fc4_b, fc5_w, fc5_b, out);
}

// Round 13
// 310.875 us; speedup vs baseline: 1.3318x; 1.3318x over previous
//
#include <hip/hip_runtime.h>
#include <hip/hip_fp16.h>

#define N_NODES 50000
#define N_EDGES 800000
#define N_GRAPHS 256
#define F_IN 112
#define DIM 32
#define BN_EPS 1e-5
#define PAD 32     // ints per atomic slot: one 128-B line per cursor
#define HROW 128   // fp16 gather-row stride (256 B = exactly 2 lines, zero waste)
#define CAP 64     // edge slots per node (P(deg>63) ~ 1e-19 for Poisson(16))
#define NB 1563    // buckets = ceil(50000/32)
#define NREP 8     // one bucket replica per XCD
#define RCAP 128   // entries per replica-bucket (Poisson(64), 8 sigma headroom)

typedef __attribute__((ext_vector_type(8))) short short8;
typedef __attribute__((ext_vector_type(4))) float float4v;

// ---- bf16 helpers (RNE) ----
__device__ inline unsigned short f2bf(float f) {
    union { float f; unsigned int u; } v; v.f = f;
    unsigned int u = v.u;
    u += 0x7FFFu + ((u >> 16) & 1u);
    return (unsigned short)(u >> 16);
}
__device__ inline float bf2f(unsigned short h) {
    union { unsigned int u; float f; } v; v.u = ((unsigned int)h) << 16;
    return v.f;
}

__device__ inline void w_split_body(const float* __restrict__ W, int K, int N, int Kpad,
                                    unsigned short* __restrict__ hi_t,
                                    unsigned short* __restrict__ lo_t, int idx) {
    if (idx >= N * Kpad) return;
    int n = idx / Kpad, k = idx - n * Kpad;
    float v = (k < K) ? W[(size_t)k * N + n] : 0.f;
    unsigned short h = f2bf(v);
    hi_t[idx] = h;
    lo_t[idx] = f2bf(v - bf2f(h));
}

// ---- merged prep: bucket_append FIRST (long pole), then x->fp16, weight
//      splits, graph bounds. Bucket src/dst reads are non-temporal so the
//      streaming sweep doesn't evict dirty bucket-replica lines from L2.
#define PB_BA 3125                   // 800000/256 bucket-append blocks
#define PB_XH (PB_BA + 12500)        // 50000*64 half2 / 256
#define PB_W1 (PB_XH + 56)
#define PB_W2 (PB_W1 + 56)
#define PB_W4 (PB_W2 + 4)
#define PB_GB (PB_W4 + 196)          // total blocks
__global__ __launch_bounds__(256) void prep_kernel(const int* __restrict__ src, const int* __restrict__ dst,
                                                   int* __restrict__ bcur_pad, int* __restrict__ bucket,
                                                   const float* __restrict__ X, __half* __restrict__ Xh,
                                                   const float* __restrict__ g1_w1, unsigned short* w1h, unsigned short* w1l,
                                                   const float* __restrict__ g1_w2, unsigned short* w2h, unsigned short* w2l,
                                                   const float* __restrict__ g2_w2, unsigned short* w4h, unsigned short* w4l,
                                                   const int* __restrict__ batch, int* __restrict__ goff) {
    int b = blockIdx.x, t = threadIdx.x;
    if (b < PB_BA) {
        unsigned xcc = 0;
        asm volatile("s_getreg_b32 %0, hwreg(HW_REG_XCC_ID)" : "=s"(xcc));
        int r = (int)(xcc & (NREP - 1));
        int i = b * 256 + t;
        if (i < N_EDGES) {
            int d = __builtin_nontemporal_load(dst + i);
            int s = __builtin_nontemporal_load(src + i);
            int bk = d >> 5;
            size_t slot = (size_t)bk * NREP + r;
            int c = atomicAdd(&bcur_pad[slot * PAD], 1);
            if (c < RCAP) bucket[slot * RCAP + c] = ((d & 31) << 16) | s;
        }
    } else if (b < PB_XH) {
        int idx = (b - PB_BA) * 256 + t;             // one half2 per thread
        if (idx >= N_NODES * (HROW / 2)) return;
        int row = idx / (HROW / 2), c2 = idx - row * (HROW / 2);
        int col = c2 * 2;
        float2 v = make_float2(0.f, 0.f);
        if (col < F_IN) v = *(const float2*)(X + (size_t)row * F_IN + col);
        ((__half2*)Xh)[idx] = __floats2half2_rn(v.x, v.y);
    } else if (b < PB_W1) {
        w_split_body(g1_w1, F_IN, F_IN, 128, w1h, w1l, (b - PB_XH) * 256 + t);
    } else if (b < PB_W2) {
        w_split_body(g1_w2, F_IN, F_IN, 128, w2h, w2l, (b - PB_W1) * 256 + t);
    } else if (b < PB_W4) {
        w_split_body(g2_w2, DIM, DIM, 32, w4h, w4l, (b - PB_W2) * 256 + t);
    } else {
        int i = (b - PB_W4) * 256 + t;
        if (i >= N_NODES) return;
        int cur = batch[i];
        int prev = (i == 0) ? -1 : batch[i - 1];
        for (int g = prev + 1; g <= cur; g++) goff[g] = i;
        if (i == N_NODES - 1) {
            for (int g = cur + 1; g <= N_GRAPHS; g++) goff[g] = N_NODES;
        }
    }
}

// ---------------- phase B: per-bucket LDS binning -> coalesced perm/deg write
__global__ __launch_bounds__(256) void bin_build(const int* __restrict__ bcur_pad,
                                                 const int* __restrict__ bucket,
                                                 int* __restrict__ perm_pad,
                                                 int* __restrict__ deg) {
    __shared__ int bins[32][CAP];
    __shared__ int lcur[32];
    int b = blockIdx.x, t = threadIdx.x;
    if (t < 32) lcur[t] = 0;
    __syncthreads();
    for (int r = 0; r < NREP; r++) {
        size_t slot = (size_t)b * NREP + r;
        int count = min(bcur_pad[slot * PAD], RCAP);
        for (int i = t; i < count; i += 256) {
            int e = bucket[slot * RCAP + i];
            int l = e >> 16, s = e & 0xFFFF;
            int c = atomicAdd(&lcur[l], 1);
            if (c < CAP) bins[l][c] = s;
        }
    }
    __syncthreads();
    if (t < 32) {
        int node = b * 32 + t;
        if (node < N_NODES) deg[node] = min(lcur[t], CAP);
    }
    for (int i = t; i < 32 * (CAP / 4); i += 256) {
        int l = i / (CAP / 4), q = i % (CAP / 4);
        int node = b * 32 + l;
        if (node < N_NODES) {
            ((int4*)&perm_pad[(size_t)node * CAP])[q] = ((const int4*)bins[l])[q];
        }
    }
}

// ------------------- layer-1 aggregation (wave per node), fp16 gather
__global__ __launch_bounds__(256) void agg_kernel(const float* __restrict__ X,
                                                  const __half* __restrict__ Xh,
                                                  const int* __restrict__ deg_arr,
                                                  const int* __restrict__ perm_pad,
                                                  float* __restrict__ out, int M) {
    constexpr int P = F_IN / 2;
    int w = (blockIdx.x * 256 + threadIdx.x) >> 6;
    int lane = threadIdx.x & 63;
    if (w >= M) return;
    int deg = deg_arr[w];
    const int* pl = perm_pad + (size_t)w * CAP;
    float ax = 0.f, ay = 0.f;
    int e = 0;
    for (; e + 16 <= deg; e += 16) {
        int s[16];
#pragma unroll
        for (int j = 0; j < 16; j++) s[j] = pl[e + j];
        float2 v[16];
#pragma unroll
        for (int j = 0; j < 16; j++)
            v[j] = __half22float2(*(const __half2*)(Xh + (size_t)s[j] * HROW + 2 * lane));
#pragma unroll
        for (int j = 0; j < 16; j++) { ax += v[j].x; ay += v[j].y; }
    }
    for (; e + 4 <= deg; e += 4) {
        int s0 = pl[e], s1 = pl[e + 1], s2 = pl[e + 2], s3 = pl[e + 3];
        float2 v0 = __half22float2(*(const __half2*)(Xh + (size_t)s0 * HROW + 2 * lane));
        float2 v1 = __half22float2(*(const __half2*)(Xh + (size_t)s1 * HROW + 2 * lane));
        float2 v2 = __half22float2(*(const __half2*)(Xh + (size_t)s2 * HROW + 2 * lane));
        float2 v3 = __half22float2(*(const __half2*)(Xh + (size_t)s3 * HROW + 2 * lane));
        ax += (v0.x + v1.x) + (v2.x + v3.x);
        ay += (v0.y + v1.y) + (v2.y + v3.y);
    }
    for (; e < deg; e++) {
        int s = pl[e];
        float2 v = __half22float2(*(const __half2*)(Xh + (size_t)s * HROW + 2 * lane));
        ax += v.x;
        ay += v.y;
    }
    if (lane < P) {
        float2 self = *(const float2*)(X + (size_t)w * F_IN + 2 * lane);
        *(float2*)(out + (size_t)w * F_IN + 2 * lane) = make_float2(self.x + ax, self.y + ay);
    }
}

// ---------- layer-2 aggregation on 32-wide fp16 y rows (quarter-wave/edge)
__global__ __launch_bounds__(256) void agg32_kernel(const __half* __restrict__ Y,
                                                    const int* __restrict__ deg_arr,
                                                    const int* __restrict__ perm_pad,
                                                    const float* __restrict__ c0,
                                                    const float* __restrict__ b1,
                                                    float* __restrict__ out, int M) {
    int w = (blockIdx.x * 256 + threadIdx.x) >> 6;
    int lane = threadIdx.x & 63;
    if (w >= M) return;
    int f = lane & 15;
    int g = lane >> 4;
    int deg = deg_arr[w];
    const int* pl = perm_pad + (size_t)w * CAP;
    float ax = 0.f, ay = 0.f;
    int e = g;
    for (; e + 4 < deg; e += 8) {
        int s0 = pl[e], s1 = pl[e + 4];
        float2 v0 = __half22float2(*(const __half2*)(Y + (size_t)s0 * DIM + 2 * f));
        float2 v1 = __half22float2(*(const __half2*)(Y + (size_t)s1 * DIM + 2 * f));
        ax += v0.x + v1.x;
        ay += v0.y + v1.y;
    }
    if (e < deg) {
        int s0 = pl[e];
        float2 v0 = __half22float2(*(const __half2*)(Y + (size_t)s0 * DIM + 2 * f));
        ax += v0.x;
        ay += v0.y;
    }
    ax += __shfl_xor(ax, 16); ax += __shfl_xor(ax, 32);
    ay += __shfl_xor(ay, 16); ay += __shfl_xor(ay, 32);
    if (g == 0) {
        float2 self = __half22float2(*(const __half2*)(Y + (size_t)w * DIM + 2 * f));
        float deg1 = (float)(deg + 1);
        float zx = self.x + ax + deg1 * c0[2 * f] + b1[2 * f];
        float zy = self.y + ay + deg1 * c0[2 * f + 1] + b1[2 * f + 1];
        *(float2*)(out + (size_t)w * DIM + 2 * f) = make_float2(fmaxf(zx, 0.f), fmaxf(zy, 0.f));
    }
}

// ------- BN1-folded W3 split: W3'[k][n] = s1[k]*W3[k][n]; c0[n] = sum t1[k]W3[k][n]
__global__ __launch_bounds__(256) void w3_fold(const float* __restrict__ W,   // [112][32]
                                               const float* __restrict__ s1,
                                               const float* __restrict__ t1,
                                               unsigned short* __restrict__ hi_t,  // [32][128]
                                               unsigned short* __restrict__ lo_t,
                                               float* __restrict__ c0) {
    int idx = blockIdx.x * 256 + threadIdx.x;
    if (idx < DIM * 128) {
        int n = idx >> 7, k = idx & 127;
        float v = (k < F_IN) ? s1[k] * W[(size_t)k * DIM + n] : 0.f;
        unsigned short h = f2bf(v);
        hi_t[idx] = h;
        lo_t[idx] = f2bf(v - bf2f(h));
    }
    if (blockIdx.x == 0 && threadIdx.x < DIM) {
        int n = threadIdx.x;
        float acc = 0.f;
        for (int k = 0; k < F_IN; k++) acc += t1[k] * W[(size_t)k * DIM + n];
        c0[n] = acc;
    }
}

// ------------------------- split-bf16 MFMA GEMM: C = act(A @ W + bias)
// STATS: fuse per-block BN partial sums (sum, sumsq per column) into epilogue.
template <int NT, int KC, int K, bool RELU, int CHS, bool STATS>
__global__ __launch_bounds__(256) void gemm_mfma(const float* __restrict__ A,
                                                 const unsigned short* __restrict__ Whi,
                                                 const unsigned short* __restrict__ Wlo,
                                                 const float* __restrict__ bias,
                                                 float* __restrict__ C,
                                                 __half* __restrict__ Ch,
                                                 float* __restrict__ pbuf, int M) {
    constexpr int N = NT * 16;
    constexpr int Kpad = KC * 32;
    __shared__ __align__(16) unsigned short Ah[64 * 32];
    __shared__ __align__(16) unsigned short Al[64 * 32];
    __shared__ __align__(16) unsigned short Wh[N * 32];
    __shared__ __align__(16) unsigned short Wl[N * 32];
    int t = threadIdx.x;
    int lane = t & 63, wid = t >> 6;
    int r0 = blockIdx.x * 64;
    int m = lane & 15, quad = lane >> 4;

    float4v acc[NT];
#pragma unroll
    for (int nt = 0; nt < NT; nt++) acc[nt] = (float4v){0.f, 0.f, 0.f, 0.f};

    for (int c = 0; c < KC; c++) {
        int kc = c * 32;
#pragma unroll
        for (int i = 0; i < 2; i++) {
            int idx = t + i * 256;
            int row = idx >> 3, c4 = idx & 7;
            int col = kc + c4 * 4;
            int grow = r0 + row;
            float4 v = make_float4(0.f, 0.f, 0.f, 0.f);
            if (grow < M) {
                if (col + 3 < K) {
                    v = *(const float4*)(A + (size_t)grow * K + col);
                } else {
                    float tmp[4] = {0.f, 0.f, 0.f, 0.f};
                    for (int j = 0; j < 4; j++) if (col + j < K) tmp[j] = A[(size_t)grow * K + col + j];
                    v = make_float4(tmp[0], tmp[1], tmp[2], tmp[3]);
                }
            }
            unsigned short h0 = f2bf(v.x), h1 = f2bf(v.y), h2 = f2bf(v.z), h3 = f2bf(v.w);
            unsigned short l0 = f2bf(v.x - bf2f(h0)), l1 = f2bf(v.y - bf2f(h1));
            unsigned short l2 = f2bf(v.z - bf2f(h2)), l3 = f2bf(v.w - bf2f(h3));
            int o = row * 32 + c4 * 4;
            *(uint2*)&Ah[o] = make_uint2((unsigned)h0 | ((unsigned)h1 << 16), (unsigned)h2 | ((unsigned)h3 << 16));
            *(uint2*)&Al[o] = make_uint2((unsigned)l0 | ((unsigned)l1 << 16), (unsigned)l2 | ((unsigned)l3 << 16));
        }
        for (int idx = t; idx < N * 8; idx += 256) {
            int n = idx >> 3, w = idx & 7;
            int gsrc = n * (Kpad / 4) + (kc >> 2) + w;
            ((uint2*)Wh)[idx] = ((const uint2*)Whi)[gsrc];
            ((uint2*)Wl)[idx] = ((const uint2*)Wlo)[gsrc];
        }
        __syncthreads();
        short8 a_h = *(const short8*)&Ah[(wid * 16 + m) * 32 + quad * 8];
        short8 a_l = *(const short8*)&Al[(wid * 16 + m) * 32 + quad * 8];
#pragma unroll
        for (int nt = 0; nt < NT; nt++) {
            short8 b_h = *(const short8*)&Wh[(nt * 16 + m) * 32 + quad * 8];
            short8 b_l = *(const short8*)&Wl[(nt * 16 + m) * 32 + quad * 8];
            acc[nt] = __builtin_amdgcn_mfma_f32_16x16x32_bf16(a_h, b_h, acc[nt], 0, 0, 0);
            acc[nt] = __builtin_amdgcn_mfma_f32_16x16x32_bf16(a_h, b_l, acc[nt], 0, 0, 0);
            acc[nt] = __builtin_amdgcn_mfma_f32_16x16x32_bf16(a_l, b_h, acc[nt], 0, 0, 0);
        }
        __syncthreads();
    }
    float st_s[NT], st_q[NT];
#pragma unroll
    for (int nt = 0; nt < NT; nt++) {
        int col = nt * 16 + m;
        float b = bias ? bias[col] : 0.f;
        float s_loc = 0.f, q_loc = 0.f;
#pragma unroll
        for (int r = 0; r < 4; r++) {
            int row = r0 + wid * 16 + quad * 4 + r;
            float v = acc[nt][r] + b;
            if (RELU) v = fmaxf(v, 0.f);
            if (row < M) {
                if (C) C[(size_t)row * N + col] = v;
                if (Ch) Ch[(size_t)row * CHS + col] = __float2half(v);
                if (STATS) { s_loc += v; q_loc += v * v; }
            }
        }
        st_s[nt] = s_loc;
        st_q[nt] = q_loc;
    }
    if constexpr (STATS) {
        __shared__ float sls[4][2 * N];
#pragma unroll
        for (int nt = 0; nt < NT; nt++) {
            float s = st_s[nt], q = st_q[nt];
            s += __shfl_xor(s, 16); s += __shfl_xor(s, 32);
            q += __shfl_xor(q, 16); q += __shfl_xor(q, 32);
            if (quad == 0) {
                sls[wid][nt * 16 + m] = s;
                sls[wid][N + nt * 16 + m] = q;
            }
        }
        __syncthreads();
        for (int j = t; j < 2 * N; j += 256) {
            pbuf[(size_t)blockIdx.x * 2 * N + j] = sls[0][j] + sls[1][j] + sls[2][j] + sls[3][j];
        }
    }
}

// ----------------------------------- BN stats (layer 2 only, 32-wide)
template <int BLOCKS>
__global__ __launch_bounds__(256) void bn_stats32(const float* __restrict__ H, int M,
                                                  float* __restrict__ pbuf) {
    __shared__ float ls[8][64];
    int t = threadIdx.x;
    int col = t & 31, rg = t >> 5;
    float s = 0.f, q = 0.f;
    for (int r = blockIdx.x * 8 + rg; r < M; r += BLOCKS * 8) {
        float v = H[(size_t)r * 32 + col];
        s += v; q += v * v;
    }
    ls[rg][col] = s;
    ls[rg][32 + col] = q;
    __syncthreads();
    if (t < 64) {
        float a = 0.f;
        for (int i = 0; i < 8; i++) a += ls[i][t];
        pbuf[(size_t)blockIdx.x * 64 + t] = a;
    }
}

// --------- parallel BN finalize: one block per feature, 256-thread reduce
template <int F, int BLOCKS>
__global__ __launch_bounds__(256) void bn_finalize_par(const float* __restrict__ pbuf,
                                                       const float* __restrict__ g,
                                                       const float* __restrict__ b,
                                                       float* __restrict__ s,
                                                       float* __restrict__ tt, int M) {
    __shared__ double red[256];
    int j = blockIdx.x;      // feature index
    int t = threadIdx.x;
    double sum = 0.0, sq = 0.0;
    for (int i = t; i < BLOCKS; i += 256) {
        sum += (double)pbuf[(size_t)i * 2 * F + j];
        sq  += (double)pbuf[(size_t)i * 2 * F + F + j];
    }
    red[t] = sum;
    __syncthreads();
    for (int o = 128; o > 0; o >>= 1) { if (t < o) red[t] += red[t + o]; __syncthreads(); }
    double total_sum = red[0];
    __syncthreads();
    red[t] = sq;
    __syncthreads();
    for (int o = 128; o > 0; o >>= 1) { if (t < o) red[t] += red[t + o]; __syncthreads(); }
    if (t == 0) {
        double mean = total_sum / M;
        double var = red[0] / M - mean * mean;
        double sc = (double)g[j] / sqrt(var + BN_EPS);
        s[j] = (float)sc;
        tt[j] = (float)((double)b[j] - mean * sc);
    }
}

// -------------------------------------------- pool (BN2 folded) + head
__global__ __launch_bounds__(256) void pool_head(const float* __restrict__ H2, const int* __restrict__ goff,
                                                 const float* __restrict__ s2, const float* __restrict__ t2,
                                                 const float* __restrict__ fcxd_w, const float* __restrict__ fcxd_b,
                                                 const float* __restrict__ fc1_w, const float* __restrict__ fc1_b,
                                                 const float* __restrict__ fc2_w, const float* __restrict__ fc2_b,
                                                 const float* __restrict__ fc3_w, const float* __restrict__ fc3_b,
                                                 const float* __restrict__ fc4_w, const float* __restrict__ fc4_b,
                                                 const float* __restrict__ fc5_w, const float* __restrict__ fc5_b,
                                                 float* __restrict__ out) {
    __shared__ float red[256];
    __shared__ float p[64];
    __shared__ float z[64];
    int g = blockIdx.x, t = threadIdx.x;
    int r0 = goff[g], r1 = goff[g + 1];
    int cnt = r1 - r0;
    int j = t & 31, rr = t >> 5;
    float a = 0.f;
    for (int r = r0 + rr; r < r1; r += 8) a += H2[(size_t)r * DIM + j];
    red[t] = a;
    __syncthreads();
    if (t < 32) {
        float ssum = 0.f;
        for (int q = 0; q < 8; q++) ssum += red[q * 32 + j];
        p[j] = s2[j] * ssum + (float)cnt * t2[j];
    }
    __syncthreads();
    if (t < 64) {
        float acc = fcxd_b[t];
        for (int i = 0; i < 32; i++) acc += p[i] * fcxd_w[i * 64 + t];
        z[t] = fmaxf(acc, 0.f);
    }
    __syncthreads();
    if (t < 32) {
        float acc = fc1_b[t];
        for (int i = 0; i < 64; i++) acc += z[i] * fc1_w[i * 32 + t];
        p[t] = acc;
    }
    __syncthreads();
    if (t < 16) {
        float acc = fc2_b[t];
        for (int i = 0; i < 32; i++) acc += p[i] * fc2_w[i * 16 + t];
        z[t] = acc;
    }
    __syncthreads();
    if (t < 8) {
        float acc = fc3_b[t];
        for (int i = 0; i < 16; i++) acc += z[i] * fc3_w[i * 8 + t];
        p[t] = acc;
    }
    __syncthreads();
    if (t < 2) {
        float acc = fc4_b[t];
        for (int i = 0; i < 8; i++) acc += p[i] * fc4_w[i * 2 + t];
        z[t] = acc;
    }
    __syncthreads();
    if (t == 0) {
        out[g] = z[0] * fc5_w[0] + z[1] * fc5_w[1] + fc5_b[0];
    }
}

// ---------------------------------------------------------------- launch
extern "C" void kernel_launch(void* const* d_in, const int* in_sizes, int n_in,
                              void* d_out, int out_size, void* d_ws, size_t ws_size,
                              hipStream_t stream) {
    const float* x     = (const float*)d_in[0];
    const int*   src   = (const int*)d_in[1];
    const int*   dst   = (const int*)d_in[2];
    const int*   batch = (const int*)d_in[3];
    const float* g1_w1 = (const float*)d_in[4];
    const float* g1_b1 = (const float*)d_in[5];
    const float* g1_w2 = (const float*)d_in[6];
    const float* g1_b2 = (const float*)d_in[7];
    const float* bn1_g = (const float*)d_in[8];
    const float* bn1_b = (const float*)d_in[9];
    const float* g2_w1 = (const float*)d_in[10];
    const float* g2_b1 = (const float*)d_in[11];
    const float* g2_w2 = (const float*)d_in[12];
    const float* g2_b2 = (const float*)d_in[13];
    const float* bn2_g = (const float*)d_in[14];
    const float* bn2_b = (const float*)d_in[15];
    const float* fcxd_w = (const float*)d_in[16];
    const float* fcxd_b = (const float*)d_in[17];
    const float* fc1_w = (const float*)d_in[18];
    const float* fc1_b = (const float*)d_in[19];
    const float* fc2_w = (const float*)d_in[20];
    const float* fc2_b = (const float*)d_in[21];
    const float* fc3_w = (const float*)d_in[22];
    const float* fc3_b = (const float*)d_in[23];
    const float* fc4_w = (const float*)d_in[24];
    const float* fc4_b = (const float*)d_in[25];
    const float* fc5_w = (const float*)d_in[26];
    const float* fc5_b = (const float*)d_in[27];
    float* out = (float*)d_out;
    char* ws = (char*)d_ws;

    const int GEMM_MB = (N_NODES + 63) / 64;       // 782 (also BN1 partial blocks)
    constexpr int BN2_BLOCKS = 128;

    size_t off = 0;
    auto take = [&](size_t bytes) { size_t o = off; off += (bytes + 255) & ~(size_t)255; return o; };
    int* bcur_pad  = (int*)(ws + take((size_t)NB * NREP * PAD * 4));    // zeroed (1.6 MB)
    size_t zero_bytes = off;
    int* bucket    = (int*)(ws + take((size_t)NB * NREP * RCAP * 4));
    int* perm_pad  = (int*)(ws + take((size_t)N_NODES * CAP * 4));
    int* deg       = (int*)(ws + take((size_t)N_NODES * 4));
    int* goff      = (int*)(ws + take((size_t)(N_GRAPHS + 4) * 4));
    float* s1      = (float*)(ws + take(F_IN * 4));
    float* t1      = (float*)(ws + take(F_IN * 4));
    float* s2      = (float*)(ws + take(DIM * 4));
    float* t2      = (float*)(ws + take(DIM * 4));
    float* c0      = (float*)(ws + take(DIM * 4));
    float* pb1     = (float*)(ws + take((size_t)GEMM_MB * 2 * F_IN * 4));
    float* pb2     = (float*)(ws + take((size_t)BN2_BLOCKS * 2 * DIM * 4));
    unsigned short* w1h = (unsigned short*)(ws + take((size_t)F_IN * 128 * 2));
    unsigned short* w1l = (unsigned short*)(ws + take((size_t)F_IN * 128 * 2));
    unsigned short* w2h = (unsigned short*)(ws + take((size_t)F_IN * 128 * 2));
    unsigned short* w2l = (unsigned short*)(ws + take((size_t)F_IN * 128 * 2));
    unsigned short* w3h = (unsigned short*)(ws + take((size_t)DIM * 128 * 2));
    unsigned short* w3l = (unsigned short*)(ws + take((size_t)DIM * 128 * 2));
    unsigned short* w4h = (unsigned short*)(ws + take((size_t)DIM * 32 * 2));
    unsigned short* w4l = (unsigned short*)(ws + take((size_t)DIM * 32 * 2));
    __half* x_half = (__half*)(ws + take((size_t)N_NODES * HROW * 2));
    __half* y_half = (__half*)(ws + take((size_t)N_NODES * DIM * 2));
    float* bufA    = (float*)(ws + take((size_t)N_NODES * F_IN * 4));
    float* bufB    = (float*)(ws + take((size_t)N_NODES * F_IN * 4));
    float* bufS1   = (float*)(ws + take((size_t)N_NODES * DIM * 4));
    float* bufS2   = (float*)(ws + take((size_t)N_NODES * DIM * 4));
    (void)ws_size; (void)in_sizes; (void)n_in; (void)out_size;

    hipMemsetAsync(ws, 0, zero_bytes, stream);

    // merged prep: bucket append (NT loads, XCD-replicated) + x->fp16 + weight
    // splits + graph bounds — one launch, bucket blocks dispatched first.
    prep_kernel<<<PB_GB, 256, 0, stream>>>(src, dst, bcur_pad, bucket,
                                           x, x_half,
                                           g1_w1, w1h, w1l, g1_w2, w2h, w2l, g2_w2, w4h, w4l,
                                           batch, goff);
    bin_build<<<NB, 256, 0, stream>>>(bcur_pad, bucket, perm_pad, deg);

    const int AGG_BLOCKS = (N_NODES + 3) / 4;

    // GIN layer 1 (BN1 stats fused into gemm1b epilogue; parallel finalize)
    agg_kernel<<<AGG_BLOCKS, 256, 0, stream>>>(x, x_half, deg, perm_pad, bufA, N_NODES);
    gemm_mfma<7, 4, F_IN, true, 0, false><<<GEMM_MB, 256, 0, stream>>>(bufA, w1h, w1l, g1_b1, bufB, nullptr, nullptr, N_NODES);
    gemm_mfma<7, 4, F_IN, true, 0, true><<<GEMM_MB, 256, 0, stream>>>(bufB, w2h, w2l, g1_b2, bufA, nullptr, pb1, N_NODES);
    bn_finalize_par<F_IN, 782><<<F_IN, 256, 0, stream>>>(pb1, bn1_g, bn1_b, s1, t1, N_NODES);

    // GIN layer 2: linear-first (BN1 folded into W3' and c0), then 32-wide agg
    w3_fold<<<(DIM * 128 + 255) / 256, 256, 0, stream>>>(g2_w1, s1, t1, w3h, w3l, c0);
    gemm_mfma<2, 4, F_IN, false, DIM, false><<<GEMM_MB, 256, 0, stream>>>(bufA, w3h, w3l, nullptr, nullptr, y_half, nullptr, N_NODES);
    agg32_kernel<<<AGG_BLOCKS, 256, 0, stream>>>(y_half, deg, perm_pad, c0, g2_b1, bufS1, N_NODES);
    gemm_mfma<2, 1, DIM, true, 0, false><<<GEMM_MB, 256, 0, stream>>>(bufS1, w4h, w4l, g2_b2, bufS2, nullptr, nullptr, N_NODES);
    bn_stats32<BN2_BLOCKS><<<BN2_BLOCKS, 256, 0, stream>>>(bufS2, N_NODES, pb2);
    bn_finalize_par<DIM, BN2_BLOCKS><<<DIM, 256, 0, stream>>>(pb2, bn2_g, bn2_b, s2, t2, N_NODES);

    // pool (BN2 folded) + dense head
    pool_head<<<N_GRAPHS, 256, 0, stream>>>(bufS2, goff, s2, t2,
                                            fcxd_w, fcxd_b, fc1_w, fc1_b, fc2_w, fc2_b,
                                            fc3_w, fc3_b, fc4_w, fc4_b, fc5_w, fc5_b, out);
}

// Round 14
// 306.023 us; speedup vs baseline: 1.3529x; 1.0159x over previous
//
#include <hip/hip_runtime.h>
#include <hip/hip_fp16.h>

#define N_NODES 50000
#define N_EDGES 800000
#define N_GRAPHS 256
#define F_IN 112
#define DIM 32
#define BN_EPS 1e-5
#define PAD 32     // ints per atomic slot: one 128-B line per cursor
#define HROW 128   // fp16 gather-row stride (256 B = exactly 2 lines, zero waste)
#define CAP 64     // edge slots per node (P(deg>63) ~ 1e-19 for Poisson(16))
#define NB 1563    // buckets = ceil(50000/32)
#define NREP 8     // one bucket replica per XCD
#define RCAP 128   // entries per replica-bucket (Poisson(64), 8 sigma headroom)

typedef __attribute__((ext_vector_type(8))) short short8;
typedef __attribute__((ext_vector_type(4))) float float4v;

// ---- bf16 helpers (RNE) ----
__device__ inline unsigned short f2bf(float f) {
    union { float f; unsigned int u; } v; v.f = f;
    unsigned int u = v.u;
    u += 0x7FFFu + ((u >> 16) & 1u);
    return (unsigned short)(u >> 16);
}
__device__ inline float bf2f(unsigned short h) {
    union { unsigned int u; float f; } v; v.u = ((unsigned int)h) << 16;
    return v.f;
}

__device__ inline void w_split_body(const float* __restrict__ W, int K, int N, int Kpad,
                                    unsigned short* __restrict__ hi_t,
                                    unsigned short* __restrict__ lo_t, int idx) {
    if (idx >= N * Kpad) return;
    int n = idx / Kpad, k = idx - n * Kpad;
    float v = (k < K) ? W[(size_t)k * N + n] : 0.f;
    unsigned short h = f2bf(v);
    hi_t[idx] = h;
    lo_t[idx] = f2bf(v - bf2f(h));
}

// ---- merged prep: bucket_append FIRST (long pole), then x->fp16, weight
//      splits, graph bounds.
#define PB_BA 3125                   // 800000/256 bucket-append blocks
#define PB_XH (PB_BA + 12500)        // 50000*64 half2 / 256
#define PB_W1 (PB_XH + 56)
#define PB_W2 (PB_W1 + 56)
#define PB_W4 (PB_W2 + 4)
#define PB_GB (PB_W4 + 196)          // total blocks
__global__ __launch_bounds__(256) void prep_kernel(const int* __restrict__ src, const int* __restrict__ dst,
                                                   int* __restrict__ bcur_pad, int* __restrict__ bucket,
                                                   const float* __restrict__ X, __half* __restrict__ Xh,
                                                   const float* __restrict__ g1_w1, unsigned short* w1h, unsigned short* w1l,
                                                   const float* __restrict__ g1_w2, unsigned short* w2h, unsigned short* w2l,
                                                   const float* __restrict__ g2_w2, unsigned short* w4h, unsigned short* w4l,
                                                   const int* __restrict__ batch, int* __restrict__ goff) {
    int b = blockIdx.x, t = threadIdx.x;
    if (b < PB_BA) {
        unsigned xcc = 0;
        asm volatile("s_getreg_b32 %0, hwreg(HW_REG_XCC_ID)" : "=s"(xcc));
        int r = (int)(xcc & (NREP - 1));
        int i = b * 256 + t;
        if (i < N_EDGES) {
            int d = __builtin_nontemporal_load(dst + i);
            int s = __builtin_nontemporal_load(src + i);
            int bk = d >> 5;
            size_t slot = (size_t)bk * NREP + r;
            int c = atomicAdd(&bcur_pad[slot * PAD], 1);
            if (c < RCAP) bucket[slot * RCAP + c] = ((d & 31) << 16) | s;
        }
    } else if (b < PB_XH) {
        int idx = (b - PB_BA) * 256 + t;             // one half2 per thread
        if (idx >= N_NODES * (HROW / 2)) return;
        int row = idx / (HROW / 2), c2 = idx - row * (HROW / 2);
        int col = c2 * 2;
        float2 v = make_float2(0.f, 0.f);
        if (col < F_IN) v = *(const float2*)(X + (size_t)row * F_IN + col);
        ((__half2*)Xh)[idx] = __floats2half2_rn(v.x, v.y);
    } else if (b < PB_W1) {
        w_split_body(g1_w1, F_IN, F_IN, 128, w1h, w1l, (b - PB_XH) * 256 + t);
    } else if (b < PB_W2) {
        w_split_body(g1_w2, F_IN, F_IN, 128, w2h, w2l, (b - PB_W1) * 256 + t);
    } else if (b < PB_W4) {
        w_split_body(g2_w2, DIM, DIM, 32, w4h, w4l, (b - PB_W2) * 256 + t);
    } else {
        int i = (b - PB_W4) * 256 + t;
        if (i >= N_NODES) return;
        int cur = batch[i];
        int prev = (i == 0) ? -1 : batch[i - 1];
        for (int g = prev + 1; g <= cur; g++) goff[g] = i;
        if (i == N_NODES - 1) {
            for (int g = cur + 1; g <= N_GRAPHS; g++) goff[g] = N_NODES;
        }
    }
}

// ---------------- phase B: per-bucket LDS binning -> coalesced perm/deg write
__global__ __launch_bounds__(256) void bin_build(const int* __restrict__ bcur_pad,
                                                 const int* __restrict__ bucket,
                                                 int* __restrict__ perm_pad,
                                                 int* __restrict__ deg) {
    __shared__ int bins[32][CAP];
    __shared__ int lcur[32];
    int b = blockIdx.x, t = threadIdx.x;
    if (t < 32) lcur[t] = 0;
    __syncthreads();
    for (int r = 0; r < NREP; r++) {
        size_t slot = (size_t)b * NREP + r;
        int count = min(bcur_pad[slot * PAD], RCAP);
        for (int i = t; i < count; i += 256) {
            int e = bucket[slot * RCAP + i];
            int l = e >> 16, s = e & 0xFFFF;
            int c = atomicAdd(&lcur[l], 1);
            if (c < CAP) bins[l][c] = s;
        }
    }
    __syncthreads();
    if (t < 32) {
        int node = b * 32 + t;
        if (node < N_NODES) deg[node] = min(lcur[t], CAP);
    }
    for (int i = t; i < 32 * (CAP / 4); i += 256) {
        int l = i / (CAP / 4), q = i % (CAP / 4);
        int node = b * 32 + l;
        if (node < N_NODES) {
            ((int4*)&perm_pad[(size_t)node * CAP])[q] = ((const int4*)bins[l])[q];
        }
    }
}

// ------------------- layer-1 aggregation (wave per node), fp16 gather
__global__ __launch_bounds__(256) void agg_kernel(const float* __restrict__ X,
                                                  const __half* __restrict__ Xh,
                                                  const int* __restrict__ deg_arr,
                                                  const int* __restrict__ perm_pad,
                                                  float* __restrict__ out, int M) {
    constexpr int P = F_IN / 2;
    int w = (blockIdx.x * 256 + threadIdx.x) >> 6;
    int lane = threadIdx.x & 63;
    if (w >= M) return;
    int deg = deg_arr[w];
    const int* pl = perm_pad + (size_t)w * CAP;
    float ax = 0.f, ay = 0.f;
    int e = 0;
    for (; e + 16 <= deg; e += 16) {
        int s[16];
#pragma unroll
        for (int j = 0; j < 16; j++) s[j] = pl[e + j];
        float2 v[16];
#pragma unroll
        for (int j = 0; j < 16; j++)
            v[j] = __half22float2(*(const __half2*)(Xh + (size_t)s[j] * HROW + 2 * lane));
#pragma unroll
        for (int j = 0; j < 16; j++) { ax += v[j].x; ay += v[j].y; }
    }
    for (; e + 4 <= deg; e += 4) {
        int s0 = pl[e], s1 = pl[e + 1], s2 = pl[e + 2], s3 = pl[e + 3];
        float2 v0 = __half22float2(*(const __half2*)(Xh + (size_t)s0 * HROW + 2 * lane));
        float2 v1 = __half22float2(*(const __half2*)(Xh + (size_t)s1 * HROW + 2 * lane));
        float2 v2 = __half22float2(*(const __half2*)(Xh + (size_t)s2 * HROW + 2 * lane));
        float2 v3 = __half22float2(*(const __half2*)(Xh + (size_t)s3 * HROW + 2 * lane));
        ax += (v0.x + v1.x) + (v2.x + v3.x);
        ay += (v0.y + v1.y) + (v2.y + v3.y);
    }
    for (; e < deg; e++) {
        int s = pl[e];
        float2 v = __half22float2(*(const __half2*)(Xh + (size_t)s * HROW + 2 * lane));
        ax += v.x;
        ay += v.y;
    }
    if (lane < P) {
        float2 self = *(const float2*)(X + (size_t)w * F_IN + 2 * lane);
        *(float2*)(out + (size_t)w * F_IN + 2 * lane) = make_float2(self.x + ax, self.y + ay);
    }
}

// ---------- layer-2 aggregation on 32-wide fp16 y rows (quarter-wave/edge)
__global__ __launch_bounds__(256) void agg32_kernel(const __half* __restrict__ Y,
                                                    const int* __restrict__ deg_arr,
                                                    const int* __restrict__ perm_pad,
                                                    const float* __restrict__ c0,
                                                    const float* __restrict__ b1,
                                                    float* __restrict__ out, int M) {
    int w = (blockIdx.x * 256 + threadIdx.x) >> 6;
    int lane = threadIdx.x & 63;
    if (w >= M) return;
    int f = lane & 15;
    int g = lane >> 4;
    int deg = deg_arr[w];
    const int* pl = perm_pad + (size_t)w * CAP;
    float ax = 0.f, ay = 0.f;
    int e = g;
    for (; e + 4 < deg; e += 8) {
        int s0 = pl[e], s1 = pl[e + 4];
        float2 v0 = __half22float2(*(const __half2*)(Y + (size_t)s0 * DIM + 2 * f));
        float2 v1 = __half22float2(*(const __half2*)(Y + (size_t)s1 * DIM + 2 * f));
        ax += v0.x + v1.x;
        ay += v0.y + v1.y;
    }
    if (e < deg) {
        int s0 = pl[e];
        float2 v0 = __half22float2(*(const __half2*)(Y + (size_t)s0 * DIM + 2 * f));
        ax += v0.x;
        ay += v0.y;
    }
    ax += __shfl_xor(ax, 16); ax += __shfl_xor(ax, 32);
    ay += __shfl_xor(ay, 16); ay += __shfl_xor(ay, 32);
    if (g == 0) {
        float2 self = __half22float2(*(const __half2*)(Y + (size_t)w * DIM + 2 * f));
        float deg1 = (float)(deg + 1);
        float zx = self.x + ax + deg1 * c0[2 * f] + b1[2 * f];
        float zy = self.y + ay + deg1 * c0[2 * f + 1] + b1[2 * f + 1];
        *(float2*)(out + (size_t)w * DIM + 2 * f) = make_float2(fmaxf(zx, 0.f), fmaxf(zy, 0.f));
    }
}

// ------- BN1-folded W3 split: W3'[k][n] = s1[k]*W3[k][n]; c0[n] = sum t1[k]W3[k][n]
__global__ __launch_bounds__(256) void w3_fold(const float* __restrict__ W,   // [112][32]
                                               const float* __restrict__ s1,
                                               const float* __restrict__ t1,
                                               unsigned short* __restrict__ hi_t,  // [32][128]
                                               unsigned short* __restrict__ lo_t,
                                               float* __restrict__ c0) {
    int idx = blockIdx.x * 256 + threadIdx.x;
    if (idx < DIM * 128) {
        int n = idx >> 7, k = idx & 127;
        float v = (k < F_IN) ? s1[k] * W[(size_t)k * DIM + n] : 0.f;
        unsigned short h = f2bf(v);
        hi_t[idx] = h;
        lo_t[idx] = f2bf(v - bf2f(h));
    }
    if (blockIdx.x == 0 && threadIdx.x < DIM) {
        int n = threadIdx.x;
        float acc = 0.f;
        for (int k = 0; k < F_IN; k++) acc += t1[k] * W[(size_t)k * DIM + n];
        c0[n] = acc;
    }
}

// ------------- FUSED layer-1 MLP: C = relu(relu(A@W1+b1)@W2+b2), + BN1 stats
// Intermediate tile (64x112) lives in LDS as split-bf16; never touches HBM.
__global__ __launch_bounds__(256) void gemm_mlp112(const float* __restrict__ A,
                                                   const unsigned short* __restrict__ W1h,
                                                   const unsigned short* __restrict__ W1l,
                                                   const float* __restrict__ b1,
                                                   const unsigned short* __restrict__ W2h,
                                                   const unsigned short* __restrict__ W2l,
                                                   const float* __restrict__ b2,
                                                   float* __restrict__ C,
                                                   float* __restrict__ pbuf, int M) {
    constexpr int NT = 7, N = 112, K = 112, Kpad = 128, TS = 136;
    __shared__ __align__(16) unsigned short Ah[64 * 32];
    __shared__ __align__(16) unsigned short Al[64 * 32];
    __shared__ __align__(16) unsigned short Wh[N * 32];
    __shared__ __align__(16) unsigned short Wl[N * 32];
    __shared__ __align__(16) unsigned short T1h[64 * TS];
    __shared__ __align__(16) unsigned short T1l[64 * TS];
    int t = threadIdx.x;
    int lane = t & 63, wid = t >> 6;
    int r0 = blockIdx.x * 64;
    int m = lane & 15, quad = lane >> 4;

    // zero the k in [112,128) pad region of T1 (MFMA would NaN-poison on garbage)
    for (int i = t; i < 64 * 16; i += 256) {
        int r = i >> 4, k = 112 + (i & 15);
        T1h[r * TS + k] = 0;
        T1l[r * TS + k] = 0;
    }

    float4v acc[NT];
#pragma unroll
    for (int nt = 0; nt < NT; nt++) acc[nt] = (float4v){0.f, 0.f, 0.f, 0.f};

    // ---- phase 1: acc = A @ W1 ----
    for (int c = 0; c < 4; c++) {
        int kc = c * 32;
#pragma unroll
        for (int i = 0; i < 2; i++) {
            int idx = t + i * 256;
            int row = idx >> 3, c4 = idx & 7;
            int col = kc + c4 * 4;
            int grow = r0 + row;
            float4 v = make_float4(0.f, 0.f, 0.f, 0.f);
            if (grow < M) {
                if (col + 3 < K) {
                    v = *(const float4*)(A + (size_t)grow * K + col);
                } else {
                    float tmp[4] = {0.f, 0.f, 0.f, 0.f};
                    for (int j = 0; j < 4; j++) if (col + j < K) tmp[j] = A[(size_t)grow * K + col + j];
                    v = make_float4(tmp[0], tmp[1], tmp[2], tmp[3]);
                }
            }
            unsigned short h0 = f2bf(v.x), h1 = f2bf(v.y), h2 = f2bf(v.z), h3 = f2bf(v.w);
            unsigned short l0 = f2bf(v.x - bf2f(h0)), l1 = f2bf(v.y - bf2f(h1));
            unsigned short l2 = f2bf(v.z - bf2f(h2)), l3 = f2bf(v.w - bf2f(h3));
            int o = row * 32 + c4 * 4;
            *(uint2*)&Ah[o] = make_uint2((unsigned)h0 | ((unsigned)h1 << 16), (unsigned)h2 | ((unsigned)h3 << 16));
            *(uint2*)&Al[o] = make_uint2((unsigned)l0 | ((unsigned)l1 << 16), (unsigned)l2 | ((unsigned)l3 << 16));
        }
        for (int idx = t; idx < N * 8; idx += 256) {
            int n = idx >> 3, w = idx & 7;
            int gsrc = n * (Kpad / 4) + (kc >> 2) + w;
            ((uint2*)Wh)[idx] = ((const uint2*)W1h)[gsrc];
            ((uint2*)Wl)[idx] = ((const uint2*)W1l)[gsrc];
        }
        __syncthreads();
        short8 a_h = *(const short8*)&Ah[(wid * 16 + m) * 32 + quad * 8];
        short8 a_l = *(const short8*)&Al[(wid * 16 + m) * 32 + quad * 8];
#pragma unroll
        for (int nt = 0; nt < NT; nt++) {
            short8 b_h = *(const short8*)&Wh[(nt * 16 + m) * 32 + quad * 8];
            short8 b_l = *(const short8*)&Wl[(nt * 16 + m) * 32 + quad * 8];
            acc[nt] = __builtin_amdgcn_mfma_f32_16x16x32_bf16(a_h, b_h, acc[nt], 0, 0, 0);
            acc[nt] = __builtin_amdgcn_mfma_f32_16x16x32_bf16(a_h, b_l, acc[nt], 0, 0, 0);
            acc[nt] = __builtin_amdgcn_mfma_f32_16x16x32_bf16(a_l, b_h, acc[nt], 0, 0, 0);
        }
        __syncthreads();
    }

    // ---- tile1 = relu(acc + b1) -> LDS split-bf16 (C-layout scatter) ----
#pragma unroll
    for (int nt = 0; nt < NT; nt++) {
        int col = nt * 16 + m;
        float bb = b1[col];
#pragma unroll
        for (int r = 0; r < 4; r++) {
            int row = wid * 16 + quad * 4 + r;
            float v = fmaxf(acc[nt][r] + bb, 0.f);
            unsigned short h = f2bf(v);
            T1h[row * TS + col] = h;
            T1l[row * TS + col] = f2bf(v - bf2f(h));
        }
        acc[nt] = (float4v){0.f, 0.f, 0.f, 0.f};
    }
    __syncthreads();

    // ---- phase 2: acc = tile1 @ W2 (A-frags straight from LDS) ----
    for (int c = 0; c < 4; c++) {
        int kc = c * 32;
        for (int idx = t; idx < N * 8; idx += 256) {
            int n = idx >> 3, w = idx & 7;
            int gsrc = n * (Kpad / 4) + (kc >> 2) + w;
            ((uint2*)Wh)[idx] = ((const uint2*)W2h)[gsrc];
            ((uint2*)Wl)[idx] = ((const uint2*)W2l)[gsrc];
        }
        __syncthreads();
        short8 a_h = *(const short8*)&T1h[(wid * 16 + m) * TS + kc + quad * 8];
        short8 a_l = *(const short8*)&T1l[(wid * 16 + m) * TS + kc + quad * 8];
#pragma unroll
        for (int nt = 0; nt < NT; nt++) {
            short8 b_h = *(const short8*)&Wh[(nt * 16 + m) * 32 + quad * 8];
            short8 b_l = *(const short8*)&Wl[(nt * 16 + m) * 32 + quad * 8];
            acc[nt] = __builtin_amdgcn_mfma_f32_16x16x32_bf16(a_h, b_h, acc[nt], 0, 0, 0);
            acc[nt] = __builtin_amdgcn_mfma_f32_16x16x32_bf16(a_h, b_l, acc[nt], 0, 0, 0);
            acc[nt] = __builtin_amdgcn_mfma_f32_16x16x32_bf16(a_l, b_h, acc[nt], 0, 0, 0);
        }
        __syncthreads();
    }

    // ---- epilogue: bias2 + relu + store + BN1 partial stats ----
    float st_s[NT], st_q[NT];
#pragma unroll
    for (int nt = 0; nt < NT; nt++) {
        int col = nt * 16 + m;
        float bb = b2[col];
        float s_loc = 0.f, q_loc = 0.f;
#pragma unroll
        for (int r = 0; r < 4; r++) {
            int row = r0 + wid * 16 + quad * 4 + r;
            float v = fmaxf(acc[nt][r] + bb, 0.f);
            if (row < M) {
                C[(size_t)row * N + col] = v;
                s_loc += v;
                q_loc += v * v;
            }
        }
        st_s[nt] = s_loc;
        st_q[nt] = q_loc;
    }
    __shared__ float sls[4][2 * N];
#pragma unroll
    for (int nt = 0; nt < NT; nt++) {
        float s = st_s[nt], q = st_q[nt];
        s += __shfl_xor(s, 16); s += __shfl_xor(s, 32);
        q += __shfl_xor(q, 16); q += __shfl_xor(q, 32);
        if (quad == 0) {
            sls[wid][nt * 16 + m] = s;
            sls[wid][N + nt * 16 + m] = q;
        }
    }
    __syncthreads();
    for (int j = t; j < 2 * N; j += 256) {
        pbuf[(size_t)blockIdx.x * 2 * N + j] = sls[0][j] + sls[1][j] + sls[2][j] + sls[3][j];
    }
}

// ------------------------- split-bf16 MFMA GEMM: C = act(A @ W + bias)
// STATS: fuse per-block BN partial sums (sum, sumsq per column) into epilogue.
template <int NT, int KC, int K, bool RELU, int CHS, bool STATS>
__global__ __launch_bounds__(256) void gemm_mfma(const float* __restrict__ A,
                                                 const unsigned short* __restrict__ Whi,
                                                 const unsigned short* __restrict__ Wlo,
                                                 const float* __restrict__ bias,
                                                 float* __restrict__ C,
                                                 __half* __restrict__ Ch,
                                                 float* __restrict__ pbuf, int M) {
    constexpr int N = NT * 16;
    constexpr int Kpad = KC * 32;
    __shared__ __align__(16) unsigned short Ah[64 * 32];
    __shared__ __align__(16) unsigned short Al[64 * 32];
    __shared__ __align__(16) unsigned short Wh[N * 32];
    __shared__ __align__(16) unsigned short Wl[N * 32];
    int t = threadIdx.x;
    int lane = t & 63, wid = t >> 6;
    int r0 = blockIdx.x * 64;
    int m = lane & 15, quad = lane >> 4;

    float4v acc[NT];
#pragma unroll
    for (int nt = 0; nt < NT; nt++) acc[nt] = (float4v){0.f, 0.f, 0.f, 0.f};

    for (int c = 0; c < KC; c++) {
        int kc = c * 32;
#pragma unroll
        for (int i = 0; i < 2; i++) {
            int idx = t + i * 256;
            int row = idx >> 3, c4 = idx & 7;
            int col = kc + c4 * 4;
            int grow = r0 + row;
            float4 v = make_float4(0.f, 0.f, 0.f, 0.f);
            if (grow < M) {
                if (col + 3 < K) {
                    v = *(const float4*)(A + (size_t)grow * K + col);
                } else {
                    float tmp[4] = {0.f, 0.f, 0.f, 0.f};
                    for (int j = 0; j < 4; j++) if (col + j < K) tmp[j] = A[(size_t)grow * K + col + j];
                    v = make_float4(tmp[0], tmp[1], tmp[2], tmp[3]);
                }
            }
            unsigned short h0 = f2bf(v.x), h1 = f2bf(v.y), h2 = f2bf(v.z), h3 = f2bf(v.w);
            unsigned short l0 = f2bf(v.x - bf2f(h0)), l1 = f2bf(v.y - bf2f(h1));
            unsigned short l2 = f2bf(v.z - bf2f(h2)), l3 = f2bf(v.w - bf2f(h3));
            int o = row * 32 + c4 * 4;
            *(uint2*)&Ah[o] = make_uint2((unsigned)h0 | ((unsigned)h1 << 16), (unsigned)h2 | ((unsigned)h3 << 16));
            *(uint2*)&Al[o] = make_uint2((unsigned)l0 | ((unsigned)l1 << 16), (unsigned)l2 | ((unsigned)l3 << 16));
        }
        for (int idx = t; idx < N * 8; idx += 256) {
            int n = idx >> 3, w = idx & 7;
            int gsrc = n * (Kpad / 4) + (kc >> 2) + w;
            ((uint2*)Wh)[idx] = ((const uint2*)Whi)[gsrc];
            ((uint2*)Wl)[idx] = ((const uint2*)Wlo)[gsrc];
        }
        __syncthreads();
        short8 a_h = *(const short8*)&Ah[(wid * 16 + m) * 32 + quad * 8];
        short8 a_l = *(const short8*)&Al[(wid * 16 + m) * 32 + quad * 8];
#pragma unroll
        for (int nt = 0; nt < NT; nt++) {
            short8 b_h = *(const short8*)&Wh[(nt * 16 + m) * 32 + quad * 8];
            short8 b_l = *(const short8*)&Wl[(nt * 16 + m) * 32 + quad * 8];
            acc[nt] = __builtin_amdgcn_mfma_f32_16x16x32_bf16(a_h, b_h, acc[nt], 0, 0, 0);
            acc[nt] = __builtin_amdgcn_mfma_f32_16x16x32_bf16(a_h, b_l, acc[nt], 0, 0, 0);
            acc[nt] = __builtin_amdgcn_mfma_f32_16x16x32_bf16(a_l, b_h, acc[nt], 0, 0, 0);
        }
        __syncthreads();
    }
    float st_s[NT], st_q[NT];
#pragma unroll
    for (int nt = 0; nt < NT; nt++) {
        int col = nt * 16 + m;
        float b = bias ? bias[col] : 0.f;
        float s_loc = 0.f, q_loc = 0.f;
#pragma unroll
        for (int r = 0; r < 4; r++) {
            int row = r0 + wid * 16 + quad * 4 + r;
            float v = acc[nt][r] + b;
            if (RELU) v = fmaxf(v, 0.f);
            if (row < M) {
                if (C) C[(size_t)row * N + col] = v;
                if (Ch) Ch[(size_t)row * CHS + col] = __float2half(v);
                if (STATS) { s_loc += v; q_loc += v * v; }
            }
        }
        st_s[nt] = s_loc;
        st_q[nt] = q_loc;
    }
    if constexpr (STATS) {
        __shared__ float sls[4][2 * N];
#pragma unroll
        for (int nt = 0; nt < NT; nt++) {
            float s = st_s[nt], q = st_q[nt];
            s += __shfl_xor(s, 16); s += __shfl_xor(s, 32);
            q += __shfl_xor(q, 16); q += __shfl_xor(q, 32);
            if (quad == 0) {
                sls[wid][nt * 16 + m] = s;
                sls[wid][N + nt * 16 + m] = q;
            }
        }
        __syncthreads();
        for (int j = t; j < 2 * N; j += 256) {
            pbuf[(size_t)blockIdx.x * 2 * N + j] = sls[0][j] + sls[1][j] + sls[2][j] + sls[3][j];
        }
    }
}

// --------- parallel BN finalize: one block per feature, 256-thread reduce
template <int F, int BLOCKS>
__global__ __launch_bounds__(256) void bn_finalize_par(const float* __restrict__ pbuf,
                                                       const float* __restrict__ g,
                                                       const float* __restrict__ b,
                                                       float* __restrict__ s,
                                                       float* __restrict__ tt, int M) {
    __shared__ double red[256];
    int j = blockIdx.x;      // feature index
    int t = threadIdx.x;
    double sum = 0.0, sq = 0.0;
    for (int i = t; i < BLOCKS; i += 256) {
        sum += (double)pbuf[(size_t)i * 2 * F + j];
        sq  += (double)pbuf[(size_t)i * 2 * F + F + j];
    }
    red[t] = sum;
    __syncthreads();
    for (int o = 128; o > 0; o >>= 1) { if (t < o) red[t] += red[t + o]; __syncthreads(); }
    double total_sum = red[0];
    __syncthreads();
    red[t] = sq;
    __syncthreads();
    for (int o = 128; o > 0; o >>= 1) { if (t < o) red[t] += red[t + o]; __syncthreads(); }
    if (t == 0) {
        double mean = total_sum / M;
        double var = red[0] / M - mean * mean;
        double sc = (double)g[j] / sqrt(var + BN_EPS);
        s[j] = (float)sc;
        tt[j] = (float)((double)b[j] - mean * sc);
    }
}

// -------------------------------------------- pool (BN2 folded) + head
__global__ __launch_bounds__(256) void pool_head(const float* __restrict__ H2, const int* __restrict__ goff,
                                                 const float* __restrict__ s2, const float* __restrict__ t2,
                                                 const float* __restrict__ fcxd_w, const float* __restrict__ fcxd_b,
                                                 const float* __restrict__ fc1_w, const float* __restrict__ fc1_b,
                                                 const float* __restrict__ fc2_w, const float* __restrict__ fc2_b,
                                                 const float* __restrict__ fc3_w, const float* __restrict__ fc3_b,
                                                 const float* __restrict__ fc4_w, const float* __restrict__ fc4_b,
                                                 const float* __restrict__ fc5_w, const float* __restrict__ fc5_b,
                                                 float* __restrict__ out) {
    __shared__ float red[256];
    __shared__ float p[64];
    __shared__ float z[64];
    int g = blockIdx.x, t = threadIdx.x;
    int r0 = goff[g], r1 = goff[g + 1];
    int cnt = r1 - r0;
    int j = t & 31, rr = t >> 5;
    float a = 0.f;
    for (int r = r0 + rr; r < r1; r += 8) a += H2[(size_t)r * DIM + j];
    red[t] = a;
    __syncthreads();
    if (t < 32) {
        float ssum = 0.f;
        for (int q = 0; q < 8; q++) ssum += red[q * 32 + j];
        p[j] = s2[j] * ssum + (float)cnt * t2[j];
    }
    __syncthreads();
    if (t < 64) {
        float acc = fcxd_b[t];
        for (int i = 0; i < 32; i++) acc += p[i] * fcxd_w[i * 64 + t];
        z[t] = fmaxf(acc, 0.f);
    }
    __syncthreads();
    if (t < 32) {
        float acc = fc1_b[t];
        for (int i = 0; i < 64; i++) acc += z[i] * fc1_w[i * 32 + t];
        p[t] = acc;
    }
    __syncthreads();
    if (t < 16) {
        float acc = fc2_b[t];
        for (int i = 0; i < 32; i++) acc += p[i] * fc2_w[i * 16 + t];
        z[t] = acc;
    }
    __syncthreads();
    if (t < 8) {
        float acc = fc3_b[t];
        for (int i = 0; i < 16; i++) acc += z[i] * fc3_w[i * 8 + t];
        p[t] = acc;
    }
    __syncthreads();
    if (t < 2) {
        float acc = fc4_b[t];
        for (int i = 0; i < 8; i++) acc += p[i] * fc4_w[i * 2 + t];
        z[t] = acc;
    }
    __syncthreads();
    if (t == 0) {
        out[g] = z[0] * fc5_w[0] + z[1] * fc5_w[1] + fc5_b[0];
    }
}

// ---------------------------------------------------------------- launch
extern "C" void kernel_launch(void* const* d_in, const int* in_sizes, int n_in,
                              void* d_out, int out_size, void* d_ws, size_t ws_size,
                              hipStream_t stream) {
    const float* x     = (const float*)d_in[0];
    const int*   src   = (const int*)d_in[1];
    const int*   dst   = (const int*)d_in[2];
    const int*   batch = (const int*)d_in[3];
    const float* g1_w1 = (const float*)d_in[4];
    const float* g1_b1 = (const float*)d_in[5];
    const float* g1_w2 = (const float*)d_in[6];
    const float* g1_b2 = (const float*)d_in[7];
    const float* bn1_g = (const float*)d_in[8];
    const float* bn1_b = (const float*)d_in[9];
    const float* g2_w1 = (const float*)d_in[10];
    const float* g2_b1 = (const float*)d_in[11];
    const float* g2_w2 = (const float*)d_in[12];
    const float* g2_b2 = (const float*)d_in[13];
    const float* bn2_g = (const float*)d_in[14];
    const float* bn2_b = (const float*)d_in[15];
    const float* fcxd_w = (const float*)d_in[16];
    const float* fcxd_b = (const float*)d_in[17];
    const float* fc1_w = (const float*)d_in[18];
    const float* fc1_b = (const float*)d_in[19];
    const float* fc2_w = (const float*)d_in[20];
    const float* fc2_b = (const float*)d_in[21];
    const float* fc3_w = (const float*)d_in[22];
    const float* fc3_b = (const float*)d_in[23];
    const float* fc4_w = (const float*)d_in[24];
    const float* fc4_b = (const float*)d_in[25];
    const float* fc5_w = (const float*)d_in[26];
    const float* fc5_b = (const float*)d_in[27];
    float* out = (float*)d_out;
    char* ws = (char*)d_ws;

    const int GEMM_MB = (N_NODES + 63) / 64;       // 782 (also BN partial blocks)

    size_t off = 0;
    auto take = [&](size_t bytes) { size_t o = off; off += (bytes + 255) & ~(size_t)255; return o; };
    int* bcur_pad  = (int*)(ws + take((size_t)NB * NREP * PAD * 4));    // zeroed (1.6 MB)
    size_t zero_bytes = off;
    int* bucket    = (int*)(ws + take((size_t)NB * NREP * RCAP * 4));
    int* perm_pad  = (int*)(ws + take((size_t)N_NODES * CAP * 4));
    int* deg       = (int*)(ws + take((size_t)N_NODES * 4));
    int* goff      = (int*)(ws + take((size_t)(N_GRAPHS + 4) * 4));
    float* s1      = (float*)(ws + take(F_IN * 4));
    float* t1      = (float*)(ws + take(F_IN * 4));
    float* s2      = (float*)(ws + take(DIM * 4));
    float* t2      = (float*)(ws + take(DIM * 4));
    float* c0      = (float*)(ws + take(DIM * 4));
    float* pb1     = (float*)(ws + take((size_t)GEMM_MB * 2 * F_IN * 4));
    float* pb2     = (float*)(ws + take((size_t)GEMM_MB * 2 * DIM * 4));
    unsigned short* w1h = (unsigned short*)(ws + take((size_t)F_IN * 128 * 2));
    unsigned short* w1l = (unsigned short*)(ws + take((size_t)F_IN * 128 * 2));
    unsigned short* w2h = (unsigned short*)(ws + take((size_t)F_IN * 128 * 2));
    unsigned short* w2l = (unsigned short*)(ws + take((size_t)F_IN * 128 * 2));
    unsigned short* w3h = (unsigned short*)(ws + take((size_t)DIM * 128 * 2));
    unsigned short* w3l = (unsigned short*)(ws + take((size_t)DIM * 128 * 2));
    unsigned short* w4h = (unsigned short*)(ws + take((size_t)DIM * 32 * 2));
    unsigned short* w4l = (unsigned short*)(ws + take((size_t)DIM * 32 * 2));
    __half* x_half = (__half*)(ws + take((size_t)N_NODES * HROW * 2));
    __half* y_half = (__half*)(ws + take((size_t)N_NODES * DIM * 2));
    float* bufA    = (float*)(ws + take((size_t)N_NODES * F_IN * 4));
    float* bufS1   = (float*)(ws + take((size_t)N_NODES * DIM * 4));
    float* bufS2   = (float*)(ws + take((size_t)N_NODES * DIM * 4));
    (void)ws_size; (void)in_sizes; (void)n_in; (void)out_size;

    hipMemsetAsync(ws, 0, zero_bytes, stream);

    // merged prep: bucket append (XCD-replicated) + x->fp16 + weight splits +
    // graph bounds — one launch, bucket blocks dispatched first.
    prep_kernel<<<PB_GB, 256, 0, stream>>>(src, dst, bcur_pad, bucket,
                                           x, x_half,
                                           g1_w1, w1h, w1l, g1_w2, w2h, w2l, g2_w2, w4h, w4l,
                                           batch, goff);
    bin_build<<<NB, 256, 0, stream>>>(bcur_pad, bucket, perm_pad, deg);

    const int AGG_BLOCKS = (N_NODES + 3) / 4;

    // GIN layer 1: agg -> fused 2-GEMM MLP (LDS-resident intermediate, BN1
    // stats in epilogue) -> parallel finalize
    agg_kernel<<<AGG_BLOCKS, 256, 0, stream>>>(x, x_half, deg, perm_pad, bufA, N_NODES);
    gemm_mlp112<<<GEMM_MB, 256, 0, stream>>>(bufA, w1h, w1l, g1_b1, w2h, w2l, g1_b2, bufA, pb1, N_NODES);
    bn_finalize_par<F_IN, 782><<<F_IN, 256, 0, stream>>>(pb1, bn1_g, bn1_b, s1, t1, N_NODES);

    // GIN layer 2: linear-first (BN1 folded into W3' and c0), then 32-wide agg;
    // BN2 stats fused into gemm2b epilogue.
    w3_fold<<<(DIM * 128 + 255) / 256, 256, 0, stream>>>(g2_w1, s1, t1, w3h, w3l, c0);
    gemm_mfma<2, 4, F_IN, false, DIM, false><<<GEMM_MB, 256, 0, stream>>>(bufA, w3h, w3l, nullptr, nullptr, y_half, nullptr, N_NODES);
    agg32_kernel<<<AGG_BLOCKS, 256, 0, stream>>>(y_half, deg, perm_pad, c0, g2_b1, bufS1, N_NODES);
    gemm_mfma<2, 1, DIM, true, 0, true><<<GEMM_MB, 256, 0, stream>>>(bufS1, w4h, w4l, g2_b2, bufS2, nullptr, pb2, N_NODES);
    bn_finalize_par<DIM, 782><<<DIM, 256, 0, stream>>>(pb2, bn2_g, bn2_b, s2, t2, N_NODES);

    // pool (BN2 folded) + dense head
    pool_head<<<N_GRAPHS, 256, 0, stream>>>(bufS2, goff, s2, t2,
                                            fcxd_w, fcxd_b, fc1_w, fc1_b, fc2_w, fc2_b,
                                            fc3_w, fc3_b, fc4_w, fc4_b, fc5_w, fc5_b, out);
}

// Round 15
// 304.034 us; speedup vs baseline: 1.3618x; 1.0065x over previous
//
#include <hip/hip_runtime.h>
#include <hip/hip_fp16.h>

#define N_NODES 50000
#define N_EDGES 800000
#define N_GRAPHS 256
#define F_IN 112
#define DIM 32
#define BN_EPS 1e-5
#define PAD 32     // ints per atomic slot: one 128-B line per cursor
#define HROW 128   // fp16 gather-row stride (256 B = exactly 2 lines, zero waste)
#define CAP 64     // edge slots per node (P(deg>63) ~ 1e-19 for Poisson(16))
#define NB 1563    // buckets = ceil(50000/32)
#define NREP 8     // one bucket replica per XCD
#define RCAP 128   // entries per replica-bucket (Poisson(64), 8 sigma headroom)

typedef __attribute__((ext_vector_type(8))) short short8;
typedef __attribute__((ext_vector_type(4))) float float4v;

// ---- bf16 helpers (RNE) ----
__device__ inline unsigned short f2bf(float f) {
    union { float f; unsigned int u; } v; v.f = f;
    unsigned int u = v.u;
    u += 0x7FFFu + ((u >> 16) & 1u);
    return (unsigned short)(u >> 16);
}
__device__ inline float bf2f(unsigned short h) {
    union { unsigned int u; float f; } v; v.u = ((unsigned int)h) << 16;
    return v.f;
}

__device__ inline void w_split_body(const float* __restrict__ W, int K, int N, int Kpad,
                                    unsigned short* __restrict__ hi_t,
                                    unsigned short* __restrict__ lo_t, int idx) {
    if (idx >= N * Kpad) return;
    int n = idx / Kpad, k = idx - n * Kpad;
    float v = (k < K) ? W[(size_t)k * N + n] : 0.f;
    unsigned short h = f2bf(v);
    hi_t[idx] = h;
    lo_t[idx] = f2bf(v - bf2f(h));
}

// ---- merged prep: bucket_append FIRST (long pole; 4 edges/thread for MLP),
//      then x->fp16, weight splits, graph bounds.
#define PB_BA 782                    // ceil(800000 / (256*4)) bucket-append blocks
#define PB_XH (PB_BA + 12500)        // 50000*64 half2 / 256
#define PB_W1 (PB_XH + 56)
#define PB_W2 (PB_W1 + 56)
#define PB_W4 (PB_W2 + 4)
#define PB_GB (PB_W4 + 196)          // total blocks
__global__ __launch_bounds__(256) void prep_kernel(const int* __restrict__ src, const int* __restrict__ dst,
                                                   int* __restrict__ bcur_pad, int* __restrict__ bucket,
                                                   const float* __restrict__ X, __half* __restrict__ Xh,
                                                   const float* __restrict__ g1_w1, unsigned short* w1h, unsigned short* w1l,
                                                   const float* __restrict__ g1_w2, unsigned short* w2h, unsigned short* w2l,
                                                   const float* __restrict__ g2_w2, unsigned short* w4h, unsigned short* w4l,
                                                   const int* __restrict__ batch, int* __restrict__ goff) {
    int b = blockIdx.x, t = threadIdx.x;
    if (b < PB_BA) {
        unsigned xcc = 0;
        asm volatile("s_getreg_b32 %0, hwreg(HW_REG_XCC_ID)" : "=s"(xcc));
        int r = (int)(xcc & (NREP - 1));
        int base = b * 1024 + t;
        int d[4], s[4];
#pragma unroll
        for (int j = 0; j < 4; j++) {
            int i = base + j * 256;
            if (i < N_EDGES) {
                d[j] = __builtin_nontemporal_load(dst + i);
                s[j] = __builtin_nontemporal_load(src + i);
            } else {
                d[j] = -1;
            }
        }
        int c[4];
#pragma unroll
        for (int j = 0; j < 4; j++) {
            if (d[j] >= 0) {
                size_t slot = (size_t)(d[j] >> 5) * NREP + r;
                c[j] = atomicAdd(&bcur_pad[slot * PAD], 1);
            }
        }
#pragma unroll
        for (int j = 0; j < 4; j++) {
            if (d[j] >= 0 && c[j] < RCAP) {
                size_t slot = (size_t)(d[j] >> 5) * NREP + r;
                bucket[slot * RCAP + c[j]] = ((d[j] & 31) << 16) | s[j];
            }
        }
    } else if (b < PB_XH) {
        int idx = (b - PB_BA) * 256 + t;             // one half2 per thread
        if (idx >= N_NODES * (HROW / 2)) return;
        int row = idx / (HROW / 2), c2 = idx - row * (HROW / 2);
        int col = c2 * 2;
        float2 v = make_float2(0.f, 0.f);
        if (col < F_IN) v = *(const float2*)(X + (size_t)row * F_IN + col);
        ((__half2*)Xh)[idx] = __floats2half2_rn(v.x, v.y);
    } else if (b < PB_W1) {
        w_split_body(g1_w1, F_IN, F_IN, 128, w1h, w1l, (b - PB_XH) * 256 + t);
    } else if (b < PB_W2) {
        w_split_body(g1_w2, F_IN, F_IN, 128, w2h, w2l, (b - PB_W1) * 256 + t);
    } else if (b < PB_W4) {
        w_split_body(g2_w2, DIM, DIM, 32, w4h, w4l, (b - PB_W2) * 256 + t);
    } else {
        int i = (b - PB_W4) * 256 + t;
        if (i >= N_NODES) return;
        int cur = batch[i];
        int prev = (i == 0) ? -1 : batch[i - 1];
        for (int g = prev + 1; g <= cur; g++) goff[g] = i;
        if (i == N_NODES - 1) {
            for (int g = cur + 1; g <= N_GRAPHS; g++) goff[g] = N_NODES;
        }
    }
}

// ---------------- phase B: per-bucket LDS binning -> coalesced perm/deg write
__global__ __launch_bounds__(256) void bin_build(const int* __restrict__ bcur_pad,
                                                 const int* __restrict__ bucket,
                                                 int* __restrict__ perm_pad,
                                                 int* __restrict__ deg) {
    __shared__ int bins[32][CAP];
    __shared__ int lcur[32];
    int b = blockIdx.x, t = threadIdx.x;
    if (t < 32) lcur[t] = 0;
    __syncthreads();
    for (int r = 0; r < NREP; r++) {
        size_t slot = (size_t)b * NREP + r;
        int count = min(bcur_pad[slot * PAD], RCAP);
        for (int i = t; i < count; i += 256) {
            int e = bucket[slot * RCAP + i];
            int l = e >> 16, s = e & 0xFFFF;
            int c = atomicAdd(&lcur[l], 1);
            if (c < CAP) bins[l][c] = s;
        }
    }
    __syncthreads();
    if (t < 32) {
        int node = b * 32 + t;
        if (node < N_NODES) deg[node] = min(lcur[t], CAP);
    }
    for (int i = t; i < 32 * (CAP / 4); i += 256) {
        int l = i / (CAP / 4), q = i % (CAP / 4);
        int node = b * 32 + l;
        if (node < N_NODES) {
            ((int4*)&perm_pad[(size_t)node * CAP])[q] = ((const int4*)bins[l])[q];
        }
    }
}

// ------------------- layer-1 aggregation (wave per node), fp16 gather
__global__ __launch_bounds__(256) void agg_kernel(const float* __restrict__ X,
                                                  const __half* __restrict__ Xh,
                                                  const int* __restrict__ deg_arr,
                                                  const int* __restrict__ perm_pad,
                                                  float* __restrict__ out, int M) {
    constexpr int P = F_IN / 2;
    int w = (blockIdx.x * 256 + threadIdx.x) >> 6;
    int lane = threadIdx.x & 63;
    if (w >= M) return;
    int deg = deg_arr[w];
    const int* pl = perm_pad + (size_t)w * CAP;
    float ax = 0.f, ay = 0.f;
    int e = 0;
    for (; e + 16 <= deg; e += 16) {
        int s[16];
#pragma unroll
        for (int j = 0; j < 16; j++) s[j] = pl[e + j];
        float2 v[16];
#pragma unroll
        for (int j = 0; j < 16; j++)
            v[j] = __half22float2(*(const __half2*)(Xh + (size_t)s[j] * HROW + 2 * lane));
#pragma unroll
        for (int j = 0; j < 16; j++) { ax += v[j].x; ay += v[j].y; }
    }
    for (; e + 4 <= deg; e += 4) {
        int s0 = pl[e], s1 = pl[e + 1], s2 = pl[e + 2], s3 = pl[e + 3];
        float2 v0 = __half22float2(*(const __half2*)(Xh + (size_t)s0 * HROW + 2 * lane));
        float2 v1 = __half22float2(*(const __half2*)(Xh + (size_t)s1 * HROW + 2 * lane));
        float2 v2 = __half22float2(*(const __half2*)(Xh + (size_t)s2 * HROW + 2 * lane));
        float2 v3 = __half22float2(*(const __half2*)(Xh + (size_t)s3 * HROW + 2 * lane));
        ax += (v0.x + v1.x) + (v2.x + v3.x);
        ay += (v0.y + v1.y) + (v2.y + v3.y);
    }
    for (; e < deg; e++) {
        int s = pl[e];
        float2 v = __half22float2(*(const __half2*)(Xh + (size_t)s * HROW + 2 * lane));
        ax += v.x;
        ay += v.y;
    }
    if (lane < P) {
        float2 self = *(const float2*)(X + (size_t)w * F_IN + 2 * lane);
        *(float2*)(out + (size_t)w * F_IN + 2 * lane) = make_float2(self.x + ax, self.y + ay);
    }
}

// ---------- layer-2 aggregation on 32-wide fp16 y rows (quarter-wave/edge)
__global__ __launch_bounds__(256) void agg32_kernel(const __half* __restrict__ Y,
                                                    const int* __restrict__ deg_arr,
                                                    const int* __restrict__ perm_pad,
                                                    const float* __restrict__ c0,
                                                    const float* __restrict__ b1,
                                                    float* __restrict__ out, int M) {
    int w = (blockIdx.x * 256 + threadIdx.x) >> 6;
    int lane = threadIdx.x & 63;
    if (w >= M) return;
    int f = lane & 15;
    int g = lane >> 4;
    int deg = deg_arr[w];
    const int* pl = perm_pad + (size_t)w * CAP;
    float ax = 0.f, ay = 0.f;
    int e = g;
    for (; e + 4 < deg; e += 8) {
        int s0 = pl[e], s1 = pl[e + 4];
        float2 v0 = __half22float2(*(const __half2*)(Y + (size_t)s0 * DIM + 2 * f));
        float2 v1 = __half22float2(*(const __half2*)(Y + (size_t)s1 * DIM + 2 * f));
        ax += v0.x + v1.x;
        ay += v0.y + v1.y;
    }
    if (e < deg) {
        int s0 = pl[e];
        float2 v0 = __half22float2(*(const __half2*)(Y + (size_t)s0 * DIM + 2 * f));
        ax += v0.x;
        ay += v0.y;
    }
    ax += __shfl_xor(ax, 16); ax += __shfl_xor(ax, 32);
    ay += __shfl_xor(ay, 16); ay += __shfl_xor(ay, 32);
    if (g == 0) {
        float2 self = __half22float2(*(const __half2*)(Y + (size_t)w * DIM + 2 * f));
        float deg1 = (float)(deg + 1);
        float zx = self.x + ax + deg1 * c0[2 * f] + b1[2 * f];
        float zy = self.y + ay + deg1 * c0[2 * f + 1] + b1[2 * f + 1];
        *(float2*)(out + (size_t)w * DIM + 2 * f) = make_float2(fmaxf(zx, 0.f), fmaxf(zy, 0.f));
    }
}

// ------- BN1-folded W3 split: W3'[k][n] = s1[k]*W3[k][n]; c0[n] = sum t1[k]W3[k][n]
__global__ __launch_bounds__(256) void w3_fold(const float* __restrict__ W,   // [112][32]
                                               const float* __restrict__ s1,
                                               const float* __restrict__ t1,
                                               unsigned short* __restrict__ hi_t,  // [32][128]
                                               unsigned short* __restrict__ lo_t,
                                               float* __restrict__ c0) {
    int idx = blockIdx.x * 256 + threadIdx.x;
    if (idx < DIM * 128) {
        int n = idx >> 7, k = idx & 127;
        float v = (k < F_IN) ? s1[k] * W[(size_t)k * DIM + n] : 0.f;
        unsigned short h = f2bf(v);
        hi_t[idx] = h;
        lo_t[idx] = f2bf(v - bf2f(h));
    }
    if (blockIdx.x == 0 && threadIdx.x < DIM) {
        int n = threadIdx.x;
        float acc = 0.f;
        for (int k = 0; k < F_IN; k++) acc += t1[k] * W[(size_t)k * DIM + n];
        c0[n] = acc;
    }
}

// ------------- FUSED layer-1 MLP: C = relu(relu(A@W1+b1)@W2+b2), + BN1 stats
__global__ __launch_bounds__(256) void gemm_mlp112(const float* __restrict__ A,
                                                   const unsigned short* __restrict__ W1h,
                                                   const unsigned short* __restrict__ W1l,
                                                   const float* __restrict__ b1,
                                                   const unsigned short* __restrict__ W2h,
                                                   const unsigned short* __restrict__ W2l,
                                                   const float* __restrict__ b2,
                                                   float* __restrict__ C,
                                                   float* __restrict__ pbuf, int M) {
    constexpr int NT = 7, N = 112, K = 112, Kpad = 128, TS = 136;
    __shared__ __align__(16) unsigned short Ah[64 * 32];
    __shared__ __align__(16) unsigned short Al[64 * 32];
    __shared__ __align__(16) unsigned short Wh[N * 32];
    __shared__ __align__(16) unsigned short Wl[N * 32];
    __shared__ __align__(16) unsigned short T1h[64 * TS];
    __shared__ __align__(16) unsigned short T1l[64 * TS];
    int t = threadIdx.x;
    int lane = t & 63, wid = t >> 6;
    int r0 = blockIdx.x * 64;
    int m = lane & 15, quad = lane >> 4;

    for (int i = t; i < 64 * 16; i += 256) {
        int r = i >> 4, k = 112 + (i & 15);
        T1h[r * TS + k] = 0;
        T1l[r * TS + k] = 0;
    }

    float4v acc[NT];
#pragma unroll
    for (int nt = 0; nt < NT; nt++) acc[nt] = (float4v){0.f, 0.f, 0.f, 0.f};

    // ---- phase 1: acc = A @ W1 ----
    for (int c = 0; c < 4; c++) {
        int kc = c * 32;
#pragma unroll
        for (int i = 0; i < 2; i++) {
            int idx = t + i * 256;
            int row = idx >> 3, c4 = idx & 7;
            int col = kc + c4 * 4;
            int grow = r0 + row;
            float4 v = make_float4(0.f, 0.f, 0.f, 0.f);
            if (grow < M) {
                if (col + 3 < K) {
                    v = *(const float4*)(A + (size_t)grow * K + col);
                } else {
                    float tmp[4] = {0.f, 0.f, 0.f, 0.f};
                    for (int j = 0; j < 4; j++) if (col + j < K) tmp[j] = A[(size_t)grow * K + col + j];
                    v = make_float4(tmp[0], tmp[1], tmp[2], tmp[3]);
                }
            }
            unsigned short h0 = f2bf(v.x), h1 = f2bf(v.y), h2 = f2bf(v.z), h3 = f2bf(v.w);
            unsigned short l0 = f2bf(v.x - bf2f(h0)), l1 = f2bf(v.y - bf2f(h1));
            unsigned short l2 = f2bf(v.z - bf2f(h2)), l3 = f2bf(v.w - bf2f(h3));
            int o = row * 32 + c4 * 4;
            *(uint2*)&Ah[o] = make_uint2((unsigned)h0 | ((unsigned)h1 << 16), (unsigned)h2 | ((unsigned)h3 << 16));
            *(uint2*)&Al[o] = make_uint2((unsigned)l0 | ((unsigned)l1 << 16), (unsigned)l2 | ((unsigned)l3 << 16));
        }
        for (int idx = t; idx < N * 8; idx += 256) {
            int n = idx >> 3, w = idx & 7;
            int gsrc = n * (Kpad / 4) + (kc >> 2) + w;
            ((uint2*)Wh)[idx] = ((const uint2*)W1h)[gsrc];
            ((uint2*)Wl)[idx] = ((const uint2*)W1l)[gsrc];
        }
        __syncthreads();
        short8 a_h = *(const short8*)&Ah[(wid * 16 + m) * 32 + quad * 8];
        short8 a_l = *(const short8*)&Al[(wid * 16 + m) * 32 + quad * 8];
#pragma unroll
        for (int nt = 0; nt < NT; nt++) {
            short8 b_h = *(const short8*)&Wh[(nt * 16 + m) * 32 + quad * 8];
            short8 b_l = *(const short8*)&Wl[(nt * 16 + m) * 32 + quad * 8];
            acc[nt] = __builtin_amdgcn_mfma_f32_16x16x32_bf16(a_h, b_h, acc[nt], 0, 0, 0);
            acc[nt] = __builtin_amdgcn_mfma_f32_16x16x32_bf16(a_h, b_l, acc[nt], 0, 0, 0);
            acc[nt] = __builtin_amdgcn_mfma_f32_16x16x32_bf16(a_l, b_h, acc[nt], 0, 0, 0);
        }
        __syncthreads();
    }

    // ---- tile1 = relu(acc + b1) -> LDS split-bf16 ----
#pragma unroll
    for (int nt = 0; nt < NT; nt++) {
        int col = nt * 16 + m;
        float bb = b1[col];
#pragma unroll
        for (int r = 0; r < 4; r++) {
            int row = wid * 16 + quad * 4 + r;
            float v = fmaxf(acc[nt][r] + bb, 0.f);
            unsigned short h = f2bf(v);
            T1h[row * TS + col] = h;
            T1l[row * TS + col] = f2bf(v - bf2f(h));
        }
        acc[nt] = (float4v){0.f, 0.f, 0.f, 0.f};
    }
    __syncthreads();

    // ---- phase 2: acc = tile1 @ W2 ----
    for (int c = 0; c < 4; c++) {
        int kc = c * 32;
        for (int idx = t; idx < N * 8; idx += 256) {
            int n = idx >> 3, w = idx & 7;
            int gsrc = n * (Kpad / 4) + (kc >> 2) + w;
            ((uint2*)Wh)[idx] = ((const uint2*)W2h)[gsrc];
            ((uint2*)Wl)[idx] = ((const uint2*)W2l)[gsrc];
        }
        __syncthreads();
        short8 a_h = *(const short8*)&T1h[(wid * 16 + m) * TS + kc + quad * 8];
        short8 a_l = *(const short8*)&T1l[(wid * 16 + m) * TS + kc + quad * 8];
#pragma unroll
        for (int nt = 0; nt < NT; nt++) {
            short8 b_h = *(const short8*)&Wh[(nt * 16 + m) * 32 + quad * 8];
            short8 b_l = *(const short8*)&Wl[(nt * 16 + m) * 32 + quad * 8];
            acc[nt] = __builtin_amdgcn_mfma_f32_16x16x32_bf16(a_h, b_h, acc[nt], 0, 0, 0);
            acc[nt] = __builtin_amdgcn_mfma_f32_16x16x32_bf16(a_h, b_l, acc[nt], 0, 0, 0);
            acc[nt] = __builtin_amdgcn_mfma_f32_16x16x32_bf16(a_l, b_h, acc[nt], 0, 0, 0);
        }
        __syncthreads();
    }

    // ---- epilogue: bias2 + relu + store + BN1 partial stats ----
    float st_s[NT], st_q[NT];
#pragma unroll
    for (int nt = 0; nt < NT; nt++) {
        int col = nt * 16 + m;
        float bb = b2[col];
        float s_loc = 0.f, q_loc = 0.f;
#pragma unroll
        for (int r = 0; r < 4; r++) {
            int row = r0 + wid * 16 + quad * 4 + r;
            float v = fmaxf(acc[nt][r] + bb, 0.f);
            if (row < M) {
                C[(size_t)row * N + col] = v;
                s_loc += v;
                q_loc += v * v;
            }
        }
        st_s[nt] = s_loc;
        st_q[nt] = q_loc;
    }
    __shared__ float sls[4][2 * N];
#pragma unroll
    for (int nt = 0; nt < NT; nt++) {
        float s = st_s[nt], q = st_q[nt];
        s += __shfl_xor(s, 16); s += __shfl_xor(s, 32);
        q += __shfl_xor(q, 16); q += __shfl_xor(q, 32);
        if (quad == 0) {
            sls[wid][nt * 16 + m] = s;
            sls[wid][N + nt * 16 + m] = q;
        }
    }
    __syncthreads();
    for (int j = t; j < 2 * N; j += 256) {
        pbuf[(size_t)blockIdx.x * 2 * N + j] = sls[0][j] + sls[1][j] + sls[2][j] + sls[3][j];
    }
}

// ------------------------- split-bf16 MFMA GEMM: C = act(A @ W + bias)
template <int NT, int KC, int K, bool RELU, int CHS, bool STATS>
__global__ __launch_bounds__(256) void gemm_mfma(const float* __restrict__ A,
                                                 const unsigned short* __restrict__ Whi,
                                                 const unsigned short* __restrict__ Wlo,
                                                 const float* __restrict__ bias,
                                                 float* __restrict__ C,
                                                 __half* __restrict__ Ch,
                                                 float* __restrict__ pbuf, int M) {
    constexpr int N = NT * 16;
    constexpr int Kpad = KC * 32;
    __shared__ __align__(16) unsigned short Ah[64 * 32];
    __shared__ __align__(16) unsigned short Al[64 * 32];
    __shared__ __align__(16) unsigned short Wh[N * 32];
    __shared__ __align__(16) unsigned short Wl[N * 32];
    int t = threadIdx.x;
    int lane = t & 63, wid = t >> 6;
    int r0 = blockIdx.x * 64;
    int m = lane & 15, quad = lane >> 4;

    float4v acc[NT];
#pragma unroll
    for (int nt = 0; nt < NT; nt++) acc[nt] = (float4v){0.f, 0.f, 0.f, 0.f};

    for (int c = 0; c < KC; c++) {
        int kc = c * 32;
#pragma unroll
        for (int i = 0; i < 2; i++) {
            int idx = t + i * 256;
            int row = idx >> 3, c4 = idx & 7;
            int col = kc + c4 * 4;
            int grow = r0 + row;
            float4 v = make_float4(0.f, 0.f, 0.f, 0.f);
            if (grow < M) {
                if (col + 3 < K) {
                    v = *(const float4*)(A + (size_t)grow * K + col);
                } else {
                    float tmp[4] = {0.f, 0.f, 0.f, 0.f};
                    for (int j = 0; j < 4; j++) if (col + j < K) tmp[j] = A[(size_t)grow * K + col + j];
                    v = make_float4(tmp[0], tmp[1], tmp[2], tmp[3]);
                }
            }
            unsigned short h0 = f2bf(v.x), h1 = f2bf(v.y), h2 = f2bf(v.z), h3 = f2bf(v.w);
            unsigned short l0 = f2bf(v.x - bf2f(h0)), l1 = f2bf(v.y - bf2f(h1));
            unsigned short l2 = f2bf(v.z - bf2f(h2)), l3 = f2bf(v.w - bf2f(h3));
            int o = row * 32 + c4 * 4;
            *(uint2*)&Ah[o] = make_uint2((unsigned)h0 | ((unsigned)h1 << 16), (unsigned)h2 | ((unsigned)h3 << 16));
            *(uint2*)&Al[o] = make_uint2((unsigned)l0 | ((unsigned)l1 << 16), (unsigned)l2 | ((unsigned)l3 << 16));
        }
        for (int idx = t; idx < N * 8; idx += 256) {
            int n = idx >> 3, w = idx & 7;
            int gsrc = n * (Kpad / 4) + (kc >> 2) + w;
            ((uint2*)Wh)[idx] = ((const uint2*)Whi)[gsrc];
            ((uint2*)Wl)[idx] = ((const uint2*)Wlo)[gsrc];
        }
        __syncthreads();
        short8 a_h = *(const short8*)&Ah[(wid * 16 + m) * 32 + quad * 8];
        short8 a_l = *(const short8*)&Al[(wid * 16 + m) * 32 + quad * 8];
#pragma unroll
        for (int nt = 0; nt < NT; nt++) {
            short8 b_h = *(const short8*)&Wh[(nt * 16 + m) * 32 + quad * 8];
            short8 b_l = *(const short8*)&Wl[(nt * 16 + m) * 32 + quad * 8];
            acc[nt] = __builtin_amdgcn_mfma_f32_16x16x32_bf16(a_h, b_h, acc[nt], 0, 0, 0);
            acc[nt] = __builtin_amdgcn_mfma_f32_16x16x32_bf16(a_h, b_l, acc[nt], 0, 0, 0);
            acc[nt] = __builtin_amdgcn_mfma_f32_16x16x32_bf16(a_l, b_h, acc[nt], 0, 0, 0);
        }
        __syncthreads();
    }
    float st_s[NT], st_q[NT];
#pragma unroll
    for (int nt = 0; nt < NT; nt++) {
        int col = nt * 16 + m;
        float b = bias ? bias[col] : 0.f;
        float s_loc = 0.f, q_loc = 0.f;
#pragma unroll
        for (int r = 0; r < 4; r++) {
            int row = r0 + wid * 16 + quad * 4 + r;
            float v = acc[nt][r] + b;
            if (RELU) v = fmaxf(v, 0.f);
            if (row < M) {
                if (C) C[(size_t)row * N + col] = v;
                if (Ch) Ch[(size_t)row * CHS + col] = __float2half(v);
                if (STATS) { s_loc += v; q_loc += v * v; }
            }
        }
        st_s[nt] = s_loc;
        st_q[nt] = q_loc;
    }
    if constexpr (STATS) {
        __shared__ float sls[4][2 * N];
#pragma unroll
        for (int nt = 0; nt < NT; nt++) {
            float s = st_s[nt], q = st_q[nt];
            s += __shfl_xor(s, 16); s += __shfl_xor(s, 32);
            q += __shfl_xor(q, 16); q += __shfl_xor(q, 32);
            if (quad == 0) {
                sls[wid][nt * 16 + m] = s;
                sls[wid][N + nt * 16 + m] = q;
            }
        }
        __syncthreads();
        for (int j = t; j < 2 * N; j += 256) {
            pbuf[(size_t)blockIdx.x * 2 * N + j] = sls[0][j] + sls[1][j] + sls[2][j] + sls[3][j];
        }
    }
}

// --------- parallel BN finalize: one block per feature, 256-thread reduce
template <int F, int BLOCKS>
__global__ __launch_bounds__(256) void bn_finalize_par(const float* __restrict__ pbuf,
                                                       const float* __restrict__ g,
                                                       const float* __restrict__ b,
                                                       float* __restrict__ s,
                                                       float* __restrict__ tt, int M) {
    __shared__ double red[256];
    int j = blockIdx.x;      // feature index
    int t = threadIdx.x;
    double sum = 0.0, sq = 0.0;
    for (int i = t; i < BLOCKS; i += 256) {
        sum += (double)pbuf[(size_t)i * 2 * F + j];
        sq  += (double)pbuf[(size_t)i * 2 * F + F + j];
    }
    red[t] = sum;
    __syncthreads();
    for (int o = 128; o > 0; o >>= 1) { if (t < o) red[t] += red[t + o]; __syncthreads(); }
    double total_sum = red[0];
    __syncthreads();
    red[t] = sq;
    __syncthreads();
    for (int o = 128; o > 0; o >>= 1) { if (t < o) red[t] += red[t + o]; __syncthreads(); }
    if (t == 0) {
        double mean = total_sum / M;
        double var = red[0] / M - mean * mean;
        double sc = (double)g[j] / sqrt(var + BN_EPS);
        s[j] = (float)sc;
        tt[j] = (float)((double)b[j] - mean * sc);
    }
}

// -------------------------------------------- pool (BN2 folded) + head
__global__ __launch_bounds__(256) void pool_head(const float* __restrict__ H2, const int* __restrict__ goff,
                                                 const float* __restrict__ s2, const float* __restrict__ t2,
                                                 const float* __restrict__ fcxd_w, const float* __restrict__ fcxd_b,
                                                 const float* __restrict__ fc1_w, const float* __restrict__ fc1_b,
                                                 const float* __restrict__ fc2_w, const float* __restrict__ fc2_b,
                                                 const float* __restrict__ fc3_w, const float* __restrict__ fc3_b,
                                                 const float* __restrict__ fc4_w, const float* __restrict__ fc4_b,
                                                 const float* __restrict__ fc5_w, const float* __restrict__ fc5_b,
                                                 float* __restrict__ out) {
    __shared__ float red[256];
    __shared__ float p[64];
    __shared__ float z[64];
    int g = blockIdx.x, t = threadIdx.x;
    int r0 = goff[g], r1 = goff[g + 1];
    int cnt = r1 - r0;
    int j = t & 31, rr = t >> 5;
    float a = 0.f;
    for (int r = r0 + rr; r < r1; r += 8) a += H2[(size_t)r * DIM + j];
    red[t] = a;
    __syncthreads();
    if (t < 32) {
        float ssum = 0.f;
        for (int q = 0; q < 8; q++) ssum += red[q * 32 + j];
        p[j] = s2[j] * ssum + (float)cnt * t2[j];
    }
    __syncthreads();
    if (t < 64) {
        float acc = fcxd_b[t];
        for (int i = 0; i < 32; i++) acc += p[i] * fcxd_w[i * 64 + t];
        z[t] = fmaxf(acc, 0.f);
    }
    __syncthreads();
    if (t < 32) {
        float acc = fc1_b[t];
        for (int i = 0; i < 64; i++) acc += z[i] * fc1_w[i * 32 + t];
        p[t] = acc;
    }
    __syncthreads();
    if (t < 16) {
        float acc = fc2_b[t];
        for (int i = 0; i < 32; i++) acc += p[i] * fc2_w[i * 16 + t];
        z[t] = acc;
    }
    __syncthreads();
    if (t < 8) {
        float acc = fc3_b[t];
        for (int i = 0; i < 16; i++) acc += z[i] * fc3_w[i * 8 + t];
        p[t] = acc;
    }
    __syncthreads();
    if (t < 2) {
        float acc = fc4_b[t];
        for (int i = 0; i < 8; i++) acc += p[i] * fc4_w[i * 2 + t];
        z[t] = acc;
    }
    __syncthreads();
    if (t == 0) {
        out[g] = z[0] * fc5_w[0] + z[1] * fc5_w[1] + fc5_b[0];
    }
}

// ---------------------------------------------------------------- launch
extern "C" void kernel_launch(void* const* d_in, const int* in_sizes, int n_in,
                              void* d_out, int out_size, void* d_ws, size_t ws_size,
                              hipStream_t stream) {
    const float* x     = (const float*)d_in[0];
    const int*   src   = (const int*)d_in[1];
    const int*   dst   = (const int*)d_in[2];
    const int*   batch = (const int*)d_in[3];
    const float* g1_w1 = (const float*)d_in[4];
    const float* g1_b1 = (const float*)d_in[5];
    const float* g1_w2 = (const float*)d_in[6];
    const float* g1_b2 = (const float*)d_in[7];
    const float* bn1_g = (const float*)d_in[8];
    const float* bn1_b = (const float*)d_in[9];
    const float* g2_w1 = (const float*)d_in[10];
    const float* g2_b1 = (const float*)d_in[11];
    const float* g2_w2 = (const float*)d_in[12];
    const float* g2_b2 = (const float*)d_in[13];
    const float* bn2_g = (const float*)d_in[14];
    const float* bn2_b = (const float*)d_in[15];
    const float* fcxd_w = (const float*)d_in[16];
    const float* fcxd_b = (const float*)d_in[17];
    const float* fc1_w = (const float*)d_in[18];
    const float* fc1_b = (const float*)d_in[19];
    const float* fc2_w = (const float*)d_in[20];
    const float* fc2_b = (const float*)d_in[21];
    const float* fc3_w = (const float*)d_in[22];
    const float* fc3_b = (const float*)d_in[23];
    const float* fc4_w = (const float*)d_in[24];
    const float* fc4_b = (const float*)d_in[25];
    const float* fc5_w = (const float*)d_in[26];
    const float* fc5_b = (const float*)d_in[27];
    float* out = (float*)d_out;
    char* ws = (char*)d_ws;

    const int GEMM_MB = (N_NODES + 63) / 64;       // 782 (also BN partial blocks)

    size_t off = 0;
    auto take = [&](size_t bytes) { size_t o = off; off += (bytes + 255) & ~(size_t)255; return o; };
    int* bcur_pad  = (int*)(ws + take((size_t)NB * NREP * PAD * 4));    // zeroed (1.6 MB)
    size_t zero_bytes = off;
    int* bucket    = (int*)(ws + take((size_t)NB * NREP * RCAP * 4));
    int* perm_pad  = (int*)(ws + take((size_t)N_NODES * CAP * 4));
    int* deg       = (int*)(ws + take((size_t)N_NODES * 4));
    int* goff      = (int*)(ws + take((size_t)(N_GRAPHS + 4) * 4));
    float* s1      = (float*)(ws + take(F_IN * 4));
    float* t1      = (float*)(ws + take(F_IN * 4));
    float* s2      = (float*)(ws + take(DIM * 4));
    float* t2      = (float*)(ws + take(DIM * 4));
    float* c0      = (float*)(ws + take(DIM * 4));
    float* pb1     = (float*)(ws + take((size_t)GEMM_MB * 2 * F_IN * 4));
    float* pb2     = (float*)(ws + take((size_t)GEMM_MB * 2 * DIM * 4));
    unsigned short* w1h = (unsigned short*)(ws + take((size_t)F_IN * 128 * 2));
    unsigned short* w1l = (unsigned short*)(ws + take((size_t)F_IN * 128 * 2));
    unsigned short* w2h = (unsigned short*)(ws + take((size_t)F_IN * 128 * 2));
    unsigned short* w2l = (unsigned short*)(ws + take((size_t)F_IN * 128 * 2));
    unsigned short* w3h = (unsigned short*)(ws + take((size_t)DIM * 128 * 2));
    unsigned short* w3l = (unsigned short*)(ws + take((size_t)DIM * 128 * 2));
    unsigned short* w4h = (unsigned short*)(ws + take((size_t)DIM * 32 * 2));
    unsigned short* w4l = (unsigned short*)(ws + take((size_t)DIM * 32 * 2));
    __half* x_half = (__half*)(ws + take((size_t)N_NODES * HROW * 2));
    __half* y_half = (__half*)(ws + take((size_t)N_NODES * DIM * 2));
    float* bufA    = (float*)(ws + take((size_t)N_NODES * F_IN * 4));
    float* bufS1   = (float*)(ws + take((size_t)N_NODES * DIM * 4));
    float* bufS2   = (float*)(ws + take((size_t)N_NODES * DIM * 4));
    (void)ws_size; (void)in_sizes; (void)n_in; (void)out_size;

    hipMemsetAsync(ws, 0, zero_bytes, stream);

    // merged prep: bucket append (4 edges/thread, XCD-replicated) + x->fp16 +
    // weight splits + graph bounds — one launch.
    prep_kernel<<<PB_GB, 256, 0, stream>>>(src, dst, bcur_pad, bucket,
                                           x, x_half,
                                           g1_w1, w1h, w1l, g1_w2, w2h, w2l, g2_w2, w4h, w4l,
                                           batch, goff);
    bin_build<<<NB, 256, 0, stream>>>(bcur_pad, bucket, perm_pad, deg);

    const int AGG_BLOCKS = (N_NODES + 3) / 4;

    // GIN layer 1: agg -> fused 2-GEMM MLP -> parallel finalize
    agg_kernel<<<AGG_BLOCKS, 256, 0, stream>>>(x, x_half, deg, perm_pad, bufA, N_NODES);
    gemm_mlp112<<<GEMM_MB, 256, 0, stream>>>(bufA, w1h, w1l, g1_b1, w2h, w2l, g1_b2, bufA, pb1, N_NODES);
    bn_finalize_par<F_IN, 782><<<F_IN, 256, 0, stream>>>(pb1, bn1_g, bn1_b, s1, t1, N_NODES);

    // GIN layer 2: linear-first (BN1 folded), 32-wide agg, BN2 stats fused
    w3_fold<<<(DIM * 128 + 255) / 256, 256, 0, stream>>>(g2_w1, s1, t1, w3h, w3l, c0);
    gemm_mfma<2, 4, F_IN, false, DIM, false><<<GEMM_MB, 256, 0, stream>>>(bufA, w3h, w3l, nullptr, nullptr, y_half, nullptr, N_NODES);
    agg32_kernel<<<AGG_BLOCKS, 256, 0, stream>>>(y_half, deg, perm_pad, c0, g2_b1, bufS1, N_NODES);
    gemm_mfma<2, 1, DIM, true, 0, true><<<GEMM_MB, 256, 0, stream>>>(bufS1, w4h, w4l, g2_b2, bufS2, nullptr, pb2, N_NODES);
    bn_finalize_par<DIM, 782><<<DIM, 256, 0, stream>>>(pb2, bn2_g, bn2_b, s2, t2, N_NODES);

    // pool (BN2 folded) + dense head
    pool_head<<<N_GRAPHS, 256, 0, stream>>>(bufS2, goff, s2, t2,
                                            fcxd_w, fcxd_b, fc1_w, fc1_b, fc2_w, fc2_b,
                                            fc3_w, fc3_b, fc4_w, fc4_b, fc5_w, fc5_b, out);
}

// Round 16
// 278.992 us; speedup vs baseline: 1.4840x; 1.0898x over previous
//
#include <hip/hip_runtime.h>
#include <hip/hip_fp16.h>

#define N_NODES 50000
#define N_EDGES 800000
#define N_GRAPHS 256
#define F_IN 112
#define DIM 32
#define BN_EPS 1e-5
#define PAD 32     // ints per atomic slot: one 128-B line per cursor
#define HROW 128   // fp16 row stride (256 B = exactly 2 lines, zero waste)
#define CAP 64     // edge slots per node (P(deg>63) ~ 1e-19 for Poisson(16))
#define NB 1563    // buckets = ceil(50000/32)
#define NREP 8     // one bucket replica per XCD
#define RCAP 128   // entries per replica-bucket (Poisson(64), 8 sigma headroom)

typedef __attribute__((ext_vector_type(8))) _Float16 half8;
typedef __attribute__((ext_vector_type(4))) float float4v;

// ---- fp16 split helpers ----
__device__ inline unsigned short f2h_u(float f) {
    union { __half h; unsigned short u; } v; v.h = __float2half(f); return v.u;
}
__device__ inline float h2f_u(unsigned short u) {
    union { unsigned short u; __half h; } v; v.u = u; return __half2float(v.h);
}

// W[KxN] fp32 -> hi/lo fp16 [N][Kpad] (transposed, zero-padded)
__device__ inline void w_split_body(const float* __restrict__ W, int K, int N, int Kpad,
                                    unsigned short* __restrict__ hi_t,
                                    unsigned short* __restrict__ lo_t, int idx) {
    if (idx >= N * Kpad) return;
    int n = idx / Kpad, k = idx - n * Kpad;
    float v = (k < K) ? W[(size_t)k * N + n] : 0.f;
    unsigned short h = f2h_u(v);
    hi_t[idx] = h;
    lo_t[idx] = f2h_u(v - h2f_u(h));
}

// ---- merged prep: bucket_append FIRST (4 edges/thread), x->fp16, weight
//      splits, graph bounds.
#define PB_BA 782                    // ceil(800000 / (256*4))
#define PB_XH (PB_BA + 12500)        // 50000*64 half2 / 256
#define PB_W1 (PB_XH + 56)
#define PB_W2 (PB_W1 + 56)
#define PB_W4 (PB_W2 + 4)
#define PB_GB (PB_W4 + 196)
__global__ __launch_bounds__(256) void prep_kernel(const int* __restrict__ src, const int* __restrict__ dst,
                                                   int* __restrict__ bcur_pad, int* __restrict__ bucket,
                                                   const float* __restrict__ X, __half* __restrict__ Xh,
                                                   const float* __restrict__ g1_w1, unsigned short* w1h, unsigned short* w1l,
                                                   const float* __restrict__ g1_w2, unsigned short* w2h, unsigned short* w2l,
                                                   const float* __restrict__ g2_w2, unsigned short* w4h, unsigned short* w4l,
                                                   const int* __restrict__ batch, int* __restrict__ goff) {
    int b = blockIdx.x, t = threadIdx.x;
    if (b < PB_BA) {
        unsigned xcc = 0;
        asm volatile("s_getreg_b32 %0, hwreg(HW_REG_XCC_ID)" : "=s"(xcc));
        int r = (int)(xcc & (NREP - 1));
        int base = b * 1024 + t;
        int d[4], s[4];
#pragma unroll
        for (int j = 0; j < 4; j++) {
            int i = base + j * 256;
            if (i < N_EDGES) {
                d[j] = __builtin_nontemporal_load(dst + i);
                s[j] = __builtin_nontemporal_load(src + i);
            } else {
                d[j] = -1;
            }
        }
        int c[4];
#pragma unroll
        for (int j = 0; j < 4; j++) {
            if (d[j] >= 0) {
                size_t slot = (size_t)(d[j] >> 5) * NREP + r;
                c[j] = atomicAdd(&bcur_pad[slot * PAD], 1);
            }
        }
#pragma unroll
        for (int j = 0; j < 4; j++) {
            if (d[j] >= 0 && c[j] < RCAP) {
                size_t slot = (size_t)(d[j] >> 5) * NREP + r;
                bucket[slot * RCAP + c[j]] = ((d[j] & 31) << 16) | s[j];
            }
        }
    } else if (b < PB_XH) {
        int idx = (b - PB_BA) * 256 + t;
        if (idx >= N_NODES * (HROW / 2)) return;
        int row = idx / (HROW / 2), c2 = idx - row * (HROW / 2);
        int col = c2 * 2;
        float2 v = make_float2(0.f, 0.f);
        if (col < F_IN) v = *(const float2*)(X + (size_t)row * F_IN + col);
        ((__half2*)Xh)[idx] = __floats2half2_rn(v.x, v.y);
    } else if (b < PB_W1) {
        w_split_body(g1_w1, F_IN, F_IN, 128, w1h, w1l, (b - PB_XH) * 256 + t);
    } else if (b < PB_W2) {
        w_split_body(g1_w2, F_IN, F_IN, 128, w2h, w2l, (b - PB_W1) * 256 + t);
    } else if (b < PB_W4) {
        w_split_body(g2_w2, DIM, DIM, 32, w4h, w4l, (b - PB_W2) * 256 + t);
    } else {
        int i = (b - PB_W4) * 256 + t;
        if (i >= N_NODES) return;
        int cur = batch[i];
        int prev = (i == 0) ? -1 : batch[i - 1];
        for (int g = prev + 1; g <= cur; g++) goff[g] = i;
        if (i == N_NODES - 1) {
            for (int g = cur + 1; g <= N_GRAPHS; g++) goff[g] = N_NODES;
        }
    }
}

// ---------------- phase B: per-bucket LDS binning -> coalesced perm/deg write
__global__ __launch_bounds__(256) void bin_build(const int* __restrict__ bcur_pad,
                                                 const int* __restrict__ bucket,
                                                 int* __restrict__ perm_pad,
                                                 int* __restrict__ deg) {
    __shared__ int bins[32][CAP];
    __shared__ int lcur[32];
    int b = blockIdx.x, t = threadIdx.x;
    if (t < 32) lcur[t] = 0;
    __syncthreads();
    for (int r = 0; r < NREP; r++) {
        size_t slot = (size_t)b * NREP + r;
        int count = min(bcur_pad[slot * PAD], RCAP);
        for (int i = t; i < count; i += 256) {
            int e = bucket[slot * RCAP + i];
            int l = e >> 16, s = e & 0xFFFF;
            int c = atomicAdd(&lcur[l], 1);
            if (c < CAP) bins[l][c] = s;
        }
    }
    __syncthreads();
    if (t < 32) {
        int node = b * 32 + t;
        if (node < N_NODES) deg[node] = min(lcur[t], CAP);
    }
    for (int i = t; i < 32 * (CAP / 4); i += 256) {
        int l = i / (CAP / 4), q = i % (CAP / 4);
        int node = b * 32 + l;
        if (node < N_NODES) {
            ((int4*)&perm_pad[(size_t)node * CAP])[q] = ((const int4*)bins[l])[q];
        }
    }
}

// ------------------- layer-1 aggregation (wave per node), fp16 gather
// Output: fp16 [M][HROW] (pad cols zero, since x_half pad cols are zero).
__global__ __launch_bounds__(256) void agg_kernel(const float* __restrict__ X,
                                                  const __half* __restrict__ Xh,
                                                  const int* __restrict__ deg_arr,
                                                  const int* __restrict__ perm_pad,
                                                  __half* __restrict__ out, int M) {
    constexpr int P = F_IN / 2;
    int w = (blockIdx.x * 256 + threadIdx.x) >> 6;
    int lane = threadIdx.x & 63;
    if (w >= M) return;
    int deg = deg_arr[w];
    const int* pl = perm_pad + (size_t)w * CAP;
    float ax = 0.f, ay = 0.f;
    int e = 0;
    for (; e + 16 <= deg; e += 16) {
        int s[16];
#pragma unroll
        for (int j = 0; j < 16; j++) s[j] = pl[e + j];
        float2 v[16];
#pragma unroll
        for (int j = 0; j < 16; j++)
            v[j] = __half22float2(*(const __half2*)(Xh + (size_t)s[j] * HROW + 2 * lane));
#pragma unroll
        for (int j = 0; j < 16; j++) { ax += v[j].x; ay += v[j].y; }
    }
    for (; e + 4 <= deg; e += 4) {
        int s0 = pl[e], s1 = pl[e + 1], s2 = pl[e + 2], s3 = pl[e + 3];
        float2 v0 = __half22float2(*(const __half2*)(Xh + (size_t)s0 * HROW + 2 * lane));
        float2 v1 = __half22float2(*(const __half2*)(Xh + (size_t)s1 * HROW + 2 * lane));
        float2 v2 = __half22float2(*(const __half2*)(Xh + (size_t)s2 * HROW + 2 * lane));
        float2 v3 = __half22float2(*(const __half2*)(Xh + (size_t)s3 * HROW + 2 * lane));
        ax += (v0.x + v1.x) + (v2.x + v3.x);
        ay += (v0.y + v1.y) + (v2.y + v3.y);
    }
    for (; e < deg; e++) {
        int s = pl[e];
        float2 v = __half22float2(*(const __half2*)(Xh + (size_t)s * HROW + 2 * lane));
        ax += v.x;
        ay += v.y;
    }
    float2 self = make_float2(0.f, 0.f);
    if (lane < P) self = *(const float2*)(X + (size_t)w * F_IN + 2 * lane);
    ((__half2*)(out + (size_t)w * HROW))[lane] = __floats2half2_rn(self.x + ax, self.y + ay);
}

// ---------- layer-2 aggregation on 32-wide fp16 y rows; fp16 output
__global__ __launch_bounds__(256) void agg32_kernel(const __half* __restrict__ Y,
                                                    const int* __restrict__ deg_arr,
                                                    const int* __restrict__ perm_pad,
                                                    const float* __restrict__ c0,
                                                    const float* __restrict__ b1,
                                                    __half* __restrict__ out, int M) {
    int w = (blockIdx.x * 256 + threadIdx.x) >> 6;
    int lane = threadIdx.x & 63;
    if (w >= M) return;
    int f = lane & 15;
    int g = lane >> 4;
    int deg = deg_arr[w];
    const int* pl = perm_pad + (size_t)w * CAP;
    float ax = 0.f, ay = 0.f;
    int e = g;
    for (; e + 4 < deg; e += 8) {
        int s0 = pl[e], s1 = pl[e + 4];
        float2 v0 = __half22float2(*(const __half2*)(Y + (size_t)s0 * DIM + 2 * f));
        float2 v1 = __half22float2(*(const __half2*)(Y + (size_t)s1 * DIM + 2 * f));
        ax += v0.x + v1.x;
        ay += v0.y + v1.y;
    }
    if (e < deg) {
        int s0 = pl[e];
        float2 v0 = __half22float2(*(const __half2*)(Y + (size_t)s0 * DIM + 2 * f));
        ax += v0.x;
        ay += v0.y;
    }
    ax += __shfl_xor(ax, 16); ax += __shfl_xor(ax, 32);
    ay += __shfl_xor(ay, 16); ay += __shfl_xor(ay, 32);
    if (g == 0) {
        float2 self = __half22float2(*(const __half2*)(Y + (size_t)w * DIM + 2 * f));
        float deg1 = (float)(deg + 1);
        float zx = fmaxf(self.x + ax + deg1 * c0[2 * f] + b1[2 * f], 0.f);
        float zy = fmaxf(self.y + ay + deg1 * c0[2 * f + 1] + b1[2 * f + 1], 0.f);
        ((__half2*)(out + (size_t)w * DIM))[f] = __floats2half2_rn(zx, zy);
    }
}

// ------- BN1-folded W3 split (fp16 hi/lo): W3'[k][n]=s1[k]W3[k][n]; c0[n]=Σt1[k]W3[k][n]
__global__ __launch_bounds__(256) void w3_fold(const float* __restrict__ W,
                                               const float* __restrict__ s1,
                                               const float* __restrict__ t1,
                                               unsigned short* __restrict__ hi_t,
                                               unsigned short* __restrict__ lo_t,
                                               float* __restrict__ c0) {
    int idx = blockIdx.x * 256 + threadIdx.x;
    if (idx < DIM * 128) {
        int n = idx >> 7, k = idx & 127;
        float v = (k < F_IN) ? s1[k] * W[(size_t)k * DIM + n] : 0.f;
        unsigned short h = f2h_u(v);
        hi_t[idx] = h;
        lo_t[idx] = f2h_u(v - h2f_u(h));
    }
    if (blockIdx.x == 0 && threadIdx.x < DIM) {
        int n = threadIdx.x;
        float acc = 0.f;
        for (int k = 0; k < F_IN; k++) acc += t1[k] * W[(size_t)k * DIM + n];
        c0[n] = acc;
    }
}

// ------- FUSED layer-1 MLP (fp16): H1 = relu(relu(A@W1+b1)@W2+b2), + BN1 stats
// A: fp16 [M][HROW]. W1/W2: fp16 hi/lo [112][128]. Output: fp16 [M][HROW]
// (cols 112..127 zeroed). 2 MFMA per n-tile per chunk. LDS ~35 KB.
__global__ __launch_bounds__(256) void gemm_mlp112(const unsigned short* __restrict__ A,
                                                   const unsigned short* __restrict__ W1h,
                                                   const unsigned short* __restrict__ W1l,
                                                   const float* __restrict__ b1,
                                                   const unsigned short* __restrict__ W2h,
                                                   const unsigned short* __restrict__ W2l,
                                                   const float* __restrict__ b2,
                                                   __half* __restrict__ Ch,
                                                   float* __restrict__ pbuf, int M) {
    constexpr int NT = 7, N = 112, Kpad = 128, TS = 136;
    __shared__ __align__(16) char smem[64 * TS * 2 + 2 * N * 32 * 2 + 64 * 32 * 2];
    unsigned short* T1 = (unsigned short*)smem;                       // 17408 B
    unsigned short* Wh = (unsigned short*)(smem + 64 * TS * 2);       // 7168 B
    unsigned short* Wl = Wh + N * 32;                                 // 7168 B
    unsigned short* Ah = Wl + N * 32;                                 // 4096 B (phase 1)
    float* sls = (float*)Ah;                                          // 3584 B (epilogue, aliases Ah)
    int t = threadIdx.x;
    int lane = t & 63, wid = t >> 6;
    int r0 = blockIdx.x * 64;
    int m = lane & 15, quad = lane >> 4;

    // zero T1 pad cols [112,128)
    for (int i = t; i < 64 * 16; i += 256) {
        T1[(i >> 4) * TS + 112 + (i & 15)] = 0;
    }

    float4v acc[NT];
#pragma unroll
    for (int nt = 0; nt < NT; nt++) acc[nt] = (float4v){0.f, 0.f, 0.f, 0.f};

    // ---- phase 1: acc = A @ W1 (raw fp16 staging) ----
    for (int c = 0; c < 4; c++) {
        int kc = c * 32;
        {
            int row = t >> 2, seg = t & 3;
            int grow = r0 + row;
            uint4 v = make_uint4(0, 0, 0, 0);
            if (grow < M) v = *(const uint4*)(A + (size_t)grow * HROW + kc + seg * 8);
            *(uint4*)&Ah[row * 32 + seg * 8] = v;
        }
        for (int idx = t; idx < N * 8; idx += 256) {
            int n = idx >> 3, w = idx & 7;
            int gsrc = n * (Kpad / 4) + (kc >> 2) + w;
            ((uint2*)Wh)[idx] = ((const uint2*)W1h)[gsrc];
            ((uint2*)Wl)[idx] = ((const uint2*)W1l)[gsrc];
        }
        __syncthreads();
        half8 a = *(const half8*)&Ah[(wid * 16 + m) * 32 + quad * 8];
#pragma unroll
        for (int nt = 0; nt < NT; nt++) {
            half8 b_h = *(const half8*)&Wh[(nt * 16 + m) * 32 + quad * 8];
            half8 b_l = *(const half8*)&Wl[(nt * 16 + m) * 32 + quad * 8];
            acc[nt] = __builtin_amdgcn_mfma_f32_16x16x32_f16(a, b_h, acc[nt], 0, 0, 0);
            acc[nt] = __builtin_amdgcn_mfma_f32_16x16x32_f16(a, b_l, acc[nt], 0, 0, 0);
        }
        __syncthreads();
    }

    // ---- tile1 = relu(acc + b1) -> LDS fp16 ----
#pragma unroll
    for (int nt = 0; nt < NT; nt++) {
        int col = nt * 16 + m;
        float bb = b1[col];
#pragma unroll
        for (int r = 0; r < 4; r++) {
            int row = wid * 16 + quad * 4 + r;
            T1[row * TS + col] = f2h_u(fmaxf(acc[nt][r] + bb, 0.f));
        }
        acc[nt] = (float4v){0.f, 0.f, 0.f, 0.f};
    }
    __syncthreads();

    // ---- phase 2: acc = tile1 @ W2 ----
    for (int c = 0; c < 4; c++) {
        int kc = c * 32;
        for (int idx = t; idx < N * 8; idx += 256) {
            int n = idx >> 3, w = idx & 7;
            int gsrc = n * (Kpad / 4) + (kc >> 2) + w;
            ((uint2*)Wh)[idx] = ((const uint2*)W2h)[gsrc];
            ((uint2*)Wl)[idx] = ((const uint2*)W2l)[gsrc];
        }
        __syncthreads();
        half8 a = *(const half8*)&T1[(wid * 16 + m) * TS + kc + quad * 8];
#pragma unroll
        for (int nt = 0; nt < NT; nt++) {
            half8 b_h = *(const half8*)&Wh[(nt * 16 + m) * 32 + quad * 8];
            half8 b_l = *(const half8*)&Wl[(nt * 16 + m) * 32 + quad * 8];
            acc[nt] = __builtin_amdgcn_mfma_f32_16x16x32_f16(a, b_h, acc[nt], 0, 0, 0);
            acc[nt] = __builtin_amdgcn_mfma_f32_16x16x32_f16(a, b_l, acc[nt], 0, 0, 0);
        }
        __syncthreads();
    }

    // ---- epilogue: bias2 + relu + fp16 store + zero pad cols + BN1 stats ----
    float st_s[NT], st_q[NT];
#pragma unroll
    for (int nt = 0; nt < NT; nt++) {
        int col = nt * 16 + m;
        float bb = b2[col];
        float s_loc = 0.f, q_loc = 0.f;
#pragma unroll
        for (int r = 0; r < 4; r++) {
            int row = r0 + wid * 16 + quad * 4 + r;
            float v = fmaxf(acc[nt][r] + bb, 0.f);
            if (row < M) {
                Ch[(size_t)row * HROW + col] = __float2half(v);
                s_loc += v;
                q_loc += v * v;
            }
        }
        st_s[nt] = s_loc;
        st_q[nt] = q_loc;
    }
    // zero pad cols 112..127 of this row-tile
    for (int i = t; i < 64 * 2; i += 256) {
        int row = r0 + (i >> 1), o = (i & 1) * 8;
        if (row < M) *(uint4*)((unsigned short*)Ch + (size_t)row * HROW + 112 + o) = make_uint4(0, 0, 0, 0);
    }
#pragma unroll
    for (int nt = 0; nt < NT; nt++) {
        float s = st_s[nt], q = st_q[nt];
        s += __shfl_xor(s, 16); s += __shfl_xor(s, 32);
        q += __shfl_xor(q, 16); q += __shfl_xor(q, 32);
        if (quad == 0) {
            sls[wid * 2 * N + nt * 16 + m] = s;
            sls[wid * 2 * N + N + nt * 16 + m] = q;
        }
    }
    __syncthreads();
    for (int j = t; j < 2 * N; j += 256) {
        pbuf[(size_t)blockIdx.x * 2 * N + j] = sls[0 * 2 * N + j] + sls[1 * 2 * N + j] +
                                               sls[2 * 2 * N + j] + sls[3 * 2 * N + j];
    }
}

// ---------- fp16 MFMA GEMM: C/Ch = act(A_f16 @ W + bias), W fp16 hi+lo
// A: fp16 [M][AS]. 2 MFMA per n-tile per chunk.
template <int NT, int KC, int AS, bool RELU, int CHS, bool STATS>
__global__ __launch_bounds__(256) void gemm_mfma_h(const unsigned short* __restrict__ A,
                                                   const unsigned short* __restrict__ Whi,
                                                   const unsigned short* __restrict__ Wlo,
                                                   const float* __restrict__ bias,
                                                   float* __restrict__ C,
                                                   __half* __restrict__ Ch,
                                                   float* __restrict__ pbuf, int M) {
    constexpr int N = NT * 16;
    constexpr int Kpad = KC * 32;
    __shared__ __align__(16) unsigned short Ah[64 * 32];
    __shared__ __align__(16) unsigned short Wh[N * 32];
    __shared__ __align__(16) unsigned short Wl[N * 32];
    int t = threadIdx.x;
    int lane = t & 63, wid = t >> 6;
    int r0 = blockIdx.x * 64;
    int m = lane & 15, quad = lane >> 4;

    float4v acc[NT];
#pragma unroll
    for (int nt = 0; nt < NT; nt++) acc[nt] = (float4v){0.f, 0.f, 0.f, 0.f};

    for (int c = 0; c < KC; c++) {
        int kc = c * 32;
        {
            int row = t >> 2, seg = t & 3;
            int grow = r0 + row;
            uint4 v = make_uint4(0, 0, 0, 0);
            if (grow < M) v = *(const uint4*)(A + (size_t)grow * AS + kc + seg * 8);
            *(uint4*)&Ah[row * 32 + seg * 8] = v;
        }
        for (int idx = t; idx < N * 8; idx += 256) {
            int n = idx >> 3, w = idx & 7;
            int gsrc = n * (Kpad / 4) + (kc >> 2) + w;
            ((uint2*)Wh)[idx] = ((const uint2*)Whi)[gsrc];
            ((uint2*)Wl)[idx] = ((const uint2*)Wlo)[gsrc];
        }
        __syncthreads();
        half8 a = *(const half8*)&Ah[(wid * 16 + m) * 32 + quad * 8];
#pragma unroll
        for (int nt = 0; nt < NT; nt++) {
            half8 b_h = *(const half8*)&Wh[(nt * 16 + m) * 32 + quad * 8];
            half8 b_l = *(const half8*)&Wl[(nt * 16 + m) * 32 + quad * 8];
            acc[nt] = __builtin_amdgcn_mfma_f32_16x16x32_f16(a, b_h, acc[nt], 0, 0, 0);
            acc[nt] = __builtin_amdgcn_mfma_f32_16x16x32_f16(a, b_l, acc[nt], 0, 0, 0);
        }
        __syncthreads();
    }
    float st_s[NT], st_q[NT];
#pragma unroll
    for (int nt = 0; nt < NT; nt++) {
        int col = nt * 16 + m;
        float b = bias ? bias[col] : 0.f;
        float s_loc = 0.f, q_loc = 0.f;
#pragma unroll
        for (int r = 0; r < 4; r++) {
            int row = r0 + wid * 16 + quad * 4 + r;
            float v = acc[nt][r] + b;
            if (RELU) v = fmaxf(v, 0.f);
            if (row < M) {
                if (C) C[(size_t)row * N + col] = v;
                if (Ch) Ch[(size_t)row * CHS + col] = __float2half(v);
                if (STATS) { s_loc += v; q_loc += v * v; }
            }
        }
        st_s[nt] = s_loc;
        st_q[nt] = q_loc;
    }
    if constexpr (STATS) {
        __shared__ float sls[4][2 * N];
#pragma unroll
        for (int nt = 0; nt < NT; nt++) {
            float s = st_s[nt], q = st_q[nt];
            s += __shfl_xor(s, 16); s += __shfl_xor(s, 32);
            q += __shfl_xor(q, 16); q += __shfl_xor(q, 32);
            if (quad == 0) {
                sls[wid][nt * 16 + m] = s;
                sls[wid][N + nt * 16 + m] = q;
            }
        }
        __syncthreads();
        for (int j = t; j < 2 * N; j += 256) {
            pbuf[(size_t)blockIdx.x * 2 * N + j] = sls[0][j] + sls[1][j] + sls[2][j] + sls[3][j];
        }
    }
}

// --------- parallel BN finalize: one block per feature, 256-thread reduce
template <int F, int BLOCKS>
__global__ __launch_bounds__(256) void bn_finalize_par(const float* __restrict__ pbuf,
                                                       const float* __restrict__ g,
                                                       const float* __restrict__ b,
                                                       float* __restrict__ s,
                                                       float* __restrict__ tt, int M) {
    __shared__ double red[256];
    int j = blockIdx.x;
    int t = threadIdx.x;
    double sum = 0.0, sq = 0.0;
    for (int i = t; i < BLOCKS; i += 256) {
        sum += (double)pbuf[(size_t)i * 2 * F + j];
        sq  += (double)pbuf[(size_t)i * 2 * F + F + j];
    }
    red[t] = sum;
    __syncthreads();
    for (int o = 128; o > 0; o >>= 1) { if (t < o) red[t] += red[t + o]; __syncthreads(); }
    double total_sum = red[0];
    __syncthreads();
    red[t] = sq;
    __syncthreads();
    for (int o = 128; o > 0; o >>= 1) { if (t < o) red[t] += red[t + o]; __syncthreads(); }
    if (t == 0) {
        double mean = total_sum / M;
        double var = red[0] / M - mean * mean;
        double sc = (double)g[j] / sqrt(var + BN_EPS);
        s[j] = (float)sc;
        tt[j] = (float)((double)b[j] - mean * sc);
    }
}

// -------------------------------------------- pool (BN2 folded) + head
__global__ __launch_bounds__(256) void pool_head(const float* __restrict__ H2, const int* __restrict__ goff,
                                                 const float* __restrict__ s2, const float* __restrict__ t2,
                                                 const float* __restrict__ fcxd_w, const float* __restrict__ fcxd_b,
                                                 const float* __restrict__ fc1_w, const float* __restrict__ fc1_b,
                                                 const float* __restrict__ fc2_w, const float* __restrict__ fc2_b,
                                                 const float* __restrict__ fc3_w, const float* __restrict__ fc3_b,
                                                 const float* __restrict__ fc4_w, const float* __restrict__ fc4_b,
                                                 const float* __restrict__ fc5_w, const float* __restrict__ fc5_b,
                                                 float* __restrict__ out) {
    __shared__ float red[256];
    __shared__ float p[64];
    __shared__ float z[64];
    int g = blockIdx.x, t = threadIdx.x;
    int r0 = goff[g], r1 = goff[g + 1];
    int cnt = r1 - r0;
    int j = t & 31, rr = t >> 5;
    float a = 0.f;
    for (int r = r0 + rr; r < r1; r += 8) a += H2[(size_t)r * DIM + j];
    red[t] = a;
    __syncthreads();
    if (t < 32) {
        float ssum = 0.f;
        for (int q = 0; q < 8; q++) ssum += red[q * 32 + j];
        p[j] = s2[j] * ssum + (float)cnt * t2[j];
    }
    __syncthreads();
    if (t < 64) {
        float acc = fcxd_b[t];
        for (int i = 0; i < 32; i++) acc += p[i] * fcxd_w[i * 64 + t];
        z[t] = fmaxf(acc, 0.f);
    }
    __syncthreads();
    if (t < 32) {
        float acc = fc1_b[t];
        for (int i = 0; i < 64; i++) acc += z[i] * fc1_w[i * 32 + t];
        p[t] = acc;
    }
    __syncthreads();
    if (t < 16) {
        float acc = fc2_b[t];
        for (int i = 0; i < 32; i++) acc += p[i] * fc2_w[i * 16 + t];
        z[t] = acc;
    }
    __syncthreads();
    if (t < 8) {
        float acc = fc3_b[t];
        for (int i = 0; i < 16; i++) acc += z[i] * fc3_w[i * 8 + t];
        p[t] = acc;
    }
    __syncthreads();
    if (t < 2) {
        float acc = fc4_b[t];
        for (int i = 0; i < 8; i++) acc += p[i] * fc4_w[i * 2 + t];
        z[t] = acc;
    }
    __syncthreads();
    if (t == 0) {
        out[g] = z[0] * fc5_w[0] + z[1] * fc5_w[1] + fc5_b[0];
    }
}

// ---------------------------------------------------------------- launch
extern "C" void kernel_launch(void* const* d_in, const int* in_sizes, int n_in,
                              void* d_out, int out_size, void* d_ws, size_t ws_size,
                              hipStream_t stream) {
    const float* x     = (const float*)d_in[0];
    const int*   src   = (const int*)d_in[1];
    const int*   dst   = (const int*)d_in[2];
    const int*   batch = (const int*)d_in[3];
    const float* g1_w1 = (const float*)d_in[4];
    const float* g1_b1 = (const float*)d_in[5];
    const float* g1_w2 = (const float*)d_in[6];
    const float* g1_b2 = (const float*)d_in[7];
    const float* bn1_g = (const float*)d_in[8];
    const float* bn1_b = (const float*)d_in[9];
    const float* g2_w1 = (const float*)d_in[10];
    const float* g2_b1 = (const float*)d_in[11];
    const float* g2_w2 = (const float*)d_in[12];
    const float* g2_b2 = (const float*)d_in[13];
    const float* bn2_g = (const float*)d_in[14];
    const float* bn2_b = (const float*)d_in[15];
    const float* fcxd_w = (const float*)d_in[16];
    const float* fcxd_b = (const float*)d_in[17];
    const float* fc1_w = (const float*)d_in[18];
    const float* fc1_b = (const float*)d_in[19];
    const float* fc2_w = (const float*)d_in[20];
    const float* fc2_b = (const float*)d_in[21];
    const float* fc3_w = (const float*)d_in[22];
    const float* fc3_b = (const float*)d_in[23];
    const float* fc4_w = (const float*)d_in[24];
    const float* fc4_b = (const float*)d_in[25];
    const float* fc5_w = (const float*)d_in[26];
    const float* fc5_b = (const float*)d_in[27];
    float* out = (float*)d_out;
    char* ws = (char*)d_ws;

    const int GEMM_MB = (N_NODES + 63) / 64;       // 782

    size_t off = 0;
    auto take = [&](size_t bytes) { size_t o = off; off += (bytes + 255) & ~(size_t)255; return o; };
    int* bcur_pad  = (int*)(ws + take((size_t)NB * NREP * PAD * 4));    // zeroed
    size_t zero_bytes = off;
    int* bucket    = (int*)(ws + take((size_t)NB * NREP * RCAP * 4));
    int* perm_pad  = (int*)(ws + take((size_t)N_NODES * CAP * 4));
    int* deg       = (int*)(ws + take((size_t)N_NODES * 4));
    int* goff      = (int*)(ws + take((size_t)(N_GRAPHS + 4) * 4));
    float* s1      = (float*)(ws + take(F_IN * 4));
    float* t1      = (float*)(ws + take(F_IN * 4));
    float* s2      = (float*)(ws + take(DIM * 4));
    float* t2      = (float*)(ws + take(DIM * 4));
    float* c0      = (float*)(ws + take(DIM * 4));
    float* pb1     = (float*)(ws + take((size_t)GEMM_MB * 2 * F_IN * 4));
    float* pb2     = (float*)(ws + take((size_t)GEMM_MB * 2 * DIM * 4));
    unsigned short* w1h = (unsigned short*)(ws + take((size_t)F_IN * 128 * 2));
    unsigned short* w1l = (unsigned short*)(ws + take((size_t)F_IN * 128 * 2));
    unsigned short* w2h = (unsigned short*)(ws + take((size_t)F_IN * 128 * 2));
    unsigned short* w2l = (unsigned short*)(ws + take((size_t)F_IN * 128 * 2));
    unsigned short* w3h = (unsigned short*)(ws + take((size_t)DIM * 128 * 2));
    unsigned short* w3l = (unsigned short*)(ws + take((size_t)DIM * 128 * 2));
    unsigned short* w4h = (unsigned short*)(ws + take((size_t)DIM * 32 * 2));
    unsigned short* w4l = (unsigned short*)(ws + take((size_t)DIM * 32 * 2));
    __half* x_half = (__half*)(ws + take((size_t)N_NODES * HROW * 2));
    __half* aggA   = (__half*)(ws + take((size_t)N_NODES * HROW * 2));
    __half* h1h    = (__half*)(ws + take((size_t)N_NODES * HROW * 2));
    __half* y_half = (__half*)(ws + take((size_t)N_NODES * DIM * 2));
    __half* s1h    = (__half*)(ws + take((size_t)N_NODES * DIM * 2));
    float* bufS2   = (float*)(ws + take((size_t)N_NODES * DIM * 4));
    (void)ws_size; (void)in_sizes; (void)n_in; (void)out_size;

    hipMemsetAsync(ws, 0, zero_bytes, stream);

    // merged prep + graph build
    prep_kernel<<<PB_GB, 256, 0, stream>>>(src, dst, bcur_pad, bucket,
                                           x, x_half,
                                           g1_w1, w1h, w1l, g1_w2, w2h, w2l, g2_w2, w4h, w4l,
                                           batch, goff);
    bin_build<<<NB, 256, 0, stream>>>(bcur_pad, bucket, perm_pad, deg);

    const int AGG_BLOCKS = (N_NODES + 3) / 4;

    // GIN layer 1: agg (fp16 out) -> fused fp16 MLP (+BN1 stats) -> finalize
    agg_kernel<<<AGG_BLOCKS, 256, 0, stream>>>(x, x_half, deg, perm_pad, aggA, N_NODES);
    gemm_mlp112<<<GEMM_MB, 256, 0, stream>>>((const unsigned short*)aggA, w1h, w1l, g1_b1,
                                             w2h, w2l, g1_b2, h1h, pb1, N_NODES);
    bn_finalize_par<F_IN, 782><<<F_IN, 256, 0, stream>>>(pb1, bn1_g, bn1_b, s1, t1, N_NODES);

    // GIN layer 2: linear-first (BN1 folded), 32-wide agg, BN2 stats fused
    w3_fold<<<(DIM * 128 + 255) / 256, 256, 0, stream>>>(g2_w1, s1, t1, w3h, w3l, c0);
    gemm_mfma_h<2, 4, HROW, false, DIM, false><<<GEMM_MB, 256, 0, stream>>>(
        (const unsigned short*)h1h, w3h, w3l, nullptr, nullptr, y_half, nullptr, N_NODES);
    agg32_kernel<<<AGG_BLOCKS, 256, 0, stream>>>(y_half, deg, perm_pad, c0, g2_b1, s1h, N_NODES);
    gemm_mfma_h<2, 1, DIM, true, 0, true><<<GEMM_MB, 256, 0, stream>>>(
        (const unsigned short*)s1h, w4h, w4l, g2_b2, bufS2, nullptr, pb2, N_NODES);
    bn_finalize_par<DIM, 782><<<DIM, 256, 0, stream>>>(pb2, bn2_g, bn2_b, s2, t2, N_NODES);

    // pool (BN2 folded) + dense head
    pool_head<<<N_GRAPHS, 256, 0, stream>>>(bufS2, goff, s2, t2,
                                            fcxd_w, fcxd_b, fc1_w, fc1_b, fc2_w, fc2_b,
                                            fc3_w, fc3_b, fc4_w, fc4_b, fc5_w, fc5_b, out);
}

// Round 17
// 251.069 us; speedup vs baseline: 1.6490x; 1.1112x over previous
//
#include <hip/hip_runtime.h>
#include <hip/hip_fp16.h>

#define N_NODES 50000
#define N_EDGES 800000
#define N_GRAPHS 256
#define F_IN 112
#define DIM 32
#define BN_EPS 1e-5
#define HROW 128   // fp16 row stride (256 B = exactly 2 lines, zero waste)
#define CAP 64     // edge slots per node (P(deg>63) ~ 1e-19 for Poisson(16))
#define CB 391     // coarse buckets of 128 nodes (ceil(50000/128))
#define CBCAP 2560 // entries per coarse bucket (Poisson(2046) + 11 sigma)
#define CHUNK 8192 // edges per partition block
#define NPART 98   // ceil(800000/8192)

typedef __attribute__((ext_vector_type(8))) _Float16 half8;
typedef __attribute__((ext_vector_type(4))) float float4v;

// ---- fp16 split helpers ----
__device__ inline unsigned short f2h_u(float f) {
    union { __half h; unsigned short u; } v; v.h = __float2half(f); return v.u;
}
__device__ inline float h2f_u(unsigned short u) {
    union { unsigned short u; __half h; } v; v.u = u; return __half2float(v.h);
}

// W[KxN] fp32 -> hi/lo fp16 [N][Kpad] (transposed, zero-padded)
__device__ inline void w_split_body(const float* __restrict__ W, int K, int N, int Kpad,
                                    unsigned short* __restrict__ hi_t,
                                    unsigned short* __restrict__ lo_t, int idx) {
    if (idx >= N * Kpad) return;
    int n = idx / Kpad, k = idx - n * Kpad;
    float v = (k < K) ? W[(size_t)k * N + n] : 0.f;
    unsigned short h = f2h_u(v);
    hi_t[idx] = h;
    lo_t[idx] = f2h_u(v - h2f_u(h));
}

// ---- edge partition: block-local LDS counting sort -> coalesced bucket runs
// Entry packed (dst<<16)|src (both < 65536).
__global__ __launch_bounds__(1024) void edge_partition(const int* __restrict__ src,
                                                       const int* __restrict__ dst,
                                                       int* __restrict__ gcur,     // [CB], zeroed
                                                       int* __restrict__ bucket) { // [CB][CBCAP]
    __shared__ int hist[512];
    __shared__ int lofs[512];
    __shared__ int lcur[512];
    __shared__ int gbase[512];
    __shared__ int staging[CHUNK];
    int t = threadIdx.x;
    int base = blockIdx.x * CHUNK;
    int total = min(CHUNK, N_EDGES - base);
    for (int i = t; i < 512; i += 1024) hist[i] = 0;
    __syncthreads();
    int d[8], s[8];
#pragma unroll
    for (int j = 0; j < 8; j++) {
        int i = base + j * 1024 + t;
        if (i < N_EDGES) {
            d[j] = __builtin_nontemporal_load(dst + i);
            s[j] = __builtin_nontemporal_load(src + i);
        } else {
            d[j] = -1;
        }
    }
#pragma unroll
    for (int j = 0; j < 8; j++) {
        if (d[j] >= 0) atomicAdd(&hist[d[j] >> 7], 1);
    }
    __syncthreads();
    // inclusive scan of hist[0..511] into lofs
    if (t < 512) lofs[t] = hist[t];
    __syncthreads();
    for (int o = 1; o < 512; o <<= 1) {
        int add = (t < 512 && t >= o) ? lofs[t - o] : 0;
        __syncthreads();
        if (t < 512) lofs[t] += add;
        __syncthreads();
    }
    // reserve global segments + init chunk-local cursors to exclusive starts
    if (t < CB) {
        gbase[t] = (hist[t] > 0) ? atomicAdd(&gcur[t], hist[t]) : 0;
    }
    if (t < 512) lcur[t] = lofs[t] - hist[t];
    __syncthreads();
    // re-scatter into bucket-sorted staging
#pragma unroll
    for (int j = 0; j < 8; j++) {
        if (d[j] >= 0) {
            int b = d[j] >> 7;
            int p = atomicAdd(&lcur[b], 1);
            staging[p] = (d[j] << 16) | s[j];
        }
    }
    __syncthreads();
    // linear copy-out: consecutive staging positions -> consecutive global slots
    for (int p = t; p < total; p += 1024) {
        int e = staging[p];
        int b = ((unsigned)e >> 16) >> 7;
        int ls = lofs[b] - hist[b];
        int di = gbase[b] + (p - ls);
        if (di < CBCAP) bucket[(size_t)b * CBCAP + di] = e;
    }
}

// ---- merged prep: x->fp16 rows, 3 weight splits, graph bounds
#define PB_XH 12500                  // 50000*64 half2 / 256
#define PB_W1 (PB_XH + 56)
#define PB_W2 (PB_W1 + 56)
#define PB_W4 (PB_W2 + 4)
#define PB_GB (PB_W4 + 196)
__global__ __launch_bounds__(256) void prep_kernel(const float* __restrict__ X, __half* __restrict__ Xh,
                                                   const float* __restrict__ g1_w1, unsigned short* w1h, unsigned short* w1l,
                                                   const float* __restrict__ g1_w2, unsigned short* w2h, unsigned short* w2l,
                                                   const float* __restrict__ g2_w2, unsigned short* w4h, unsigned short* w4l,
                                                   const int* __restrict__ batch, int* __restrict__ goff) {
    int b = blockIdx.x, t = threadIdx.x;
    if (b < PB_XH) {
        int idx = b * 256 + t;
        if (idx >= N_NODES * (HROW / 2)) return;
        int row = idx / (HROW / 2), c2 = idx - row * (HROW / 2);
        int col = c2 * 2;
        float2 v = make_float2(0.f, 0.f);
        if (col < F_IN) v = *(const float2*)(X + (size_t)row * F_IN + col);
        ((__half2*)Xh)[idx] = __floats2half2_rn(v.x, v.y);
    } else if (b < PB_W1) {
        w_split_body(g1_w1, F_IN, F_IN, 128, w1h, w1l, (b - PB_XH) * 256 + t);
    } else if (b < PB_W2) {
        w_split_body(g1_w2, F_IN, F_IN, 128, w2h, w2l, (b - PB_W1) * 256 + t);
    } else if (b < PB_W4) {
        w_split_body(g2_w2, DIM, DIM, 32, w4h, w4l, (b - PB_W2) * 256 + t);
    } else {
        int i = (b - PB_W4) * 256 + t;
        if (i >= N_NODES) return;
        int cur = batch[i];
        int prev = (i == 0) ? -1 : batch[i - 1];
        for (int g = prev + 1; g <= cur; g++) goff[g] = i;
        if (i == N_NODES - 1) {
            for (int g = cur + 1; g <= N_GRAPHS; g++) goff[g] = N_NODES;
        }
    }
}

// ---- bin_build: one block per 128-node coarse bucket -> perm/deg coalesced
__global__ __launch_bounds__(1024) void bin_build(const int* __restrict__ gcur,
                                                  const int* __restrict__ bucket,
                                                  int* __restrict__ perm_pad,
                                                  int* __restrict__ deg) {
    __shared__ int bins[128][CAP];   // 32 KB
    __shared__ int lcur[128];
    int b = blockIdx.x, t = threadIdx.x;
    if (t < 128) lcur[t] = 0;
    __syncthreads();
    int count = min(gcur[b], CBCAP);
    for (int i = t; i < count; i += 1024) {
        int e = bucket[(size_t)b * CBCAP + i];
        int l = ((unsigned)e >> 16) & 127;
        int s = e & 0xFFFF;
        int c = atomicAdd(&lcur[l], 1);
        if (c < CAP) bins[l][c] = s;
    }
    __syncthreads();
    if (t < 128) {
        int node = b * 128 + t;
        if (node < N_NODES) deg[node] = min(lcur[t], CAP);
    }
    for (int i = t; i < 128 * (CAP / 4); i += 1024) {
        int l = i / (CAP / 4), q = i % (CAP / 4);
        int node = b * 128 + l;
        if (node < N_NODES) {
            ((int4*)&perm_pad[(size_t)node * CAP])[q] = ((const int4*)bins[l])[q];
        }
    }
}

// ------------------- layer-1 aggregation (wave per node), fp16 gather
__global__ __launch_bounds__(256) void agg_kernel(const float* __restrict__ X,
                                                  const __half* __restrict__ Xh,
                                                  const int* __restrict__ deg_arr,
                                                  const int* __restrict__ perm_pad,
                                                  __half* __restrict__ out, int M) {
    constexpr int P = F_IN / 2;
    int w = (blockIdx.x * 256 + threadIdx.x) >> 6;
    int lane = threadIdx.x & 63;
    if (w >= M) return;
    int deg = deg_arr[w];
    const int* pl = perm_pad + (size_t)w * CAP;
    float ax = 0.f, ay = 0.f;
    int e = 0;
    for (; e + 16 <= deg; e += 16) {
        int s[16];
#pragma unroll
        for (int j = 0; j < 16; j++) s[j] = pl[e + j];
        float2 v[16];
#pragma unroll
        for (int j = 0; j < 16; j++)
            v[j] = __half22float2(*(const __half2*)(Xh + (size_t)s[j] * HROW + 2 * lane));
#pragma unroll
        for (int j = 0; j < 16; j++) { ax += v[j].x; ay += v[j].y; }
    }
    for (; e + 4 <= deg; e += 4) {
        int s0 = pl[e], s1 = pl[e + 1], s2 = pl[e + 2], s3 = pl[e + 3];
        float2 v0 = __half22float2(*(const __half2*)(Xh + (size_t)s0 * HROW + 2 * lane));
        float2 v1 = __half22float2(*(const __half2*)(Xh + (size_t)s1 * HROW + 2 * lane));
        float2 v2 = __half22float2(*(const __half2*)(Xh + (size_t)s2 * HROW + 2 * lane));
        float2 v3 = __half22float2(*(const __half2*)(Xh + (size_t)s3 * HROW + 2 * lane));
        ax += (v0.x + v1.x) + (v2.x + v3.x);
        ay += (v0.y + v1.y) + (v2.y + v3.y);
    }
    for (; e < deg; e++) {
        int s = pl[e];
        float2 v = __half22float2(*(const __half2*)(Xh + (size_t)s * HROW + 2 * lane));
        ax += v.x;
        ay += v.y;
    }
    float2 self = make_float2(0.f, 0.f);
    if (lane < P) self = *(const float2*)(X + (size_t)w * F_IN + 2 * lane);
    ((__half2*)(out + (size_t)w * HROW))[lane] = __floats2half2_rn(self.x + ax, self.y + ay);
}

// ---------- layer-2 aggregation on 32-wide fp16 y rows; fp16 output
__global__ __launch_bounds__(256) void agg32_kernel(const __half* __restrict__ Y,
                                                    const int* __restrict__ deg_arr,
                                                    const int* __restrict__ perm_pad,
                                                    const float* __restrict__ c0,
                                                    const float* __restrict__ b1,
                                                    __half* __restrict__ out, int M) {
    int w = (blockIdx.x * 256 + threadIdx.x) >> 6;
    int lane = threadIdx.x & 63;
    if (w >= M) return;
    int f = lane & 15;
    int g = lane >> 4;
    int deg = deg_arr[w];
    const int* pl = perm_pad + (size_t)w * CAP;
    float ax = 0.f, ay = 0.f;
    int e = g;
    for (; e + 4 < deg; e += 8) {
        int s0 = pl[e], s1 = pl[e + 4];
        float2 v0 = __half22float2(*(const __half2*)(Y + (size_t)s0 * DIM + 2 * f));
        float2 v1 = __half22float2(*(const __half2*)(Y + (size_t)s1 * DIM + 2 * f));
        ax += v0.x + v1.x;
        ay += v0.y + v1.y;
    }
    if (e < deg) {
        int s0 = pl[e];
        float2 v0 = __half22float2(*(const __half2*)(Y + (size_t)s0 * DIM + 2 * f));
        ax += v0.x;
        ay += v0.y;
    }
    ax += __shfl_xor(ax, 16); ax += __shfl_xor(ax, 32);
    ay += __shfl_xor(ay, 16); ay += __shfl_xor(ay, 32);
    if (g == 0) {
        float2 self = __half22float2(*(const __half2*)(Y + (size_t)w * DIM + 2 * f));
        float deg1 = (float)(deg + 1);
        float zx = fmaxf(self.x + ax + deg1 * c0[2 * f] + b1[2 * f], 0.f);
        float zy = fmaxf(self.y + ay + deg1 * c0[2 * f + 1] + b1[2 * f + 1], 0.f);
        ((__half2*)(out + (size_t)w * DIM))[f] = __floats2half2_rn(zx, zy);
    }
}

// ------- BN1-folded W3 split (fp16 hi/lo)
__global__ __launch_bounds__(256) void w3_fold(const float* __restrict__ W,
                                               const float* __restrict__ s1,
                                               const float* __restrict__ t1,
                                               unsigned short* __restrict__ hi_t,
                                               unsigned short* __restrict__ lo_t,
                                               float* __restrict__ c0) {
    int idx = blockIdx.x * 256 + threadIdx.x;
    if (idx < DIM * 128) {
        int n = idx >> 7, k = idx & 127;
        float v = (k < F_IN) ? s1[k] * W[(size_t)k * DIM + n] : 0.f;
        unsigned short h = f2h_u(v);
        hi_t[idx] = h;
        lo_t[idx] = f2h_u(v - h2f_u(h));
    }
    if (blockIdx.x == 0 && threadIdx.x < DIM) {
        int n = threadIdx.x;
        float acc = 0.f;
        for (int k = 0; k < F_IN; k++) acc += t1[k] * W[(size_t)k * DIM + n];
        c0[n] = acc;
    }
}

// ------- FUSED layer-1 MLP (fp16): H1 = relu(relu(A@W1+b1)@W2+b2), + BN1 stats
__global__ __launch_bounds__(256) void gemm_mlp112(const unsigned short* __restrict__ A,
                                                   const unsigned short* __restrict__ W1h,
                                                   const unsigned short* __restrict__ W1l,
                                                   const float* __restrict__ b1,
                                                   const unsigned short* __restrict__ W2h,
                                                   const unsigned short* __restrict__ W2l,
                                                   const float* __restrict__ b2,
                                                   __half* __restrict__ Ch,
                                                   float* __restrict__ pbuf, int M) {
    constexpr int NT = 7, N = 112, Kpad = 128, TS = 136;
    __shared__ __align__(16) char smem[64 * TS * 2 + 2 * N * 32 * 2 + 64 * 32 * 2];
    unsigned short* T1 = (unsigned short*)smem;
    unsigned short* Wh = (unsigned short*)(smem + 64 * TS * 2);
    unsigned short* Wl = Wh + N * 32;
    unsigned short* Ah = Wl + N * 32;
    float* sls = (float*)Ah;
    int t = threadIdx.x;
    int lane = t & 63, wid = t >> 6;
    int r0 = blockIdx.x * 64;
    int m = lane & 15, quad = lane >> 4;

    for (int i = t; i < 64 * 16; i += 256) {
        T1[(i >> 4) * TS + 112 + (i & 15)] = 0;
    }

    float4v acc[NT];
#pragma unroll
    for (int nt = 0; nt < NT; nt++) acc[nt] = (float4v){0.f, 0.f, 0.f, 0.f};

    for (int c = 0; c < 4; c++) {
        int kc = c * 32;
        {
            int row = t >> 2, seg = t & 3;
            int grow = r0 + row;
            uint4 v = make_uint4(0, 0, 0, 0);
            if (grow < M) v = *(const uint4*)(A + (size_t)grow * HROW + kc + seg * 8);
            *(uint4*)&Ah[row * 32 + seg * 8] = v;
        }
        for (int idx = t; idx < N * 8; idx += 256) {
            int n = idx >> 3, w = idx & 7;
            int gsrc = n * (Kpad / 4) + (kc >> 2) + w;
            ((uint2*)Wh)[idx] = ((const uint2*)W1h)[gsrc];
            ((uint2*)Wl)[idx] = ((const uint2*)W1l)[gsrc];
        }
        __syncthreads();
        half8 a = *(const half8*)&Ah[(wid * 16 + m) * 32 + quad * 8];
#pragma unroll
        for (int nt = 0; nt < NT; nt++) {
            half8 b_h = *(const half8*)&Wh[(nt * 16 + m) * 32 + quad * 8];
            half8 b_l = *(const half8*)&Wl[(nt * 16 + m) * 32 + quad * 8];
            acc[nt] = __builtin_amdgcn_mfma_f32_16x16x32_f16(a, b_h, acc[nt], 0, 0, 0);
            acc[nt] = __builtin_amdgcn_mfma_f32_16x16x32_f16(a, b_l, acc[nt], 0, 0, 0);
        }
        __syncthreads();
    }

#pragma unroll
    for (int nt = 0; nt < NT; nt++) {
        int col = nt * 16 + m;
        float bb = b1[col];
#pragma unroll
        for (int r = 0; r < 4; r++) {
            int row = wid * 16 + quad * 4 + r;
            T1[row * TS + col] = f2h_u(fmaxf(acc[nt][r] + bb, 0.f));
        }
        acc[nt] = (float4v){0.f, 0.f, 0.f, 0.f};
    }
    __syncthreads();

    for (int c = 0; c < 4; c++) {
        int kc = c * 32;
        for (int idx = t; idx < N * 8; idx += 256) {
            int n = idx >> 3, w = idx & 7;
            int gsrc = n * (Kpad / 4) + (kc >> 2) + w;
            ((uint2*)Wh)[idx] = ((const uint2*)W2h)[gsrc];
            ((uint2*)Wl)[idx] = ((const uint2*)W2l)[gsrc];
        }
        __syncthreads();
        half8 a = *(const half8*)&T1[(wid * 16 + m) * TS + kc + quad * 8];
#pragma unroll
        for (int nt = 0; nt < NT; nt++) {
            half8 b_h = *(const half8*)&Wh[(nt * 16 + m) * 32 + quad * 8];
            half8 b_l = *(const half8*)&Wl[(nt * 16 + m) * 32 + quad * 8];
            acc[nt] = __builtin_amdgcn_mfma_f32_16x16x32_f16(a, b_h, acc[nt], 0, 0, 0);
            acc[nt] = __builtin_amdgcn_mfma_f32_16x16x32_f16(a, b_l, acc[nt], 0, 0, 0);
        }
        __syncthreads();
    }

    float st_s[NT], st_q[NT];
#pragma unroll
    for (int nt = 0; nt < NT; nt++) {
        int col = nt * 16 + m;
        float bb = b2[col];
        float s_loc = 0.f, q_loc = 0.f;
#pragma unroll
        for (int r = 0; r < 4; r++) {
            int row = r0 + wid * 16 + quad * 4 + r;
            float v = fmaxf(acc[nt][r] + bb, 0.f);
            if (row < M) {
                Ch[(size_t)row * HROW + col] = __float2half(v);
                s_loc += v;
                q_loc += v * v;
            }
        }
        st_s[nt] = s_loc;
        st_q[nt] = q_loc;
    }
    for (int i = t; i < 64 * 2; i += 256) {
        int row = r0 + (i >> 1), o = (i & 1) * 8;
        if (row < M) *(uint4*)((unsigned short*)Ch + (size_t)row * HROW + 112 + o) = make_uint4(0, 0, 0, 0);
    }
#pragma unroll
    for (int nt = 0; nt < NT; nt++) {
        float s = st_s[nt], q = st_q[nt];
        s += __shfl_xor(s, 16); s += __shfl_xor(s, 32);
        q += __shfl_xor(q, 16); q += __shfl_xor(q, 32);
        if (quad == 0) {
            sls[wid * 2 * N + nt * 16 + m] = s;
            sls[wid * 2 * N + N + nt * 16 + m] = q;
        }
    }
    __syncthreads();
    for (int j = t; j < 2 * N; j += 256) {
        pbuf[(size_t)blockIdx.x * 2 * N + j] = sls[0 * 2 * N + j] + sls[1 * 2 * N + j] +
                                               sls[2 * 2 * N + j] + sls[3 * 2 * N + j];
    }
}

// ---------- fp16 MFMA GEMM: C/Ch = act(A_f16 @ W + bias), W fp16 hi+lo
template <int NT, int KC, int AS, bool RELU, int CHS, bool STATS>
__global__ __launch_bounds__(256) void gemm_mfma_h(const unsigned short* __restrict__ A,
                                                   const unsigned short* __restrict__ Whi,
                                                   const unsigned short* __restrict__ Wlo,
                                                   const float* __restrict__ bias,
                                                   float* __restrict__ C,
                                                   __half* __restrict__ Ch,
                                                   float* __restrict__ pbuf, int M) {
    constexpr int N = NT * 16;
    constexpr int Kpad = KC * 32;
    __shared__ __align__(16) unsigned short Ah[64 * 32];
    __shared__ __align__(16) unsigned short Wh[N * 32];
    __shared__ __align__(16) unsigned short Wl[N * 32];
    int t = threadIdx.x;
    int lane = t & 63, wid = t >> 6;
    int r0 = blockIdx.x * 64;
    int m = lane & 15, quad = lane >> 4;

    float4v acc[NT];
#pragma unroll
    for (int nt = 0; nt < NT; nt++) acc[nt] = (float4v){0.f, 0.f, 0.f, 0.f};

    for (int c = 0; c < KC; c++) {
        int kc = c * 32;
        {
            int row = t >> 2, seg = t & 3;
            int grow = r0 + row;
            uint4 v = make_uint4(0, 0, 0, 0);
            if (grow < M) v = *(const uint4*)(A + (size_t)grow * AS + kc + seg * 8);
            *(uint4*)&Ah[row * 32 + seg * 8] = v;
        }
        for (int idx = t; idx < N * 8; idx += 256) {
            int n = idx >> 3, w = idx & 7;
            int gsrc = n * (Kpad / 4) + (kc >> 2) + w;
            ((uint2*)Wh)[idx] = ((const uint2*)Whi)[gsrc];
            ((uint2*)Wl)[idx] = ((const uint2*)Wlo)[gsrc];
        }
        __syncthreads();
        half8 a = *(const half8*)&Ah[(wid * 16 + m) * 32 + quad * 8];
#pragma unroll
        for (int nt = 0; nt < NT; nt++) {
            half8 b_h = *(const half8*)&Wh[(nt * 16 + m) * 32 + quad * 8];
            half8 b_l = *(const half8*)&Wl[(nt * 16 + m) * 32 + quad * 8];
            acc[nt] = __builtin_amdgcn_mfma_f32_16x16x32_f16(a, b_h, acc[nt], 0, 0, 0);
            acc[nt] = __builtin_amdgcn_mfma_f32_16x16x32_f16(a, b_l, acc[nt], 0, 0, 0);
        }
        __syncthreads();
    }
    float st_s[NT], st_q[NT];
#pragma unroll
    for (int nt = 0; nt < NT; nt++) {
        int col = nt * 16 + m;
        float b = bias ? bias[col] : 0.f;
        float s_loc = 0.f, q_loc = 0.f;
#pragma unroll
        for (int r = 0; r < 4; r++) {
            int row = r0 + wid * 16 + quad * 4 + r;
            float v = acc[nt][r] + b;
            if (RELU) v = fmaxf(v, 0.f);
            if (row < M) {
                if (C) C[(size_t)row * N + col] = v;
                if (Ch) Ch[(size_t)row * CHS + col] = __float2half(v);
                if (STATS) { s_loc += v; q_loc += v * v; }
            }
        }
        st_s[nt] = s_loc;
        st_q[nt] = q_loc;
    }
    if constexpr (STATS) {
        __shared__ float sls[4][2 * N];
#pragma unroll
        for (int nt = 0; nt < NT; nt++) {
            float s = st_s[nt], q = st_q[nt];
            s += __shfl_xor(s, 16); s += __shfl_xor(s, 32);
            q += __shfl_xor(q, 16); q += __shfl_xor(q, 32);
            if (quad == 0) {
                sls[wid][nt * 16 + m] = s;
                sls[wid][N + nt * 16 + m] = q;
            }
        }
        __syncthreads();
        for (int j = t; j < 2 * N; j += 256) {
            pbuf[(size_t)blockIdx.x * 2 * N + j] = sls[0][j] + sls[1][j] + sls[2][j] + sls[3][j];
        }
    }
}

// --------- parallel BN finalize: one block per feature, 256-thread reduce
template <int F, int BLOCKS>
__global__ __launch_bounds__(256) void bn_finalize_par(const float* __restrict__ pbuf,
                                                       const float* __restrict__ g,
                                                       const float* __restrict__ b,
                                                       float* __restrict__ s,
                                                       float* __restrict__ tt, int M) {
    __shared__ double red[256];
    int j = blockIdx.x;
    int t = threadIdx.x;
    double sum = 0.0, sq = 0.0;
    for (int i = t; i < BLOCKS; i += 256) {
        sum += (double)pbuf[(size_t)i * 2 * F + j];
        sq  += (double)pbuf[(size_t)i * 2 * F + F + j];
    }
    red[t] = sum;
    __syncthreads();
    for (int o = 128; o > 0; o >>= 1) { if (t < o) red[t] += red[t + o]; __syncthreads(); }
    double total_sum = red[0];
    __syncthreads();
    red[t] = sq;
    __syncthreads();
    for (int o = 128; o > 0; o >>= 1) { if (t < o) red[t] += red[t + o]; __syncthreads(); }
    if (t == 0) {
        double mean = total_sum / M;
        double var = red[0] / M - mean * mean;
        double sc = (double)g[j] / sqrt(var + BN_EPS);
        s[j] = (float)sc;
        tt[j] = (float)((double)b[j] - mean * sc);
    }
}

// -------------------------------------------- pool (BN2 folded) + head
__global__ __launch_bounds__(256) void pool_head(const float* __restrict__ H2, const int* __restrict__ goff,
                                                 const float* __restrict__ s2, const float* __restrict__ t2,
                                                 const float* __restrict__ fcxd_w, const float* __restrict__ fcxd_b,
                                                 const float* __restrict__ fc1_w, const float* __restrict__ fc1_b,
                                                 const float* __restrict__ fc2_w, const float* __restrict__ fc2_b,
                                                 const float* __restrict__ fc3_w, const float* __restrict__ fc3_b,
                                                 const float* __restrict__ fc4_w, const float* __restrict__ fc4_b,
                                                 const float* __restrict__ fc5_w, const float* __restrict__ fc5_b,
                                                 float* __restrict__ out) {
    __shared__ float red[256];
    __shared__ float p[64];
    __shared__ float z[64];
    int g = blockIdx.x, t = threadIdx.x;
    int r0 = goff[g], r1 = goff[g + 1];
    int cnt = r1 - r0;
    int j = t & 31, rr = t >> 5;
    float a = 0.f;
    for (int r = r0 + rr; r < r1; r += 8) a += H2[(size_t)r * DIM + j];
    red[t] = a;
    __syncthreads();
    if (t < 32) {
        float ssum = 0.f;
        for (int q = 0; q < 8; q++) ssum += red[q * 32 + j];
        p[j] = s2[j] * ssum + (float)cnt * t2[j];
    }
    __syncthreads();
    if (t < 64) {
        float acc = fcxd_b[t];
        for (int i = 0; i < 32; i++) acc += p[i] * fcxd_w[i * 64 + t];
        z[t] = fmaxf(acc, 0.f);
    }
    __syncthreads();
    if (t < 32) {
        float acc = fc1_b[t];
        for (int i = 0; i < 64; i++) acc += z[i] * fc1_w[i * 32 + t];
        p[t] = acc;
    }
    __syncthreads();
    if (t < 16) {
        float acc = fc2_b[t];
        for (int i = 0; i < 32; i++) acc += p[i] * fc2_w[i * 16 + t];
        z[t] = acc;
    }
    __syncthreads();
    if (t < 8) {
        float acc = fc3_b[t];
        for (int i = 0; i < 16; i++) acc += z[i] * fc3_w[i * 8 + t];
        p[t] = acc;
    }
    __syncthreads();
    if (t < 2) {
        float acc = fc4_b[t];
        for (int i = 0; i < 8; i++) acc += p[i] * fc4_w[i * 2 + t];
        z[t] = acc;
    }
    __syncthreads();
    if (t == 0) {
        out[g] = z[0] * fc5_w[0] + z[1] * fc5_w[1] + fc5_b[0];
    }
}

// ---------------------------------------------------------------- launch
extern "C" void kernel_launch(void* const* d_in, const int* in_sizes, int n_in,
                              void* d_out, int out_size, void* d_ws, size_t ws_size,
                              hipStream_t stream) {
    const float* x     = (const float*)d_in[0];
    const int*   src   = (const int*)d_in[1];
    const int*   dst   = (const int*)d_in[2];
    const int*   batch = (const int*)d_in[3];
    const float* g1_w1 = (const float*)d_in[4];
    const float* g1_b1 = (const float*)d_in[5];
    const float* g1_w2 = (const float*)d_in[6];
    const float* g1_b2 = (const float*)d_in[7];
    const float* bn1_g = (const float*)d_in[8];
    const float* bn1_b = (const float*)d_in[9];
    const float* g2_w1 = (const float*)d_in[10];
    const float* g2_b1 = (const float*)d_in[11];
    const float* g2_w2 = (const float*)d_in[12];
    const float* g2_b2 = (const float*)d_in[13];
    const float* bn2_g = (const float*)d_in[14];
    const float* bn2_b = (const float*)d_in[15];
    const float* fcxd_w = (const float*)d_in[16];
    const float* fcxd_b = (const float*)d_in[17];
    const float* fc1_w = (const float*)d_in[18];
    const float* fc1_b = (const float*)d_in[19];
    const float* fc2_w = (const float*)d_in[20];
    const float* fc2_b = (const float*)d_in[21];
    const float* fc3_w = (const float*)d_in[22];
    const float* fc3_b = (const float*)d_in[23];
    const float* fc4_w = (const float*)d_in[24];
    const float* fc4_b = (const float*)d_in[25];
    const float* fc5_w = (const float*)d_in[26];
    const float* fc5_b = (const float*)d_in[27];
    float* out = (float*)d_out;
    char* ws = (char*)d_ws;

    const int GEMM_MB = (N_NODES + 63) / 64;       // 782

    size_t off = 0;
    auto take = [&](size_t bytes) { size_t o = off; off += (bytes + 255) & ~(size_t)255; return o; };
    int* gcur      = (int*)(ws + take((size_t)CB * 4));                 // zeroed (tiny)
    size_t zero_bytes = off;
    int* bucket    = (int*)(ws + take((size_t)CB * CBCAP * 4));
    int* perm_pad  = (int*)(ws + take((size_t)N_NODES * CAP * 4));
    int* deg       = (int*)(ws + take((size_t)N_NODES * 4));
    int* goff      = (int*)(ws + take((size_t)(N_GRAPHS + 4) * 4));
    float* s1      = (float*)(ws + take(F_IN * 4));
    float* t1      = (float*)(ws + take(F_IN * 4));
    float* s2      = (float*)(ws + take(DIM * 4));
    float* t2      = (float*)(ws + take(DIM * 4));
    float* c0      = (float*)(ws + take(DIM * 4));
    float* pb1     = (float*)(ws + take((size_t)GEMM_MB * 2 * F_IN * 4));
    float* pb2     = (float*)(ws + take((size_t)GEMM_MB * 2 * DIM * 4));
    unsigned short* w1h = (unsigned short*)(ws + take((size_t)F_IN * 128 * 2));
    unsigned short* w1l = (unsigned short*)(ws + take((size_t)F_IN * 128 * 2));
    unsigned short* w2h = (unsigned short*)(ws + take((size_t)F_IN * 128 * 2));
    unsigned short* w2l = (unsigned short*)(ws + take((size_t)F_IN * 128 * 2));
    unsigned short* w3h = (unsigned short*)(ws + take((size_t)DIM * 128 * 2));
    unsigned short* w3l = (unsigned short*)(ws + take((size_t)DIM * 128 * 2));
    unsigned short* w4h = (unsigned short*)(ws + take((size_t)DIM * 32 * 2));
    unsigned short* w4l = (unsigned short*)(ws + take((size_t)DIM * 32 * 2));
    __half* x_half = (__half*)(ws + take((size_t)N_NODES * HROW * 2));
    __half* aggA   = (__half*)(ws + take((size_t)N_NODES * HROW * 2));
    __half* h1h    = (__half*)(ws + take((size_t)N_NODES * HROW * 2));
    __half* y_half = (__half*)(ws + take((size_t)N_NODES * DIM * 2));
    __half* s1h    = (__half*)(ws + take((size_t)N_NODES * DIM * 2));
    float* bufS2   = (float*)(ws + take((size_t)N_NODES * DIM * 4));
    (void)ws_size; (void)in_sizes; (void)n_in; (void)out_size;

    hipMemsetAsync(ws, 0, zero_bytes, stream);

    // graph build: LDS counting-sort partition (coalesced runs) + prep + bins
    edge_partition<<<NPART, 1024, 0, stream>>>(src, dst, gcur, bucket);
    prep_kernel<<<PB_GB, 256, 0, stream>>>(x, x_half,
                                           g1_w1, w1h, w1l, g1_w2, w2h, w2l, g2_w2, w4h, w4l,
                                           batch, goff);
    bin_build<<<CB, 1024, 0, stream>>>(gcur, bucket, perm_pad, deg);

    const int AGG_BLOCKS = (N_NODES + 3) / 4;

    // GIN layer 1: agg (fp16 out) -> fused fp16 MLP (+BN1 stats) -> finalize
    agg_kernel<<<AGG_BLOCKS, 256, 0, stream>>>(x, x_half, deg, perm_pad, aggA, N_NODES);
    gemm_mlp112<<<GEMM_MB, 256, 0, stream>>>((const unsigned short*)aggA, w1h, w1l, g1_b1,
                                             w2h, w2l, g1_b2, h1h, pb1, N_NODES);
    bn_finalize_par<F_IN, 782><<<F_IN, 256, 0, stream>>>(pb1, bn1_g, bn1_b, s1, t1, N_NODES);

    // GIN layer 2: linear-first (BN1 folded), 32-wide agg, BN2 stats fused
    w3_fold<<<(DIM * 128 + 255) / 256, 256, 0, stream>>>(g2_w1, s1, t1, w3h, w3l, c0);
    gemm_mfma_h<2, 4, HROW, false, DIM, false><<<GEMM_MB, 256, 0, stream>>>(
        (const unsigned short*)h1h, w3h, w3l, nullptr, nullptr, y_half, nullptr, N_NODES);
    agg32_kernel<<<AGG_BLOCKS, 256, 0, stream>>>(y_half, deg, perm_pad, c0, g2_b1, s1h, N_NODES);
    gemm_mfma_h<2, 1, DIM, true, 0, true><<<GEMM_MB, 256, 0, stream>>>(
        (const unsigned short*)s1h, w4h, w4l, g2_b2, bufS2, nullptr, pb2, N_NODES);
    bn_finalize_par<DIM, 782><<<DIM, 256, 0, stream>>>(pb2, bn2_g, bn2_b, s2, t2, N_NODES);

    // pool (BN2 folded) + dense head
    pool_head<<<N_GRAPHS, 256, 0, stream>>>(bufS2, goff, s2, t2,
                                            fcxd_w, fcxd_b, fc1_w, fc1_b, fc2_w, fc2_b,
                                            fc3_w, fc3_b, fc4_w, fc4_b, fc5_w, fc5_b, out);
}